// Round 1
// 1291.460 us; speedup vs baseline: 1.3579x; 1.3579x over previous
//
#include <hip/hip_runtime.h>
#include <math.h>

#define NC 60
#define ND 952
#define DE 2040
#define NG 17737
#define NF 881
#define GAMMA_C 8.7f
#define EPS_BN 1e-5f

// ---- fp32 workspace layout (float offsets) ----
#define O_DX      0
#define O_DC      64
#define O_DY      128
#define O_DDV     1088
#define O_B4H     2048
#define O_A4H     2112
#define O_CMU     3072
#define O_CIS     3136
#define O_DMU     3200
#define O_DIS     4160
#define O_ZSC     5120
#define O_ZSH     5184
#define O_EMBC    8000       // 60*2040   = 122400
#define O_EMBD    130400     // 952*2040  = 1942080
#define O_CSUM    2072480    // 122400
#define O_DSUM    2194880    // 1942080
#define O_PS      4136960    // 10*122400 = 1224000 (slabs, reused)
#define O_H16     5360960    // fp16 pool starts here (float offset, 16B aligned)
// total floats: 5360960 + 8023680 = 13384640 -> 53.5 MB

// ---- fp16 pool layout (half offsets, all mult of 8) ----
#define H_CX    0            // 60*17760   = 1065600 (znormed cell_exprs, K-pad)
#define H_DF    1065600      // 952*896    = 852992  (drug_finger, K-pad)
#define H_LDW   1918592      // 2040*896   = 1827840 (ldd_w, K-pad)
#define H_ALC   3746432      // 60*960     = 57600   (dx.*adj.*dy)
#define H_ALD   3804032      // 952*64     = 60928   (dy.*adjT.*dx)
#define H_CH    3864960      // 60*64      = 3840
#define H_CHS   3868800      // 60*64      = 3840    (b4h.*CH.*b4h)
#define H_DH    3872640      // 952*960    = 913920
#define H_DHS   4786560      // 952*960    = 913920  (a4h.*DH.*a4h)
#define H_FIGT  5700480      // 2040*960   = 1958400 (fig^T, pad)
#define H_EXPT  7658880      // 2040*64    = 130560  (exp^T, pad)
#define H_XC    7789440      // 60*8160    = 489600
#define H_XD    8279040      // 952*8160   = 7768320 -> end 16047360 halves

typedef _Float16 f16;
typedef __attribute__((ext_vector_type(8))) _Float16 f16x8;
typedef __attribute__((ext_vector_type(4))) float f32x4;

struct Job {
    int aoff[16]; int boff[16]; int lda[16]; int ldb[16];
    int len[16]; int blim[16]; int coff[16]; int bflag[16];
    float rsg[16];
};

__device__ __forceinline__ float blockReduceSum(float v, float* red) {
    const int t = threadIdx.x;
    red[t] = v;
    __syncthreads();
    for (int off = 128; off > 0; off >>= 1) {
        if (t < off) red[t] += red[t + off];
        __syncthreads();
    }
    float r = red[0];
    __syncthreads();
    return r;
}

// ---- scalars: dx/dc/dy/ddv, b4h, a4h ----
__global__ __launch_bounds__(256) void k_pre(
    const float* __restrict__ adj, const float* __restrict__ ch,
    const float* __restrict__ dh, float* __restrict__ ws)
{
    __shared__ float red[256];
    const int b = blockIdx.x, t = threadIdx.x;
    if (b < NC) {
        const int c = b;
        float s = 0.f;
        for (int j = t; j < ND; j += 256) s += adj[c * ND + j];
        float rs = blockReduceSum(s, red) + 1.f;
        if (t == 0) { ws[O_DX + c] = rsqrtf(rs); ws[O_DC + c] = 1.f / rs + 1.f; }
        float s2 = (t < NC) ? ch[c * NC + t] : 0.f;
        float hs = blockReduceSum(s2, red) + 1.f;
        if (t == 0) ws[O_B4H + c] = 1.f / hs;
    } else {
        const int i = b - NC;
        float s = 0.f;
        for (int j = t; j < ND; j += 256) s += dh[i * ND + j];
        float hs = blockReduceSum(s, red) + 1.f;
        if (t == 0) ws[O_A4H + i] = 1.f / hs;
        float s2 = (t < NC) ? adj[t * ND + i] : 0.f;
        float cs = blockReduceSum(s2, red) + 1.f;
        if (t == 0) { ws[O_DY + i] = rsqrtf(cs); ws[O_DDV + i] = 1.f / cs + 1.f; }
    }
}

// ---- z-norm stats per cell row ----
__global__ __launch_bounds__(256) void k_zstats(
    const float* __restrict__ x, float* __restrict__ ws)
{
    __shared__ float r1[256];
    __shared__ float r2[256];
    const int c = blockIdx.x, t = threadIdx.x;
    const float* row = x + c * NG;
    float s = 0.f, q = 0.f;
    for (int j = t; j < NG; j += 256) { float v = row[j]; s += v; q += v * v; }
    r1[t] = s; r2[t] = q;
    __syncthreads();
    for (int off = 128; off > 0; off >>= 1) {
        if (t < off) { r1[t] += r1[t + off]; r2[t] += r2[t + off]; }
        __syncthreads();
    }
    if (t == 0) {
        const float mu = r1[0] / (float)NG;
        const float var = (r2[0] - (float)NG * mu * mu) / (float)(NG - 1);
        const float inv = rsqrtf(var);
        ws[O_ZSC + c] = inv;
        ws[O_ZSH + c] = -mu * inv;
    }
}

// ---- convert/pad/scale-fold all small fp16 operands in one pass ----
#define CVT_TOT 5700480
__global__ __launch_bounds__(256) void k_cvt(
    const float* __restrict__ ce, const float* __restrict__ dfing,
    const float* __restrict__ ldw, const float* __restrict__ adj,
    const float* __restrict__ chyp, const float* __restrict__ dhyp,
    const float* __restrict__ ws, f16* __restrict__ h16)
{
    const float* dx = ws + O_DX;
    const float* dy = ws + O_DY;
    const float* b4h = ws + O_B4H;
    const float* a4h = ws + O_A4H;
    const float* zsc = ws + O_ZSC;
    const float* zsh = ws + O_ZSH;
    for (int idx = blockIdx.x * 256 + threadIdx.x; idx < CVT_TOT;
         idx += gridDim.x * 256) {
        float v = 0.f;
        if (idx < H_DF) {                     // cx16: znormed cell_exprs
            const int c = idx / 17760, k = idx % 17760;
            if (k < NG) v = ce[c * NG + k] * zsc[c] + zsh[c];
        } else if (idx < H_LDW) {             // df16
            const int j = idx - H_DF;
            const int i = j / 896, k = j % 896;
            if (k < NF) v = dfing[i * NF + k];
        } else if (idx < H_ALC) {             // ldw16
            const int j = idx - H_LDW;
            const int d = j / 896, k = j % 896;
            if (k < NF) v = ldw[d * NF + k];
        } else if (idx < H_ALD) {             // aggLc
            const int j = idx - H_ALC;
            const int c = j / 960, i = j % 960;
            if (i < ND) v = dx[c] * adj[c * ND + i] * dy[i];
        } else if (idx < H_CH) {              // aggLd
            const int j = idx - H_ALD;
            const int i = j / 64, c = j % 64;
            if (c < NC) v = dy[i] * adj[c * ND + i] * dx[c];
        } else if (idx < H_CHS) {             // ch16
            const int j = idx - H_CH;
            const int c = j / 64, k = j % 64;
            if (k < NC) v = chyp[c * NC + k];
        } else if (idx < H_DH) {              // chs16
            const int j = idx - H_CHS;
            const int c = j / 64, k = j % 64;
            if (k < NC) v = b4h[c] * chyp[c * NC + k] * b4h[k];
        } else if (idx < H_DHS) {             // dh16
            const int j = idx - H_DH;
            const int i = j / 960, k = j % 960;
            if (k < ND) v = dhyp[i * ND + k];
        } else {                              // dhs16
            const int j = idx - H_DHS;
            const int i = j / 960, k = j % 960;
            if (k < ND) v = a4h[i] * dhyp[i * ND + k] * a4h[k];
        }
        h16[idx] = (f16)v;
    }
}

// ============================================================================
// Unified fp16 MFMA NT GEMM with job table.
//   acc[m,n] = sum over windows of A16[m,k] * B[n,k]
//   BMODE: 0 = B fp16 (aligned), 1 = B fp32 aligned (uint4), 2 = B fp32
//          unaligned/scalar with real-K limit blim.
//   partial=1: blockIdx.z picks one job; else loop jobs 0..nwin-1.
//   Epilogue: v = rsg*acc (+ base[m,n] if bflag); store fp32 (ws+coff) or
//   fp16 (h16+coff) per F16OUT. Deterministic, no atomics.
// Tile BMxBN, 4 waves 2x2, KT=32, 16x16x32 f16 MFMA.
// ============================================================================
template<int BM, int BN, int BMODE, int F16OUT>
__global__ __launch_bounds__(256) void k_fgemm(
    const f16* __restrict__ Ah, const void* __restrict__ Bp,
    float* __restrict__ ws, f16* __restrict__ h16,
    const float* __restrict__ basep, int baseld,
    int M, int N, int ldc, int nwin, int partial, Job jb)
{
    constexpr int PSA = BM * 8 + 8;
    constexpr int PSB = BN * 8 + 8;
    constexpr int MI = BM / 32;
    constexpr int NI = BN / 32;
    __shared__ __align__(16) unsigned short As[4 * PSA];
    __shared__ __align__(16) unsigned short Bs[4 * PSB];
    const int t = threadIdx.x;
    const int wv = t >> 6, ln = t & 63;
    const int wm = wv >> 1, wn = wv & 1;
    const int kg = ln >> 4, lm = ln & 15;
    const int m0 = blockIdx.y * BM;
    const int n0 = blockIdx.x * BN;

    f32x4 acc[MI][NI];
#pragma unroll
    for (int i = 0; i < MI; ++i)
#pragma unroll
        for (int j = 0; j < NI; ++j) acc[i][j] = (f32x4){0.f, 0.f, 0.f, 0.f};

    const int z0 = partial ? (int)blockIdx.z : 0;
    const int z1 = partial ? (int)blockIdx.z + 1 : nwin;

    for (int zi = z0; zi < z1; ++zi) {
        const int Ab = jb.aoff[zi], Bb = jb.boff[zi];
        const int lda = jb.lda[zi], ldb = jb.ldb[zi];
        const int len = jb.len[zi], bl = jb.blim[zi];
        for (int kb = 0; kb < len; kb += 32) {
            // ---- stage A (BM x 32 halves), uint4 chunks of 8 halves ----
#pragma unroll
            for (int p = 0; p < (BM * 4) / 256; ++p) {
                const int ci = p * 256 + t;
                const int m = ci >> 2, kc = ci & 3;
                const int k0 = kb + kc * 8;
                uint4 d = {0u, 0u, 0u, 0u};
                if (m0 + m < M && k0 < len)
                    d = *(const uint4*)(Ah + Ab + (m0 + m) * lda + k0);
                *(uint4*)&As[kc * PSA + m * 8] = d;
            }
            // ---- stage B (BN x 32) ----
#pragma unroll
            for (int p = 0; p < (BN * 4) / 256; ++p) {
                const int ci = p * 256 + t;
                const int n = ci >> 2, kc = ci & 3;
                const int k0 = kb + kc * 8;
                const bool ok = (n0 + n < N) && (k0 < len);
                if (BMODE == 0) {
                    uint4 d = {0u, 0u, 0u, 0u};
                    if (ok) d = *(const uint4*)((const f16*)Bp + Bb + (n0 + n) * ldb + k0);
                    *(uint4*)&Bs[kc * PSB + n * 8] = d;
                } else if (BMODE == 1) {
                    f16x8 pk = (f16x8)(f16)0.f;
                    if (ok) {
                        const float* bq = (const float*)Bp + Bb + (n0 + n) * ldb + k0;
                        const float4 x = *(const float4*)bq;
                        const float4 y = *(const float4*)(bq + 4);
                        pk[0] = (f16)x.x; pk[1] = (f16)x.y; pk[2] = (f16)x.z; pk[3] = (f16)x.w;
                        pk[4] = (f16)y.x; pk[5] = (f16)y.y; pk[6] = (f16)y.z; pk[7] = (f16)y.w;
                    }
                    *(f16x8*)&Bs[kc * PSB + n * 8] = pk;
                } else {
                    f16x8 pk = (f16x8)(f16)0.f;
                    if (n0 + n < N) {
                        const float* bq = (const float*)Bp + Bb + (n0 + n) * ldb + k0;
#pragma unroll
                        for (int e = 0; e < 8; ++e)
                            if (k0 + e < bl) pk[e] = (f16)bq[e];
                    }
                    *(f16x8*)&Bs[kc * PSB + n * 8] = pk;
                }
            }
            __syncthreads();
            f16x8 af[MI], bfr[NI];
#pragma unroll
            for (int i = 0; i < MI; ++i)
                af[i] = *(f16x8*)&As[kg * PSA + (wm * (BM / 2) + i * 16 + lm) * 8];
#pragma unroll
            for (int j = 0; j < NI; ++j)
                bfr[j] = *(f16x8*)&Bs[kg * PSB + (wn * (BN / 2) + j * 16 + lm) * 8];
#pragma unroll
            for (int i = 0; i < MI; ++i)
#pragma unroll
                for (int j = 0; j < NI; ++j)
                    acc[i][j] = __builtin_amdgcn_mfma_f32_16x16x32_f16(
                        af[i], bfr[j], acc[i][j], 0, 0, 0);
            __syncthreads();
        }
    }
    // ---- epilogue ----
    const int zz = partial ? (int)blockIdx.z : 0;
    const float rs = jb.rsg[zz];
    const int co = jb.coff[zz];
    const int bfl = jb.bflag[zz];
#pragma unroll
    for (int i = 0; i < MI; ++i) {
        const int mb = m0 + wm * (BM / 2) + i * 16 + kg * 4;
#pragma unroll
        for (int r = 0; r < 4; ++r) {
            const int m = mb + r;
            if (m >= M) continue;
#pragma unroll
            for (int j = 0; j < NI; ++j) {
                const int n = n0 + wn * (BN / 2) + j * 16 + lm;
                if (n >= N) continue;
                float v = rs * acc[i][j][r];
                if (bfl) v += basep[m * baseld + n];
                if (F16OUT) h16[co + m * ldc + n] = (f16)v;
                else        ws[co + m * ldc + n] = v;
            }
        }
    }
}

// ---- fixed-order reduction of Z partial slabs ----
__global__ __launch_bounds__(256) void k_reduce(
    const float* __restrict__ P, float* __restrict__ out, int Z, int slab, int n)
{
    const int i = blockIdx.x * 256 + threadIdx.x;
    if (i < n) {
        float s = 0.f;
        for (int z = 0; z < Z; ++z) s += P[z * slab + i];
        out[i] = s;
    }
}

// ---- BatchNorm (train stats): one block per column, register-resident ----
// Replaces the old 16-block k_bn (541 us, 0.38% occupancy, latency-bound).
// grid = 2*DE blocks x 256 threads. Each thread holds <=4 row values in
// registers; dual block-reduce -> scale/shift -> in-place fp32 write +
// coalesced transposed fp16 write (lanes index consecutive rows of T).
__global__ __launch_bounds__(256) void k_bn2(
    float* __restrict__ ws, f16* __restrict__ h16,
    const float* __restrict__ cg, const float* __restrict__ cb,
    const float* __restrict__ dg, const float* __restrict__ db)
{
    __shared__ float r1[256];
    __shared__ float r2[256];
    const int id = blockIdx.x, t = threadIdx.x;
    float* X; f16* T; const float* g; const float* b; int R, Rp, ldT, d;
    if (id < DE) { d = id; X = ws + O_EMBC; T = h16 + H_EXPT; g = cg; b = cb; R = NC; Rp = 64; ldT = 64; }
    else { d = id - DE; X = ws + O_EMBD; T = h16 + H_FIGT; g = dg; b = db; R = ND; Rp = 960; ldT = 960; }
    float vals[4];
    float s = 0.f, q = 0.f;
#pragma unroll
    for (int v = 0; v < 4; ++v) {
        const int r = t + v * 256;
        float x = 0.f;
        if (r < R) x = X[r * DE + d];
        vals[v] = x;
        s += x; q += x * x;
    }
    r1[t] = s; r2[t] = q;
    __syncthreads();
    for (int off = 128; off > 0; off >>= 1) {
        if (t < off) { r1[t] += r1[t + off]; r2[t] += r2[t + off]; }
        __syncthreads();
    }
    const float mu = r1[0] / (float)R;
    float var = r2[0] / (float)R - mu * mu;
    var = fmaxf(var, 0.f);
    const float sc = rsqrtf(var + EPS_BN) * g[d];
    const float sh = b[d] - mu * sc;
#pragma unroll
    for (int v = 0; v < 4; ++v) {
        const int r = t + v * 256;
        if (r < R) {
            const float y = vals[v] * sc + sh;
            X[r * DE + d] = y;
            T[d * ldT + r] = (f16)y;
        } else if (r < Rp) {
            T[d * ldT + r] = (f16)0.f;
        }
    }
}

// ---- Xc/Xd block0 = diag-scaled emb (fp16) ----
__global__ __launch_bounds__(256) void k_buildX(
    const float* __restrict__ ws, f16* __restrict__ h16)
{
    const int idx = blockIdx.x * 256 + threadIdx.x;
    if (idx < NC * DE) {
        const int c = idx / DE, d = idx % DE;
        h16[H_XC + c * (4 * DE) + d] = (f16)(ws[O_DC + c] * ws[O_EMBC + idx]);
    } else if (idx < (NC + ND) * DE) {
        const int k = idx - NC * DE;
        const int i = k / DE, d = k % DE;
        h16[H_XD + i * (4 * DE) + d] = (f16)(ws[O_DDV + i] * ws[O_EMBD + k]);
    }
}

// ---- epilogue: agg = relu((sum + bias)*(emb+1)) in-place ----
__global__ __launch_bounds__(256) void k_epi(
    float* __restrict__ ws, const float* __restrict__ b_agg)
{
    const int idx = blockIdx.x * 256 + threadIdx.x;
    if (idx < NC * DE) {
        const int d = idx % DE;
        const float bc = b_agg[0 * DE + d] + b_agg[1 * DE + d] + b_agg[4 * DE + d] + b_agg[6 * DE + d];
        const float v = (ws[O_CSUM + idx] + bc) * (ws[O_EMBC + idx] + 1.f);
        ws[O_CSUM + idx] = fmaxf(v, 0.f);
    } else if (idx < (NC + ND) * DE) {
        const int k = idx - NC * DE;
        const int d = k % DE;
        const float bd = b_agg[2 * DE + d] + b_agg[3 * DE + d] + b_agg[5 * DE + d] + b_agg[7 * DE + d];
        const float v = (ws[O_DSUM + k] + bd) * (ws[O_EMBD + k] + 1.f);
        ws[O_DSUM + k] = fmaxf(v, 0.f);
    }
}

// ---- per-row mean + 1/||x-mu|| ----
__global__ __launch_bounds__(256) void k_rowstats(float* __restrict__ ws)
{
    __shared__ float red[256];
    const int b = blockIdx.x, t = threadIdx.x;
    const float* row;
    int omu, ois;
    if (b < NC) { row = ws + O_CSUM + b * DE; omu = O_CMU + b; ois = O_CIS + b; }
    else { const int i = b - NC; row = ws + O_DSUM + i * DE; omu = O_DMU + i; ois = O_DIS + i; }
    float s = 0.f;
    for (int j = t; j < DE; j += 256) s += row[j];
    const float mu = blockReduceSum(s, red) / (float)DE;
    float q = 0.f;
    for (int j = t; j < DE; j += 256) { const float v = row[j] - mu; q += v * v; }
    const float ss = blockReduceSum(q, red);
    if (t == 0) { ws[omu] = mu; ws[ois] = rsqrtf(ss); }
}

// ---- corr + sigmoid ----
__global__ __launch_bounds__(256) void k_corr(
    const float* __restrict__ ws, float* __restrict__ out)
{
    const int KT = 32;
    __shared__ float xs[16][KT + 1];
    __shared__ float ys[16][KT + 1];
    const int t = threadIdx.x;
    const int tcr = t >> 4, ti = t & 15;
    const int c0 = blockIdx.y * 16, i0 = blockIdx.x * 16;
    float acc = 0.f;
    for (int kb = 0; kb < DE; kb += KT) {
#pragma unroll
        for (int q = 0; q < 2; ++q) {
            const int s = q * 256 + t;
            const int row = s >> 5, kk = s & 31;
            const int k = kb + kk;
            const int c = c0 + row;
            xs[row][kk] = (c < NC && k < DE) ? ws[O_CSUM + c * DE + k] : 0.f;
            const int i = i0 + row;
            ys[row][kk] = (i < ND && k < DE) ? ws[O_DSUM + i * DE + k] : 0.f;
        }
        __syncthreads();
#pragma unroll
        for (int kt = 0; kt < KT; ++kt) acc += xs[tcr][kt] * ys[ti][kt];
        __syncthreads();
    }
    const int c = c0 + tcr, i = i0 + ti;
    if (c < NC && i < ND) {
        const float num = acc - (float)DE * ws[O_CMU + c] * ws[O_DMU + i];
        const float corr = num * ws[O_CIS + c] * ws[O_DIS + i];
        out[c * ND + i] = 1.f / (1.f + expf(-GAMMA_C * corr));
    }
}

static inline void jclear(Job& j) {
    for (int z = 0; z < 16; ++z) {
        j.aoff[z] = j.boff[z] = j.lda[z] = j.ldb[z] = 0;
        j.len[z] = j.blim[z] = j.coff[z] = j.bflag[z] = 0;
        j.rsg[z] = 1.f;
    }
}

extern "C" void kernel_launch(void* const* d_in, const int* in_sizes, int n_in,
                              void* d_out, int out_size, void* d_ws, size_t ws_size,
                              hipStream_t stream)
{
    const float* adj         = (const float*)d_in[0];
    const float* cell_exprs  = (const float*)d_in[1];
    const float* drug_finger = (const float*)d_in[2];
    const float* cell_hyper  = (const float*)d_in[3];
    const float* drug_hyper  = (const float*)d_in[4];
    const float* W_agg       = (const float*)d_in[5];
    const float* b_agg       = (const float*)d_in[6];
    const float* ldd_w       = (const float*)d_in[7];
    const float* lcc_w       = (const float*)d_in[9];
    const float* bnd_g       = (const float*)d_in[11];
    const float* bnd_b       = (const float*)d_in[12];
    const float* bnc_g       = (const float*)d_in[13];
    const float* bnc_b       = (const float*)d_in[14];
    float* ws  = (float*)d_ws;
    float* out = (float*)d_out;
    f16* h16 = (f16*)(ws + O_H16);

    // 1) scalars
    k_pre<<<NC + ND, 256, 0, stream>>>(adj, cell_hyper, drug_hyper, ws);
    // 2) z-norm stats
    k_zstats<<<NC, 256, 0, stream>>>(cell_exprs, ws);
    // 3) fp16 operand pool (scale-folded, padded)
    k_cvt<<<2048, 256, 0, stream>>>(cell_exprs, drug_finger, ldd_w, adj,
                                    cell_hyper, drug_hyper, ws, h16);

    // 4) exp = cx16 @ lcc_w^T (K 17760 padded, 10 windows of 1776) -> slabs
    {
        Job j; jclear(j);
        for (int z = 0; z < 10; ++z) {
            j.aoff[z] = H_CX + z * 1776; j.lda[z] = 17760;
            j.boff[z] = z * 1776;        j.ldb[z] = NG;
            j.len[z] = 1776;
            int bl = NG - z * 1776; j.blim[z] = bl > 1776 ? 1776 : bl;
            j.coff[z] = O_PS + z * (NC * DE);
        }
        k_fgemm<64, 128, 2, 0><<<dim3(16, 1, 10), 256, 0, stream>>>(
            h16, lcc_w, ws, h16, nullptr, 0, NC, DE, DE, 10, 1, j);
        k_reduce<<<479, 256, 0, stream>>>(ws + O_PS, ws + O_EMBC, 10, NC * DE, NC * DE);
    }
    // 5) fig = df16 @ ldw16^T (K=896) -> embD direct
    {
        Job j; jclear(j);
        j.aoff[0] = H_DF; j.lda[0] = 896;
        j.boff[0] = H_LDW; j.ldb[0] = 896;
        j.len[0] = 896; j.coff[0] = O_EMBD;
        k_fgemm<64, 128, 0, 0><<<dim3(16, 15, 1), 256, 0, stream>>>(
            h16, h16, ws, h16, nullptr, 0, ND, DE, DE, 1, 0, j);
    }
    // 6) BN (in-place fp32) + expT16/figT16 — one block per column
    k_bn2<<<2 * DE, 256, 0, stream>>>(ws, h16, bnc_g, bnc_b, bnd_g, bnd_b);
    // 7) Xc/Xd block0
    k_buildX<<<8065, 256, 0, stream>>>(ws, h16);

    // 8) cell X-jobs: X1 / X4 / X6 in one launch
    {
        Job j; jclear(j);
        j.aoff[0] = H_ALC; j.lda[0] = 960; j.boff[0] = H_FIGT; j.ldb[0] = 960;
        j.len[0] = 960; j.coff[0] = H_XC + DE;
        j.aoff[1] = H_CH; j.lda[1] = 64; j.boff[1] = H_EXPT; j.ldb[1] = 64;
        j.len[1] = 64; j.coff[1] = H_XC + 2 * DE;
        j.aoff[2] = H_CHS; j.lda[2] = 64; j.boff[2] = H_EXPT; j.ldb[2] = 64;
        j.len[2] = 64; j.coff[2] = H_XC + 3 * DE; j.rsg[2] = -1.f; j.bflag[2] = 1;
        k_fgemm<64, 128, 0, 1><<<dim3(16, 1, 3), 256, 0, stream>>>(
            h16, h16, ws, h16, ws + O_EMBC, DE, NC, DE, 4 * DE, 3, 1, j);
    }
    // 9) drug X-jobs: X3 / X5 / X7 in one launch
    {
        Job j; jclear(j);
        j.aoff[0] = H_ALD; j.lda[0] = 64; j.boff[0] = H_EXPT; j.ldb[0] = 64;
        j.len[0] = 64; j.coff[0] = H_XD + DE;
        j.aoff[1] = H_DH; j.lda[1] = 960; j.boff[1] = H_FIGT; j.ldb[1] = 960;
        j.len[1] = 960; j.coff[1] = H_XD + 2 * DE;
        j.aoff[2] = H_DHS; j.lda[2] = 960; j.boff[2] = H_FIGT; j.ldb[2] = 960;
        j.len[2] = 960; j.coff[2] = H_XD + 3 * DE; j.rsg[2] = -1.f; j.bflag[2] = 1;
        k_fgemm<128, 128, 0, 1><<<dim3(16, 8, 3), 256, 0, stream>>>(
            h16, h16, ws, h16, ws + O_EMBD, DE, ND, DE, 4 * DE, 3, 1, j);
    }
    // 10) cell main: Xc16 @ [W0|W1|W4|W6]^T (8 windows) -> slabs -> csum
    {
        const int permc[4] = {0, 1, 4, 6};
        Job j; jclear(j);
        for (int z = 0; z < 8; ++z) {
            const int ib = z >> 1, sub = z & 1;
            j.aoff[z] = H_XC + ib * DE + sub * 1024; j.lda[z] = 4 * DE;
            j.boff[z] = permc[ib] * DE * DE + sub * 1024; j.ldb[z] = DE;
            j.len[z] = sub ? 1016 : 1024;
            j.coff[z] = O_PS + z * (NC * DE);
        }
        k_fgemm<64, 128, 1, 0><<<dim3(16, 1, 8), 256, 0, stream>>>(
            h16, W_agg, ws, h16, nullptr, 0, NC, DE, DE, 8, 1, j);
        k_reduce<<<479, 256, 0, stream>>>(ws + O_PS, ws + O_CSUM, 8, NC * DE, NC * DE);
    }
    // 11) drug main: Xd16 @ [W2|W3|W5|W7]^T (4 windows in-loop) -> dsum
    {
        const int permd[4] = {2, 3, 5, 7};
        Job j; jclear(j);
        for (int z = 0; z < 4; ++z) {
            j.aoff[z] = H_XD + z * DE; j.lda[z] = 4 * DE;
            j.boff[z] = permd[z] * DE * DE; j.ldb[z] = DE;
            j.len[z] = DE;
        }
        j.coff[0] = O_DSUM;
        k_fgemm<128, 64, 1, 0><<<dim3(32, 8, 1), 256, 0, stream>>>(
            h16, W_agg, ws, h16, nullptr, 0, ND, DE, DE, 4, 0, j);
    }

    // 12) epilogue, stats, corr
    k_epi<<<8065, 256, 0, stream>>>(ws, b_agg);
    k_rowstats<<<NC + ND, 256, 0, stream>>>(ws);
    k_corr<<<dim3(60, 4), 256, 0, stream>>>(ws, out);

    (void)in_sizes; (void)n_in; (void)out_size; (void)ws_size;
}

// Round 2
// 995.177 us; speedup vs baseline: 1.7622x; 1.2977x over previous
//
#include <hip/hip_runtime.h>
#include <math.h>

#define NC 60
#define ND 952
#define DE 2040
#define NG 17737
#define NF 881
#define GAMMA_C 8.7f
#define EPS_BN 1e-5f

// ---- fp32 workspace layout (float offsets) ----
#define O_DX      0
#define O_DC      64
#define O_DY      128
#define O_DDV     1088
#define O_B4H     2048
#define O_A4H     2112
#define O_CMU     3072
#define O_CIS     3136
#define O_DMU     3200
#define O_DIS     4160
#define O_ZSC     5120
#define O_ZSH     5184
#define O_EMBC    8000       // 60*2040   = 122400
#define O_EMBD    130400     // 952*2040  = 1942080
#define O_CSUM    2072480    // 122400
#define O_DSUM    2194880    // 1942080
#define O_PS      4136960    // 10*122400 = 1224000 (slabs, reused)
#define O_H16     5360960    // fp16 pool starts here (float offset, 16B aligned)
// total floats: 5360960 + 8023680 = 13384640 -> 53.5 MB

// ---- fp16 pool layout (half offsets, all mult of 8) ----
#define H_CX    0            // 60*17760   = 1065600 (znormed cell_exprs, K-pad)
#define H_DF    1065600      // 952*896    = 852992  (drug_finger, K-pad)
#define H_LDW   1918592      // 2040*896   = 1827840 (ldd_w, K-pad)
#define H_ALC   3746432      // 60*960     = 57600   (dx.*adj.*dy)
#define H_ALD   3804032      // 952*64     = 60928   (dy.*adjT.*dx)
#define H_CH    3864960      // 60*64      = 3840
#define H_CHS   3868800      // 60*64      = 3840    (b4h.*CH.*b4h)
#define H_DH    3872640      // 952*960    = 913920
#define H_DHS   4786560      // 952*960    = 913920  (a4h.*DH.*a4h)
#define H_FIGT  5700480      // 2040*960   = 1958400 (fig^T, pad)
#define H_EXPT  7658880      // 2040*64    = 130560  (exp^T, pad)
#define H_XC    7789440      // 60*8160    = 489600
#define H_XD    8279040      // 952*8160   = 7768320 -> end 16047360 halves

// ---- transient slab regions (aliasing dead h16 ranges; float offsets) ----
// O_PS2: 40 slabs for step-4 splitK. Aliases h16 range H_FIGT..(written at
//        step 6+), free during step 4.  5360960 + 5700480/2 = 8211200.
#define O_PS2   8211200      // 40*122400 = 4896000 -> end 13107200 (< 13384640)
// O_PS2B: 6 extra slabs for step-10. Aliases h16 range H_CX..H_LDW (dead
//        after step 5). float offset = O_H16.
#define O_PS2B  5360960      // 6*122400 = 734400 -> end 6095360 (< 7234176)

#define EXP_KW   444
#define EXP_NWIN 40          // 40*444 = 17760 = padded K

typedef _Float16 f16;
typedef __attribute__((ext_vector_type(8))) _Float16 f16x8;
typedef __attribute__((ext_vector_type(4))) float f32x4;

struct Job {
    int aoff[16]; int boff[16]; int lda[16]; int ldb[16];
    int len[16]; int blim[16]; int coff[16]; int bflag[16];
    float rsg[16];
};

__device__ __forceinline__ float blockReduceSum(float v, float* red) {
    const int t = threadIdx.x;
    red[t] = v;
    __syncthreads();
    for (int off = 128; off > 0; off >>= 1) {
        if (t < off) red[t] += red[t + off];
        __syncthreads();
    }
    float r = red[0];
    __syncthreads();
    return r;
}

// ---- scalars: dx/dc/dy/ddv, b4h, a4h ----
__global__ __launch_bounds__(256) void k_pre(
    const float* __restrict__ adj, const float* __restrict__ ch,
    const float* __restrict__ dh, float* __restrict__ ws)
{
    __shared__ float red[256];
    const int b = blockIdx.x, t = threadIdx.x;
    if (b < NC) {
        const int c = b;
        float s = 0.f;
        for (int j = t; j < ND; j += 256) s += adj[c * ND + j];
        float rs = blockReduceSum(s, red) + 1.f;
        if (t == 0) { ws[O_DX + c] = rsqrtf(rs); ws[O_DC + c] = 1.f / rs + 1.f; }
        float s2 = (t < NC) ? ch[c * NC + t] : 0.f;
        float hs = blockReduceSum(s2, red) + 1.f;
        if (t == 0) ws[O_B4H + c] = 1.f / hs;
    } else {
        const int i = b - NC;
        float s = 0.f;
        for (int j = t; j < ND; j += 256) s += dh[i * ND + j];
        float hs = blockReduceSum(s, red) + 1.f;
        if (t == 0) ws[O_A4H + i] = 1.f / hs;
        float s2 = (t < NC) ? adj[t * ND + i] : 0.f;
        float cs = blockReduceSum(s2, red) + 1.f;
        if (t == 0) { ws[O_DY + i] = rsqrtf(cs); ws[O_DDV + i] = 1.f / cs + 1.f; }
    }
}

// ---- z-norm stats per cell row ----
__global__ __launch_bounds__(256) void k_zstats(
    const float* __restrict__ x, float* __restrict__ ws)
{
    __shared__ float r1[256];
    __shared__ float r2[256];
    const int c = blockIdx.x, t = threadIdx.x;
    const float* row = x + c * NG;
    float s = 0.f, q = 0.f;
    for (int j = t; j < NG; j += 256) { float v = row[j]; s += v; q += v * v; }
    r1[t] = s; r2[t] = q;
    __syncthreads();
    for (int off = 128; off > 0; off >>= 1) {
        if (t < off) { r1[t] += r1[t + off]; r2[t] += r2[t + off]; }
        __syncthreads();
    }
    if (t == 0) {
        const float mu = r1[0] / (float)NG;
        const float var = (r2[0] - (float)NG * mu * mu) / (float)(NG - 1);
        const float inv = rsqrtf(var);
        ws[O_ZSC + c] = inv;
        ws[O_ZSH + c] = -mu * inv;
    }
}

// ---- convert/pad/scale-fold all small fp16 operands in one pass ----
#define CVT_TOT 5700480
__global__ __launch_bounds__(256) void k_cvt(
    const float* __restrict__ ce, const float* __restrict__ dfing,
    const float* __restrict__ ldw, const float* __restrict__ adj,
    const float* __restrict__ chyp, const float* __restrict__ dhyp,
    const float* __restrict__ ws, f16* __restrict__ h16)
{
    const float* dx = ws + O_DX;
    const float* dy = ws + O_DY;
    const float* b4h = ws + O_B4H;
    const float* a4h = ws + O_A4H;
    const float* zsc = ws + O_ZSC;
    const float* zsh = ws + O_ZSH;
    for (int idx = blockIdx.x * 256 + threadIdx.x; idx < CVT_TOT;
         idx += gridDim.x * 256) {
        float v = 0.f;
        if (idx < H_DF) {                     // cx16: znormed cell_exprs
            const int c = idx / 17760, k = idx % 17760;
            if (k < NG) v = ce[c * NG + k] * zsc[c] + zsh[c];
        } else if (idx < H_LDW) {             // df16
            const int j = idx - H_DF;
            const int i = j / 896, k = j % 896;
            if (k < NF) v = dfing[i * NF + k];
        } else if (idx < H_ALC) {             // ldw16
            const int j = idx - H_LDW;
            const int d = j / 896, k = j % 896;
            if (k < NF) v = ldw[d * NF + k];
        } else if (idx < H_ALD) {             // aggLc
            const int j = idx - H_ALC;
            const int c = j / 960, i = j % 960;
            if (i < ND) v = dx[c] * adj[c * ND + i] * dy[i];
        } else if (idx < H_CH) {              // aggLd
            const int j = idx - H_ALD;
            const int i = j / 64, c = j % 64;
            if (c < NC) v = dy[i] * adj[c * ND + i] * dx[c];
        } else if (idx < H_CHS) {             // ch16
            const int j = idx - H_CH;
            const int c = j / 64, k = j % 64;
            if (k < NC) v = chyp[c * NC + k];
        } else if (idx < H_DH) {              // chs16
            const int j = idx - H_CHS;
            const int c = j / 64, k = j % 64;
            if (k < NC) v = b4h[c] * chyp[c * NC + k] * b4h[k];
        } else if (idx < H_DHS) {             // dh16
            const int j = idx - H_DH;
            const int i = j / 960, k = j % 960;
            if (k < ND) v = dhyp[i * ND + k];
        } else {                              // dhs16
            const int j = idx - H_DHS;
            const int i = j / 960, k = j % 960;
            if (k < ND) v = a4h[i] * dhyp[i * ND + k] * a4h[k];
        }
        h16[idx] = (f16)v;
    }
}

// ============================================================================
// Dedicated split-K GEMM for step 4:  exp = cx16 @ lcc_w^T.
//   M=60(N C), N=2040(DE), K=17737 (padded 17760), fp32 B streamed with
//   fully-coalesced 128B row segments (32 lanes read 32 consecutive floats).
//   grid = (DE/64, 1, 40 windows of 444).  Partial sums -> O_PS2 slabs.
// ============================================================================
__global__ __launch_bounds__(256) void k_gemm_exp(
    const f16* __restrict__ Ah,      // h16 (cx16 at H_CX=0), lda 17760
    const float* __restrict__ B,     // lcc_w [DE, NG]
    float* __restrict__ ws)
{
    constexpr int BM = 64, BN = 64;
    constexpr int PSA = BM * 8 + 8;
    constexpr int PSB = BN * 8 + 8;
    __shared__ __align__(16) unsigned short As[4 * PSA];
    __shared__ __align__(16) unsigned short Bs[4 * PSB];
    const int t = threadIdx.x;
    const int wv = t >> 6, ln = t & 63;
    const int wm = wv >> 1, wn = wv & 1;
    const int kg = ln >> 4, lm = ln & 15;
    const int n0 = blockIdx.x * BN;
    const int z = blockIdx.z;
    const int kbase = z * EXP_KW;
    const int blim = (NG - kbase < EXP_KW) ? (NG - kbase) : EXP_KW;

    f32x4 acc[2][2];
#pragma unroll
    for (int i = 0; i < 2; ++i)
#pragma unroll
        for (int j = 0; j < 2; ++j) acc[i][j] = (f32x4){0.f, 0.f, 0.f, 0.f};

    // B-stage thread mapping: half-wave (32 lanes) = 32 consecutive k cols
    const int brow_l = t >> 5;        // 0..7
    const int bcol   = t & 31;        // 0..31
    const int bkc    = bcol >> 3, bke = bcol & 7;
    f16* BsH = (f16*)Bs;

    for (int kb = 0; kb < EXP_KW; kb += 32) {
        // ---- stage A (64 x 32 halves): 1 uint4 per thread ----
        {
            const int m = t >> 2, kc = t & 3;
            const int k0 = kb + kc * 8;
            uint4 d = {0u, 0u, 0u, 0u};
            if (m < NC && k0 < EXP_KW)
                d = *(const uint4*)(Ah + kbase + m * 17760 + k0);
            *(uint4*)&As[kc * PSA + m * 8] = d;
        }
        // ---- stage B (64 rows x 32 cols fp32, coalesced 128B/half-wave) ----
        {
            const int col = kb + bcol;                // col within window
            const bool cok = col < blim;
#pragma unroll
            for (int e = 0; e < 8; ++e) {
                const int n = brow_l + e * 8;         // 0..63
                const int gn = n0 + n;
                float v = 0.f;
                if (cok && gn < DE) v = B[gn * NG + kbase + col];
                BsH[bkc * PSB + n * 8 + bke] = (f16)v;
            }
        }
        __syncthreads();
        f16x8 af[2], bfr[2];
#pragma unroll
        for (int i = 0; i < 2; ++i)
            af[i] = *(f16x8*)&As[kg * PSA + (wm * 32 + i * 16 + lm) * 8];
#pragma unroll
        for (int j = 0; j < 2; ++j)
            bfr[j] = *(f16x8*)&Bs[kg * PSB + (wn * 32 + j * 16 + lm) * 8];
#pragma unroll
        for (int i = 0; i < 2; ++i)
#pragma unroll
            for (int j = 0; j < 2; ++j)
                acc[i][j] = __builtin_amdgcn_mfma_f32_16x16x32_f16(
                    af[i], bfr[j], acc[i][j], 0, 0, 0);
        __syncthreads();
    }
    // ---- epilogue: partial slab z ----
    float* P = ws + O_PS2 + z * (NC * DE);
#pragma unroll
    for (int i = 0; i < 2; ++i) {
        const int mb = wm * 32 + i * 16 + kg * 4;
#pragma unroll
        for (int r = 0; r < 4; ++r) {
            const int m = mb + r;
            if (m >= NC) continue;
#pragma unroll
            for (int j = 0; j < 2; ++j) {
                const int n = n0 + wn * 32 + j * 16 + lm;
                if (n >= DE) continue;
                P[m * DE + n] = acc[i][j][r];
            }
        }
    }
}

// ============================================================================
// Unified fp16 MFMA NT GEMM with job table.
//   acc[m,n] = sum over windows of A16[m,k] * B[n,k]
//   BMODE: 0 = B fp16 (aligned), 1 = B fp32 aligned (uint4), 2 = B fp32
//          unaligned/scalar with real-K limit blim.
//   partial=1: blockIdx.z picks one job; else loop jobs 0..nwin-1.
//   Epilogue: v = rsg*acc (+ base[m,n] if bflag); store fp32 (ws+coff) or
//   fp16 (h16+coff) per F16OUT. Deterministic, no atomics.
// Tile BMxBN, 4 waves 2x2, KT=32, 16x16x32 f16 MFMA.
// ============================================================================
template<int BM, int BN, int BMODE, int F16OUT>
__global__ __launch_bounds__(256) void k_fgemm(
    const f16* __restrict__ Ah, const void* __restrict__ Bp,
    float* __restrict__ ws, f16* __restrict__ h16,
    const float* __restrict__ basep, int baseld,
    int M, int N, int ldc, int nwin, int partial, Job jb)
{
    constexpr int PSA = BM * 8 + 8;
    constexpr int PSB = BN * 8 + 8;
    constexpr int MI = BM / 32;
    constexpr int NI = BN / 32;
    __shared__ __align__(16) unsigned short As[4 * PSA];
    __shared__ __align__(16) unsigned short Bs[4 * PSB];
    const int t = threadIdx.x;
    const int wv = t >> 6, ln = t & 63;
    const int wm = wv >> 1, wn = wv & 1;
    const int kg = ln >> 4, lm = ln & 15;
    const int m0 = blockIdx.y * BM;
    const int n0 = blockIdx.x * BN;

    f32x4 acc[MI][NI];
#pragma unroll
    for (int i = 0; i < MI; ++i)
#pragma unroll
        for (int j = 0; j < NI; ++j) acc[i][j] = (f32x4){0.f, 0.f, 0.f, 0.f};

    const int z0 = partial ? (int)blockIdx.z : 0;
    const int z1 = partial ? (int)blockIdx.z + 1 : nwin;

    for (int zi = z0; zi < z1; ++zi) {
        const int Ab = jb.aoff[zi], Bb = jb.boff[zi];
        const int lda = jb.lda[zi], ldb = jb.ldb[zi];
        const int len = jb.len[zi], bl = jb.blim[zi];
        for (int kb = 0; kb < len; kb += 32) {
            // ---- stage A (BM x 32 halves), uint4 chunks of 8 halves ----
#pragma unroll
            for (int p = 0; p < (BM * 4) / 256; ++p) {
                const int ci = p * 256 + t;
                const int m = ci >> 2, kc = ci & 3;
                const int k0 = kb + kc * 8;
                uint4 d = {0u, 0u, 0u, 0u};
                if (m0 + m < M && k0 < len)
                    d = *(const uint4*)(Ah + Ab + (m0 + m) * lda + k0);
                *(uint4*)&As[kc * PSA + m * 8] = d;
            }
            // ---- stage B (BN x 32) ----
#pragma unroll
            for (int p = 0; p < (BN * 4) / 256; ++p) {
                const int ci = p * 256 + t;
                const int n = ci >> 2, kc = ci & 3;
                const int k0 = kb + kc * 8;
                const bool ok = (n0 + n < N) && (k0 < len);
                if (BMODE == 0) {
                    uint4 d = {0u, 0u, 0u, 0u};
                    if (ok) d = *(const uint4*)((const f16*)Bp + Bb + (n0 + n) * ldb + k0);
                    *(uint4*)&Bs[kc * PSB + n * 8] = d;
                } else if (BMODE == 1) {
                    f16x8 pk = (f16x8)(f16)0.f;
                    if (ok) {
                        const float* bq = (const float*)Bp + Bb + (n0 + n) * ldb + k0;
                        const float4 x = *(const float4*)bq;
                        const float4 y = *(const float4*)(bq + 4);
                        pk[0] = (f16)x.x; pk[1] = (f16)x.y; pk[2] = (f16)x.z; pk[3] = (f16)x.w;
                        pk[4] = (f16)y.x; pk[5] = (f16)y.y; pk[6] = (f16)y.z; pk[7] = (f16)y.w;
                    }
                    *(f16x8*)&Bs[kc * PSB + n * 8] = pk;
                } else {
                    f16x8 pk = (f16x8)(f16)0.f;
                    if (n0 + n < N) {
                        const float* bq = (const float*)Bp + Bb + (n0 + n) * ldb + k0;
#pragma unroll
                        for (int e = 0; e < 8; ++e)
                            if (k0 + e < bl) pk[e] = (f16)bq[e];
                    }
                    *(f16x8*)&Bs[kc * PSB + n * 8] = pk;
                }
            }
            __syncthreads();
            f16x8 af[MI], bfr[NI];
#pragma unroll
            for (int i = 0; i < MI; ++i)
                af[i] = *(f16x8*)&As[kg * PSA + (wm * (BM / 2) + i * 16 + lm) * 8];
#pragma unroll
            for (int j = 0; j < NI; ++j)
                bfr[j] = *(f16x8*)&Bs[kg * PSB + (wn * (BN / 2) + j * 16 + lm) * 8];
#pragma unroll
            for (int i = 0; i < MI; ++i)
#pragma unroll
                for (int j = 0; j < NI; ++j)
                    acc[i][j] = __builtin_amdgcn_mfma_f32_16x16x32_f16(
                        af[i], bfr[j], acc[i][j], 0, 0, 0);
            __syncthreads();
        }
    }
    // ---- epilogue ----
    const int zz = partial ? (int)blockIdx.z : 0;
    const float rs = jb.rsg[zz];
    const int co = jb.coff[zz];
    const int bfl = jb.bflag[zz];
#pragma unroll
    for (int i = 0; i < MI; ++i) {
        const int mb = m0 + wm * (BM / 2) + i * 16 + kg * 4;
#pragma unroll
        for (int r = 0; r < 4; ++r) {
            const int m = mb + r;
            if (m >= M) continue;
#pragma unroll
            for (int j = 0; j < NI; ++j) {
                const int n = n0 + wn * (BN / 2) + j * 16 + lm;
                if (n >= N) continue;
                float v = rs * acc[i][j][r];
                if (bfl) v += basep[m * baseld + n];
                if (F16OUT) h16[co + m * ldc + n] = (f16)v;
                else        ws[co + m * ldc + n] = v;
            }
        }
    }
}

// ---- fixed-order reduction of Z partial slabs ----
__global__ __launch_bounds__(256) void k_reduce(
    const float* __restrict__ P, float* __restrict__ out, int Z, int slab, int n)
{
    const int i = blockIdx.x * 256 + threadIdx.x;
    if (i < n) {
        float s = 0.f;
        for (int z = 0; z < Z; ++z) s += P[z * slab + i];
        out[i] = s;
    }
}

// ---- fixed-order reduction over two slab regions ----
__global__ __launch_bounds__(256) void k_reduce2(
    const float* __restrict__ P1, int Z1, const float* __restrict__ P2, int Z2,
    float* __restrict__ out, int slab, int n)
{
    const int i = blockIdx.x * 256 + threadIdx.x;
    if (i < n) {
        float s = 0.f;
        for (int z = 0; z < Z1; ++z) s += P1[z * slab + i];
        for (int z = 0; z < Z2; ++z) s += P2[z * slab + i];
        out[i] = s;
    }
}

// ---- BatchNorm (train stats): one block per column, register-resident ----
__global__ __launch_bounds__(256) void k_bn2(
    float* __restrict__ ws, f16* __restrict__ h16,
    const float* __restrict__ cg, const float* __restrict__ cb,
    const float* __restrict__ dg, const float* __restrict__ db)
{
    __shared__ float r1[256];
    __shared__ float r2[256];
    const int id = blockIdx.x, t = threadIdx.x;
    float* X; f16* T; const float* g; const float* b; int R, Rp, ldT, d;
    if (id < DE) { d = id; X = ws + O_EMBC; T = h16 + H_EXPT; g = cg; b = cb; R = NC; Rp = 64; ldT = 64; }
    else { d = id - DE; X = ws + O_EMBD; T = h16 + H_FIGT; g = dg; b = db; R = ND; Rp = 960; ldT = 960; }
    float vals[4];
    float s = 0.f, q = 0.f;
#pragma unroll
    for (int v = 0; v < 4; ++v) {
        const int r = t + v * 256;
        float x = 0.f;
        if (r < R) x = X[r * DE + d];
        vals[v] = x;
        s += x; q += x * x;
    }
    r1[t] = s; r2[t] = q;
    __syncthreads();
    for (int off = 128; off > 0; off >>= 1) {
        if (t < off) { r1[t] += r1[t + off]; r2[t] += r2[t + off]; }
        __syncthreads();
    }
    const float mu = r1[0] / (float)R;
    float var = r2[0] / (float)R - mu * mu;
    var = fmaxf(var, 0.f);
    const float sc = rsqrtf(var + EPS_BN) * g[d];
    const float sh = b[d] - mu * sc;
#pragma unroll
    for (int v = 0; v < 4; ++v) {
        const int r = t + v * 256;
        if (r < R) {
            const float y = vals[v] * sc + sh;
            X[r * DE + d] = y;
            T[d * ldT + r] = (f16)y;
        } else if (r < Rp) {
            T[d * ldT + r] = (f16)0.f;
        }
    }
}

// ---- Xc/Xd block0 = diag-scaled emb (fp16) ----
__global__ __launch_bounds__(256) void k_buildX(
    const float* __restrict__ ws, f16* __restrict__ h16)
{
    const int idx = blockIdx.x * 256 + threadIdx.x;
    if (idx < NC * DE) {
        const int c = idx / DE, d = idx % DE;
        h16[H_XC + c * (4 * DE) + d] = (f16)(ws[O_DC + c] * ws[O_EMBC + idx]);
    } else if (idx < (NC + ND) * DE) {
        const int k = idx - NC * DE;
        const int i = k / DE, d = k % DE;
        h16[H_XD + i * (4 * DE) + d] = (f16)(ws[O_DDV + i] * ws[O_EMBD + k]);
    }
}

// ---- epilogue: agg = relu((sum + bias)*(emb+1)) in-place ----
__global__ __launch_bounds__(256) void k_epi(
    float* __restrict__ ws, const float* __restrict__ b_agg)
{
    const int idx = blockIdx.x * 256 + threadIdx.x;
    if (idx < NC * DE) {
        const int d = idx % DE;
        const float bc = b_agg[0 * DE + d] + b_agg[1 * DE + d] + b_agg[4 * DE + d] + b_agg[6 * DE + d];
        const float v = (ws[O_CSUM + idx] + bc) * (ws[O_EMBC + idx] + 1.f);
        ws[O_CSUM + idx] = fmaxf(v, 0.f);
    } else if (idx < (NC + ND) * DE) {
        const int k = idx - NC * DE;
        const int d = k % DE;
        const float bd = b_agg[2 * DE + d] + b_agg[3 * DE + d] + b_agg[5 * DE + d] + b_agg[7 * DE + d];
        const float v = (ws[O_DSUM + k] + bd) * (ws[O_EMBD + k] + 1.f);
        ws[O_DSUM + k] = fmaxf(v, 0.f);
    }
}

// ---- per-row mean + 1/||x-mu|| ----
__global__ __launch_bounds__(256) void k_rowstats(float* __restrict__ ws)
{
    __shared__ float red[256];
    const int b = blockIdx.x, t = threadIdx.x;
    const float* row;
    int omu, ois;
    if (b < NC) { row = ws + O_CSUM + b * DE; omu = O_CMU + b; ois = O_CIS + b; }
    else { const int i = b - NC; row = ws + O_DSUM + i * DE; omu = O_DMU + i; ois = O_DIS + i; }
    float s = 0.f;
    for (int j = t; j < DE; j += 256) s += row[j];
    const float mu = blockReduceSum(s, red) / (float)DE;
    float q = 0.f;
    for (int j = t; j < DE; j += 256) { const float v = row[j] - mu; q += v * v; }
    const float ss = blockReduceSum(q, red);
    if (t == 0) { ws[omu] = mu; ws[ois] = rsqrtf(ss); }
}

// ---- corr + sigmoid ----
__global__ __launch_bounds__(256) void k_corr(
    const float* __restrict__ ws, float* __restrict__ out)
{
    const int KT = 32;
    __shared__ float xs[16][KT + 1];
    __shared__ float ys[16][KT + 1];
    const int t = threadIdx.x;
    const int tcr = t >> 4, ti = t & 15;
    const int c0 = blockIdx.y * 16, i0 = blockIdx.x * 16;
    float acc = 0.f;
    for (int kb = 0; kb < DE; kb += KT) {
#pragma unroll
        for (int q = 0; q < 2; ++q) {
            const int s = q * 256 + t;
            const int row = s >> 5, kk = s & 31;
            const int k = kb + kk;
            const int c = c0 + row;
            xs[row][kk] = (c < NC && k < DE) ? ws[O_CSUM + c * DE + k] : 0.f;
            const int i = i0 + row;
            ys[row][kk] = (i < ND && k < DE) ? ws[O_DSUM + i * DE + k] : 0.f;
        }
        __syncthreads();
#pragma unroll
        for (int kt = 0; kt < KT; ++kt) acc += xs[tcr][kt] * ys[ti][kt];
        __syncthreads();
    }
    const int c = c0 + tcr, i = i0 + ti;
    if (c < NC && i < ND) {
        const float num = acc - (float)DE * ws[O_CMU + c] * ws[O_DMU + i];
        const float corr = num * ws[O_CIS + c] * ws[O_DIS + i];
        out[c * ND + i] = 1.f / (1.f + expf(-GAMMA_C * corr));
    }
}

static inline void jclear(Job& j) {
    for (int z = 0; z < 16; ++z) {
        j.aoff[z] = j.boff[z] = j.lda[z] = j.ldb[z] = 0;
        j.len[z] = j.blim[z] = j.coff[z] = j.bflag[z] = 0;
        j.rsg[z] = 1.f;
    }
}

extern "C" void kernel_launch(void* const* d_in, const int* in_sizes, int n_in,
                              void* d_out, int out_size, void* d_ws, size_t ws_size,
                              hipStream_t stream)
{
    const float* adj         = (const float*)d_in[0];
    const float* cell_exprs  = (const float*)d_in[1];
    const float* drug_finger = (const float*)d_in[2];
    const float* cell_hyper  = (const float*)d_in[3];
    const float* drug_hyper  = (const float*)d_in[4];
    const float* W_agg       = (const float*)d_in[5];
    const float* b_agg       = (const float*)d_in[6];
    const float* ldd_w       = (const float*)d_in[7];
    const float* lcc_w       = (const float*)d_in[9];
    const float* bnd_g       = (const float*)d_in[11];
    const float* bnd_b       = (const float*)d_in[12];
    const float* bnc_g       = (const float*)d_in[13];
    const float* bnc_b       = (const float*)d_in[14];
    float* ws  = (float*)d_ws;
    float* out = (float*)d_out;
    f16* h16 = (f16*)(ws + O_H16);

    // 1) scalars
    k_pre<<<NC + ND, 256, 0, stream>>>(adj, cell_hyper, drug_hyper, ws);
    // 2) z-norm stats
    k_zstats<<<NC, 256, 0, stream>>>(cell_exprs, ws);
    // 3) fp16 operand pool (scale-folded, padded)
    k_cvt<<<2048, 256, 0, stream>>>(cell_exprs, drug_finger, ldd_w, adj,
                                    cell_hyper, drug_hyper, ws, h16);

    // 4) exp = cx16 @ lcc_w^T — dedicated split-K (40 windows x 32 n-blocks)
    //    slabs in O_PS2 (aliases h16 H_FIGT.., free until step 6)
    k_gemm_exp<<<dim3(32, 1, EXP_NWIN), 256, 0, stream>>>(h16, lcc_w, ws);
    k_reduce<<<479, 256, 0, stream>>>(ws + O_PS2, ws + O_EMBC, EXP_NWIN,
                                      NC * DE, NC * DE);

    // 5) fig = df16 @ ldw16^T (K=896) -> embD direct
    {
        Job j; jclear(j);
        j.aoff[0] = H_DF; j.lda[0] = 896;
        j.boff[0] = H_LDW; j.ldb[0] = 896;
        j.len[0] = 896; j.coff[0] = O_EMBD;
        k_fgemm<64, 128, 0, 0><<<dim3(16, 15, 1), 256, 0, stream>>>(
            h16, h16, ws, h16, nullptr, 0, ND, DE, DE, 1, 0, j);
    }
    // 6) BN (in-place fp32) + expT16/figT16 — one block per column
    k_bn2<<<2 * DE, 256, 0, stream>>>(ws, h16, bnc_g, bnc_b, bnd_g, bnd_b);
    // 7) Xc/Xd block0
    k_buildX<<<8065, 256, 0, stream>>>(ws, h16);

    // 8) cell X-jobs: X1 / X4 / X6 in one launch
    {
        Job j; jclear(j);
        j.aoff[0] = H_ALC; j.lda[0] = 960; j.boff[0] = H_FIGT; j.ldb[0] = 960;
        j.len[0] = 960; j.coff[0] = H_XC + DE;
        j.aoff[1] = H_CH; j.lda[1] = 64; j.boff[1] = H_EXPT; j.ldb[1] = 64;
        j.len[1] = 64; j.coff[1] = H_XC + 2 * DE;
        j.aoff[2] = H_CHS; j.lda[2] = 64; j.boff[2] = H_EXPT; j.ldb[2] = 64;
        j.len[2] = 64; j.coff[2] = H_XC + 3 * DE; j.rsg[2] = -1.f; j.bflag[2] = 1;
        k_fgemm<64, 128, 0, 1><<<dim3(16, 1, 3), 256, 0, stream>>>(
            h16, h16, ws, h16, ws + O_EMBC, DE, NC, DE, 4 * DE, 3, 1, j);
    }
    // 9) drug X-jobs: X3 / X5 / X7 in one launch
    {
        Job j; jclear(j);
        j.aoff[0] = H_ALD; j.lda[0] = 64; j.boff[0] = H_EXPT; j.ldb[0] = 64;
        j.len[0] = 64; j.coff[0] = H_XD + DE;
        j.aoff[1] = H_DH; j.lda[1] = 960; j.boff[1] = H_FIGT; j.ldb[1] = 960;
        j.len[1] = 960; j.coff[1] = H_XD + 2 * DE;
        j.aoff[2] = H_DHS; j.lda[2] = 960; j.boff[2] = H_FIGT; j.ldb[2] = 960;
        j.len[2] = 960; j.coff[2] = H_XD + 3 * DE; j.rsg[2] = -1.f; j.bflag[2] = 1;
        k_fgemm<128, 128, 0, 1><<<dim3(16, 8, 3), 256, 0, stream>>>(
            h16, h16, ws, h16, ws + O_EMBD, DE, ND, DE, 4 * DE, 3, 1, j);
    }
    // 10) cell main: Xc16 @ [W0|W1|W4|W6]^T — 16 windows, BN=64, 2-region slabs
    {
        const int permc[4] = {0, 1, 4, 6};
        const int ko[4] = {0, 512, 1024, 1536};
        const int kl[4] = {512, 512, 512, 504};
        Job j; jclear(j);
        for (int z = 0; z < 16; ++z) {
            const int ib = z >> 2, sub = z & 3;
            j.aoff[z] = H_XC + ib * DE + ko[sub]; j.lda[z] = 4 * DE;
            j.boff[z] = permc[ib] * DE * DE + ko[sub]; j.ldb[z] = DE;
            j.len[z] = kl[sub];
            j.coff[z] = (z < 10) ? (O_PS + z * (NC * DE))
                                 : (O_PS2B + (z - 10) * (NC * DE));
        }
        k_fgemm<64, 64, 1, 0><<<dim3(32, 1, 16), 256, 0, stream>>>(
            h16, W_agg, ws, h16, nullptr, 0, NC, DE, DE, 16, 1, j);
        k_reduce2<<<479, 256, 0, stream>>>(ws + O_PS, 10, ws + O_PS2B, 6,
                                           ws + O_CSUM, NC * DE, NC * DE);
    }
    // 11) drug main: Xd16 @ [W2|W3|W5|W7]^T (4 windows in-loop) -> dsum
    {
        const int permd[4] = {2, 3, 5, 7};
        Job j; jclear(j);
        for (int z = 0; z < 4; ++z) {
            j.aoff[z] = H_XD + z * DE; j.lda[z] = 4 * DE;
            j.boff[z] = permd[z] * DE * DE; j.ldb[z] = DE;
            j.len[z] = DE;
        }
        j.coff[0] = O_DSUM;
        k_fgemm<128, 64, 1, 0><<<dim3(32, 8, 1), 256, 0, stream>>>(
            h16, W_agg, ws, h16, nullptr, 0, ND, DE, DE, 4, 0, j);
    }

    // 12) epilogue, stats, corr
    k_epi<<<8065, 256, 0, stream>>>(ws, b_agg);
    k_rowstats<<<NC + ND, 256, 0, stream>>>(ws);
    k_corr<<<dim3(60, 4), 256, 0, stream>>>(ws, out);

    (void)in_sizes; (void)n_in; (void)out_size; (void)ws_size;
}

// Round 3
// 852.874 us; speedup vs baseline: 2.0562x; 1.1669x over previous
//
#include <hip/hip_runtime.h>
#include <math.h>

#define NC 60
#define ND 952
#define DE 2040
#define NG 17737
#define NF 881
#define GAMMA_C 8.7f
#define EPS_BN 1e-5f

// ---- fp32 workspace layout (float offsets) ----
#define O_DX      0
#define O_DC      64
#define O_DY      128
#define O_DDV     1088
#define O_B4H     2048
#define O_A4H     2112
#define O_CMU     3072
#define O_CIS     3136
#define O_DMU     3200
#define O_DIS     4160
#define O_ZSC     5120
#define O_ZSH     5184
#define O_EMBC    8000       // 60*2040   = 122400
#define O_EMBD    130400     // 952*2040  = 1942080
#define O_CSUM    2072480    // 122400
#define O_DSUM    2194880    // 1942080
#define O_PS      4136960    // 10*122400 = 1224000 (slabs, reused)
#define O_H16     5360960    // fp16 pool starts here (float offset, 16B aligned)
// total floats: 5360960 + 8023680 = 13384640 -> 53.5 MB

// ---- fp16 pool layout (half offsets, all mult of 8) ----
#define H_CX    0            // 60*17760   = 1065600 (znormed cell_exprs, K-pad)
#define H_DF    1065600      // 952*896    = 852992  (drug_finger, K-pad)
#define H_LDW   1918592      // 2040*896   = 1827840 (ldd_w, K-pad)
#define H_ALC   3746432      // 60*960     = 57600   (dx.*adj.*dy)
#define H_ALD   3804032      // 952*64     = 60928   (dy.*adjT.*dx)
#define H_CH    3864960      // 60*64      = 3840
#define H_CHS   3868800      // 60*64      = 3840    (b4h.*CH.*b4h)
#define H_DH    3872640      // 952*960    = 913920
#define H_DHS   4786560      // 952*960    = 913920  (a4h.*DH.*a4h)
#define H_FIGT  5700480      // 2040*960   = 1958400 (fig^T, pad)
#define H_EXPT  7658880      // 2040*64    = 130560  (exp^T, pad)
#define H_XC    7789440      // 60*8160    = 489600
#define H_XD    8279040      // 952*8160   = 7768320 -> end 16047360 halves

// ---- transient slab regions (aliasing dead h16 ranges; float offsets) ----
// O_PS2: 40 slabs for step-4 splitK. Aliases h16 H_FIGT.. (written step 6+).
#define O_PS2   8211200      // 40*122400 = 4896000 -> end 13107200 (< 13384640)
// O_PS2B: 6 extra slabs for step-10. Aliases h16 H_CX.. (dead after step 5).
#define O_PS2B  5360960      // 6*122400 = 734400 -> end 6095360
// O_SLABD: step-11 z=1 partial (W5+W7). Aliases h16 H_CX..H_DH-part; all
//   consumers of that range (steps 4,5,8,9,10 incl. reduce2) are stream-
//   ordered BEFORE step 11 writes. k_epi sums DSUM + SLABD.
#define O_SLABD 5360960      // 1942080 floats -> end 7303040

#define EXP_KW   444
#define EXP_NWIN 40          // 40*444 = 17760 = padded K

typedef _Float16 f16;
typedef __attribute__((ext_vector_type(8))) _Float16 f16x8;
typedef __attribute__((ext_vector_type(4))) float f32x4;

struct Job {
    int aoff[16]; int boff[16]; int lda[16]; int ldb[16];
    int len[16]; int blim[16]; int coff[16]; int bflag[16];
    float rsg[16];
};

__device__ __forceinline__ float blockReduceSum(float v, float* red) {
    const int t = threadIdx.x;
    red[t] = v;
    __syncthreads();
    for (int off = 128; off > 0; off >>= 1) {
        if (t < off) red[t] += red[t + off];
        __syncthreads();
    }
    float r = red[0];
    __syncthreads();
    return r;
}

// ---- scalars: dx/dc/dy/ddv, b4h, a4h ----
__global__ __launch_bounds__(256) void k_pre(
    const float* __restrict__ adj, const float* __restrict__ ch,
    const float* __restrict__ dh, float* __restrict__ ws)
{
    __shared__ float red[256];
    const int b = blockIdx.x, t = threadIdx.x;
    if (b < NC) {
        const int c = b;
        float s = 0.f;
        for (int j = t; j < ND; j += 256) s += adj[c * ND + j];
        float rs = blockReduceSum(s, red) + 1.f;
        if (t == 0) { ws[O_DX + c] = rsqrtf(rs); ws[O_DC + c] = 1.f / rs + 1.f; }
        float s2 = (t < NC) ? ch[c * NC + t] : 0.f;
        float hs = blockReduceSum(s2, red) + 1.f;
        if (t == 0) ws[O_B4H + c] = 1.f / hs;
    } else {
        const int i = b - NC;
        float s = 0.f;
        for (int j = t; j < ND; j += 256) s += dh[i * ND + j];
        float hs = blockReduceSum(s, red) + 1.f;
        if (t == 0) ws[O_A4H + i] = 1.f / hs;
        float s2 = (t < NC) ? adj[t * ND + i] : 0.f;
        float cs = blockReduceSum(s2, red) + 1.f;
        if (t == 0) { ws[O_DY + i] = rsqrtf(cs); ws[O_DDV + i] = 1.f / cs + 1.f; }
    }
}

// ---- z-norm stats per cell row ----
__global__ __launch_bounds__(256) void k_zstats(
    const float* __restrict__ x, float* __restrict__ ws)
{
    __shared__ float r1[256];
    __shared__ float r2[256];
    const int c = blockIdx.x, t = threadIdx.x;
    const float* row = x + c * NG;
    float s = 0.f, q = 0.f;
    for (int j = t; j < NG; j += 256) { float v = row[j]; s += v; q += v * v; }
    r1[t] = s; r2[t] = q;
    __syncthreads();
    for (int off = 128; off > 0; off >>= 1) {
        if (t < off) { r1[t] += r1[t + off]; r2[t] += r2[t + off]; }
        __syncthreads();
    }
    if (t == 0) {
        const float mu = r1[0] / (float)NG;
        const float var = (r2[0] - (float)NG * mu * mu) / (float)(NG - 1);
        const float inv = rsqrtf(var);
        ws[O_ZSC + c] = inv;
        ws[O_ZSH + c] = -mu * inv;
    }
}

// ---- convert/pad/scale-fold all small fp16 operands in one pass ----
#define CVT_TOT 5700480
__global__ __launch_bounds__(256) void k_cvt(
    const float* __restrict__ ce, const float* __restrict__ dfing,
    const float* __restrict__ ldw, const float* __restrict__ adj,
    const float* __restrict__ chyp, const float* __restrict__ dhyp,
    const float* __restrict__ ws, f16* __restrict__ h16)
{
    const float* dx = ws + O_DX;
    const float* dy = ws + O_DY;
    const float* b4h = ws + O_B4H;
    const float* a4h = ws + O_A4H;
    const float* zsc = ws + O_ZSC;
    const float* zsh = ws + O_ZSH;
    for (int idx = blockIdx.x * 256 + threadIdx.x; idx < CVT_TOT;
         idx += gridDim.x * 256) {
        float v = 0.f;
        if (idx < H_DF) {                     // cx16: znormed cell_exprs
            const int c = idx / 17760, k = idx % 17760;
            if (k < NG) v = ce[c * NG + k] * zsc[c] + zsh[c];
        } else if (idx < H_LDW) {             // df16
            const int j = idx - H_DF;
            const int i = j / 896, k = j % 896;
            if (k < NF) v = dfing[i * NF + k];
        } else if (idx < H_ALC) {             // ldw16
            const int j = idx - H_LDW;
            const int d = j / 896, k = j % 896;
            if (k < NF) v = ldw[d * NF + k];
        } else if (idx < H_ALD) {             // aggLc
            const int j = idx - H_ALC;
            const int c = j / 960, i = j % 960;
            if (i < ND) v = dx[c] * adj[c * ND + i] * dy[i];
        } else if (idx < H_CH) {              // aggLd
            const int j = idx - H_ALD;
            const int i = j / 64, c = j % 64;
            if (c < NC) v = dy[i] * adj[c * ND + i] * dx[c];
        } else if (idx < H_CHS) {             // ch16
            const int j = idx - H_CH;
            const int c = j / 64, k = j % 64;
            if (k < NC) v = chyp[c * NC + k];
        } else if (idx < H_DH) {              // chs16
            const int j = idx - H_CHS;
            const int c = j / 64, k = j % 64;
            if (k < NC) v = b4h[c] * chyp[c * NC + k] * b4h[k];
        } else if (idx < H_DHS) {             // dh16
            const int j = idx - H_DH;
            const int i = j / 960, k = j % 960;
            if (k < ND) v = dhyp[i * ND + k];
        } else {                              // dhs16
            const int j = idx - H_DHS;
            const int i = j / 960, k = j % 960;
            if (k < ND) v = a4h[i] * dhyp[i * ND + k] * a4h[k];
        }
        h16[idx] = (f16)v;
    }
}

// ============================================================================
// Dedicated split-K GEMM for step 4:  exp = cx16 @ lcc_w^T.
// ============================================================================
__global__ __launch_bounds__(256) void k_gemm_exp(
    const f16* __restrict__ Ah,      // h16 (cx16 at H_CX=0), lda 17760
    const float* __restrict__ B,     // lcc_w [DE, NG]
    float* __restrict__ ws)
{
    constexpr int BM = 64, BN = 64;
    constexpr int PSA = BM * 8 + 8;
    constexpr int PSB = BN * 8 + 8;
    __shared__ __align__(16) unsigned short As[4 * PSA];
    __shared__ __align__(16) unsigned short Bs[4 * PSB];
    const int t = threadIdx.x;
    const int wv = t >> 6, ln = t & 63;
    const int wm = wv >> 1, wn = wv & 1;
    const int kg = ln >> 4, lm = ln & 15;
    const int n0 = blockIdx.x * BN;
    const int z = blockIdx.z;
    const int kbase = z * EXP_KW;
    const int blim = (NG - kbase < EXP_KW) ? (NG - kbase) : EXP_KW;

    f32x4 acc[2][2];
#pragma unroll
    for (int i = 0; i < 2; ++i)
#pragma unroll
        for (int j = 0; j < 2; ++j) acc[i][j] = (f32x4){0.f, 0.f, 0.f, 0.f};

    const int brow_l = t >> 5;        // 0..7
    const int bcol   = t & 31;        // 0..31
    const int bkc    = bcol >> 3, bke = bcol & 7;
    f16* BsH = (f16*)Bs;

    for (int kb = 0; kb < EXP_KW; kb += 32) {
        {
            const int m = t >> 2, kc = t & 3;
            const int k0 = kb + kc * 8;
            uint4 d = {0u, 0u, 0u, 0u};
            if (m < NC && k0 < EXP_KW)
                d = *(const uint4*)(Ah + kbase + m * 17760 + k0);
            *(uint4*)&As[kc * PSA + m * 8] = d;
        }
        {
            const int col = kb + bcol;
            const bool cok = col < blim;
#pragma unroll
            for (int e = 0; e < 8; ++e) {
                const int n = brow_l + e * 8;
                const int gn = n0 + n;
                float v = 0.f;
                if (cok && gn < DE) v = B[gn * NG + kbase + col];
                BsH[bkc * PSB + n * 8 + bke] = (f16)v;
            }
        }
        __syncthreads();
        f16x8 af[2], bfr[2];
#pragma unroll
        for (int i = 0; i < 2; ++i)
            af[i] = *(f16x8*)&As[kg * PSA + (wm * 32 + i * 16 + lm) * 8];
#pragma unroll
        for (int j = 0; j < 2; ++j)
            bfr[j] = *(f16x8*)&Bs[kg * PSB + (wn * 32 + j * 16 + lm) * 8];
#pragma unroll
        for (int i = 0; i < 2; ++i)
#pragma unroll
            for (int j = 0; j < 2; ++j)
                acc[i][j] = __builtin_amdgcn_mfma_f32_16x16x32_f16(
                    af[i], bfr[j], acc[i][j], 0, 0, 0);
        __syncthreads();
    }
    float* P = ws + O_PS2 + z * (NC * DE);
#pragma unroll
    for (int i = 0; i < 2; ++i) {
        const int mb = wm * 32 + i * 16 + kg * 4;
#pragma unroll
        for (int r = 0; r < 4; ++r) {
            const int m = mb + r;
            if (m >= NC) continue;
#pragma unroll
            for (int j = 0; j < 2; ++j) {
                const int n = n0 + wn * 32 + j * 16 + lm;
                if (n >= DE) continue;
                P[m * DE + n] = acc[i][j][r];
            }
        }
    }
}

// ============================================================================
// Unified fp16 MFMA NT GEMM with job table.
//   jpz = jobs per blockIdx.z: 0 -> loop all nwin jobs (epilogue idx 0);
//   k>0 -> loop jobs [z*jpz, (z+1)*jpz), epilogue idx z*jpz.
// ============================================================================
template<int BM, int BN, int BMODE, int F16OUT>
__global__ __launch_bounds__(256) void k_fgemm(
    const f16* __restrict__ Ah, const void* __restrict__ Bp,
    float* __restrict__ ws, f16* __restrict__ h16,
    const float* __restrict__ basep, int baseld,
    int M, int N, int ldc, int nwin, int jpz, Job jb)
{
    constexpr int PSA = BM * 8 + 8;
    constexpr int PSB = BN * 8 + 8;
    constexpr int MI = BM / 32;
    constexpr int NI = BN / 32;
    __shared__ __align__(16) unsigned short As[4 * PSA];
    __shared__ __align__(16) unsigned short Bs[4 * PSB];
    const int t = threadIdx.x;
    const int wv = t >> 6, ln = t & 63;
    const int wm = wv >> 1, wn = wv & 1;
    const int kg = ln >> 4, lm = ln & 15;
    const int m0 = blockIdx.y * BM;
    const int n0 = blockIdx.x * BN;

    f32x4 acc[MI][NI];
#pragma unroll
    for (int i = 0; i < MI; ++i)
#pragma unroll
        for (int j = 0; j < NI; ++j) acc[i][j] = (f32x4){0.f, 0.f, 0.f, 0.f};

    const int z0 = jpz ? (int)blockIdx.z * jpz : 0;
    const int z1 = jpz ? z0 + jpz : nwin;

    for (int zi = z0; zi < z1; ++zi) {
        const int Ab = jb.aoff[zi], Bb = jb.boff[zi];
        const int lda = jb.lda[zi], ldb = jb.ldb[zi];
        const int len = jb.len[zi], bl = jb.blim[zi];
        for (int kb = 0; kb < len; kb += 32) {
            // ---- stage A (BM x 32 halves), uint4 chunks of 8 halves ----
#pragma unroll
            for (int p = 0; p < (BM * 4) / 256; ++p) {
                const int ci = p * 256 + t;
                const int m = ci >> 2, kc = ci & 3;
                const int k0 = kb + kc * 8;
                uint4 d = {0u, 0u, 0u, 0u};
                if (m0 + m < M && k0 < len)
                    d = *(const uint4*)(Ah + Ab + (m0 + m) * lda + k0);
                *(uint4*)&As[kc * PSA + m * 8] = d;
            }
            // ---- stage B (BN x 32) ----
#pragma unroll
            for (int p = 0; p < (BN * 4) / 256; ++p) {
                const int ci = p * 256 + t;
                const int n = ci >> 2, kc = ci & 3;
                const int k0 = kb + kc * 8;
                const bool ok = (n0 + n < N) && (k0 < len);
                if (BMODE == 0) {
                    uint4 d = {0u, 0u, 0u, 0u};
                    if (ok) d = *(const uint4*)((const f16*)Bp + Bb + (n0 + n) * ldb + k0);
                    *(uint4*)&Bs[kc * PSB + n * 8] = d;
                } else if (BMODE == 1) {
                    f16x8 pk = (f16x8)(f16)0.f;
                    if (ok) {
                        const float* bq = (const float*)Bp + Bb + (n0 + n) * ldb + k0;
                        const float4 x = *(const float4*)bq;
                        const float4 y = *(const float4*)(bq + 4);
                        pk[0] = (f16)x.x; pk[1] = (f16)x.y; pk[2] = (f16)x.z; pk[3] = (f16)x.w;
                        pk[4] = (f16)y.x; pk[5] = (f16)y.y; pk[6] = (f16)y.z; pk[7] = (f16)y.w;
                    }
                    *(f16x8*)&Bs[kc * PSB + n * 8] = pk;
                } else {
                    f16x8 pk = (f16x8)(f16)0.f;
                    if (n0 + n < N) {
                        const float* bq = (const float*)Bp + Bb + (n0 + n) * ldb + k0;
#pragma unroll
                        for (int e = 0; e < 8; ++e)
                            if (k0 + e < bl) pk[e] = (f16)bq[e];
                    }
                    *(f16x8*)&Bs[kc * PSB + n * 8] = pk;
                }
            }
            __syncthreads();
            f16x8 af[MI], bfr[NI];
#pragma unroll
            for (int i = 0; i < MI; ++i)
                af[i] = *(f16x8*)&As[kg * PSA + (wm * (BM / 2) + i * 16 + lm) * 8];
#pragma unroll
            for (int j = 0; j < NI; ++j)
                bfr[j] = *(f16x8*)&Bs[kg * PSB + (wn * (BN / 2) + j * 16 + lm) * 8];
#pragma unroll
            for (int i = 0; i < MI; ++i)
#pragma unroll
                for (int j = 0; j < NI; ++j)
                    acc[i][j] = __builtin_amdgcn_mfma_f32_16x16x32_f16(
                        af[i], bfr[j], acc[i][j], 0, 0, 0);
            __syncthreads();
        }
    }
    // ---- epilogue ----
    const int zz = z0;
    const float rs = jb.rsg[zz];
    const int co = jb.coff[zz];
    const int bfl = jb.bflag[zz];
#pragma unroll
    for (int i = 0; i < MI; ++i) {
        const int mb = m0 + wm * (BM / 2) + i * 16 + kg * 4;
#pragma unroll
        for (int r = 0; r < 4; ++r) {
            const int m = mb + r;
            if (m >= M) continue;
#pragma unroll
            for (int j = 0; j < NI; ++j) {
                const int n = n0 + wn * (BN / 2) + j * 16 + lm;
                if (n >= N) continue;
                float v = rs * acc[i][j][r];
                if (bfl) v += basep[m * baseld + n];
                if (F16OUT) h16[co + m * ldc + n] = (f16)v;
                else        ws[co + m * ldc + n] = v;
            }
        }
    }
}

// ---- fixed-order reduction of Z partial slabs ----
__global__ __launch_bounds__(256) void k_reduce(
    const float* __restrict__ P, float* __restrict__ out, int Z, int slab, int n)
{
    const int i = blockIdx.x * 256 + threadIdx.x;
    if (i < n) {
        float s = 0.f;
        for (int z = 0; z < Z; ++z) s += P[z * slab + i];
        out[i] = s;
    }
}

// ---- fixed-order reduction over two slab regions ----
__global__ __launch_bounds__(256) void k_reduce2(
    const float* __restrict__ P1, int Z1, const float* __restrict__ P2, int Z2,
    float* __restrict__ out, int slab, int n)
{
    const int i = blockIdx.x * 256 + threadIdx.x;
    if (i < n) {
        float s = 0.f;
        for (int z = 0; z < Z1; ++z) s += P1[z * slab + i];
        for (int z = 0; z < Z2; ++z) s += P2[z * slab + i];
        out[i] = s;
    }
}

// ---- BatchNorm (train stats): one block per column, register-resident ----
__global__ __launch_bounds__(256) void k_bn2(
    float* __restrict__ ws, f16* __restrict__ h16,
    const float* __restrict__ cg, const float* __restrict__ cb,
    const float* __restrict__ dg, const float* __restrict__ db)
{
    __shared__ float r1[256];
    __shared__ float r2[256];
    const int id = blockIdx.x, t = threadIdx.x;
    float* X; f16* T; const float* g; const float* b; int R, Rp, ldT, d;
    if (id < DE) { d = id; X = ws + O_EMBC; T = h16 + H_EXPT; g = cg; b = cb; R = NC; Rp = 64; ldT = 64; }
    else { d = id - DE; X = ws + O_EMBD; T = h16 + H_FIGT; g = dg; b = db; R = ND; Rp = 960; ldT = 960; }
    float vals[4];
    float s = 0.f, q = 0.f;
#pragma unroll
    for (int v = 0; v < 4; ++v) {
        const int r = t + v * 256;
        float x = 0.f;
        if (r < R) x = X[r * DE + d];
        vals[v] = x;
        s += x; q += x * x;
    }
    r1[t] = s; r2[t] = q;
    __syncthreads();
    for (int off = 128; off > 0; off >>= 1) {
        if (t < off) { r1[t] += r1[t + off]; r2[t] += r2[t + off]; }
        __syncthreads();
    }
    const float mu = r1[0] / (float)R;
    float var = r2[0] / (float)R - mu * mu;
    var = fmaxf(var, 0.f);
    const float sc = rsqrtf(var + EPS_BN) * g[d];
    const float sh = b[d] - mu * sc;
#pragma unroll
    for (int v = 0; v < 4; ++v) {
        const int r = t + v * 256;
        if (r < R) {
            const float y = vals[v] * sc + sh;
            X[r * DE + d] = y;
            T[d * ldT + r] = (f16)y;
        } else if (r < Rp) {
            T[d * ldT + r] = (f16)0.f;
        }
    }
}

// ---- Xc/Xd block0 = diag-scaled emb (fp16) ----
__global__ __launch_bounds__(256) void k_buildX(
    const float* __restrict__ ws, f16* __restrict__ h16)
{
    const int idx = blockIdx.x * 256 + threadIdx.x;
    if (idx < NC * DE) {
        const int c = idx / DE, d = idx % DE;
        h16[H_XC + c * (4 * DE) + d] = (f16)(ws[O_DC + c] * ws[O_EMBC + idx]);
    } else if (idx < (NC + ND) * DE) {
        const int k = idx - NC * DE;
        const int i = k / DE, d = k % DE;
        h16[H_XD + i * (4 * DE) + d] = (f16)(ws[O_DDV + i] * ws[O_EMBD + k]);
    }
}

// ---- epilogue: agg = relu((sum + bias)*(emb+1)) in-place ----
// drug sum = DSUM (W2+W3) + SLABD (W5+W7), fixed order.
__global__ __launch_bounds__(256) void k_epi(
    float* __restrict__ ws, const float* __restrict__ b_agg)
{
    const int idx = blockIdx.x * 256 + threadIdx.x;
    if (idx < NC * DE) {
        const int d = idx % DE;
        const float bc = b_agg[0 * DE + d] + b_agg[1 * DE + d] + b_agg[4 * DE + d] + b_agg[6 * DE + d];
        const float v = (ws[O_CSUM + idx] + bc) * (ws[O_EMBC + idx] + 1.f);
        ws[O_CSUM + idx] = fmaxf(v, 0.f);
    } else if (idx < (NC + ND) * DE) {
        const int k = idx - NC * DE;
        const int d = k % DE;
        const float bd = b_agg[2 * DE + d] + b_agg[3 * DE + d] + b_agg[5 * DE + d] + b_agg[7 * DE + d];
        const float sum = ws[O_DSUM + k] + ws[O_SLABD + k];
        const float v = (sum + bd) * (ws[O_EMBD + k] + 1.f);
        ws[O_DSUM + k] = fmaxf(v, 0.f);
    }
}

// ---- per-row mean + 1/||x-mu|| ----
__global__ __launch_bounds__(256) void k_rowstats(float* __restrict__ ws)
{
    __shared__ float red[256];
    const int b = blockIdx.x, t = threadIdx.x;
    const float* row;
    int omu, ois;
    if (b < NC) { row = ws + O_CSUM + b * DE; omu = O_CMU + b; ois = O_CIS + b; }
    else { const int i = b - NC; row = ws + O_DSUM + i * DE; omu = O_DMU + i; ois = O_DIS + i; }
    float s = 0.f;
    for (int j = t; j < DE; j += 256) s += row[j];
    const float mu = blockReduceSum(s, red) / (float)DE;
    float q = 0.f;
    for (int j = t; j < DE; j += 256) { const float v = row[j] - mu; q += v * v; }
    const float ss = blockReduceSum(q, red);
    if (t == 0) { ws[omu] = mu; ws[ois] = rsqrtf(ss); }
}

// ---- corr + sigmoid ----
__global__ __launch_bounds__(256) void k_corr(
    const float* __restrict__ ws, float* __restrict__ out)
{
    const int KT = 32;
    __shared__ float xs[16][KT + 1];
    __shared__ float ys[16][KT + 1];
    const int t = threadIdx.x;
    const int tcr = t >> 4, ti = t & 15;
    const int c0 = blockIdx.y * 16, i0 = blockIdx.x * 16;
    float acc = 0.f;
    for (int kb = 0; kb < DE; kb += KT) {
#pragma unroll
        for (int q = 0; q < 2; ++q) {
            const int s = q * 256 + t;
            const int row = s >> 5, kk = s & 31;
            const int k = kb + kk;
            const int c = c0 + row;
            xs[row][kk] = (c < NC && k < DE) ? ws[O_CSUM + c * DE + k] : 0.f;
            const int i = i0 + row;
            ys[row][kk] = (i < ND && k < DE) ? ws[O_DSUM + i * DE + k] : 0.f;
        }
        __syncthreads();
#pragma unroll
        for (int kt = 0; kt < KT; ++kt) acc += xs[tcr][kt] * ys[ti][kt];
        __syncthreads();
    }
    const int c = c0 + tcr, i = i0 + ti;
    if (c < NC && i < ND) {
        const float num = acc - (float)DE * ws[O_CMU + c] * ws[O_DMU + i];
        const float corr = num * ws[O_CIS + c] * ws[O_DIS + i];
        out[c * ND + i] = 1.f / (1.f + expf(-GAMMA_C * corr));
    }
}

static inline void jclear(Job& j) {
    for (int z = 0; z < 16; ++z) {
        j.aoff[z] = j.boff[z] = j.lda[z] = j.ldb[z] = 0;
        j.len[z] = j.blim[z] = j.coff[z] = j.bflag[z] = 0;
        j.rsg[z] = 1.f;
    }
}

extern "C" void kernel_launch(void* const* d_in, const int* in_sizes, int n_in,
                              void* d_out, int out_size, void* d_ws, size_t ws_size,
                              hipStream_t stream)
{
    const float* adj         = (const float*)d_in[0];
    const float* cell_exprs  = (const float*)d_in[1];
    const float* drug_finger = (const float*)d_in[2];
    const float* cell_hyper  = (const float*)d_in[3];
    const float* drug_hyper  = (const float*)d_in[4];
    const float* W_agg       = (const float*)d_in[5];
    const float* b_agg       = (const float*)d_in[6];
    const float* ldd_w       = (const float*)d_in[7];
    const float* lcc_w       = (const float*)d_in[9];
    const float* bnd_g       = (const float*)d_in[11];
    const float* bnd_b       = (const float*)d_in[12];
    const float* bnc_g       = (const float*)d_in[13];
    const float* bnc_b       = (const float*)d_in[14];
    float* ws  = (float*)d_ws;
    float* out = (float*)d_out;
    f16* h16 = (f16*)(ws + O_H16);

    // 1) scalars
    k_pre<<<NC + ND, 256, 0, stream>>>(adj, cell_hyper, drug_hyper, ws);
    // 2) z-norm stats
    k_zstats<<<NC, 256, 0, stream>>>(cell_exprs, ws);
    // 3) fp16 operand pool (scale-folded, padded)
    k_cvt<<<2048, 256, 0, stream>>>(cell_exprs, drug_finger, ldd_w, adj,
                                    cell_hyper, drug_hyper, ws, h16);

    // 4) exp = cx16 @ lcc_w^T — dedicated split-K (40 windows x 32 n-blocks)
    k_gemm_exp<<<dim3(32, 1, EXP_NWIN), 256, 0, stream>>>(h16, lcc_w, ws);
    k_reduce<<<479, 256, 0, stream>>>(ws + O_PS2, ws + O_EMBC, EXP_NWIN,
                                      NC * DE, NC * DE);

    // 5) fig = df16 @ ldw16^T (K=896) -> embD direct
    {
        Job j; jclear(j);
        j.aoff[0] = H_DF; j.lda[0] = 896;
        j.boff[0] = H_LDW; j.ldb[0] = 896;
        j.len[0] = 896; j.coff[0] = O_EMBD;
        k_fgemm<64, 64, 0, 0><<<dim3(32, 15, 1), 256, 0, stream>>>(
            h16, h16, ws, h16, nullptr, 0, ND, DE, DE, 1, 0, j);
    }
    // 6) BN (in-place fp32) + expT16/figT16 — one block per column
    k_bn2<<<2 * DE, 256, 0, stream>>>(ws, h16, bnc_g, bnc_b, bnd_g, bnd_b);
    // 7) Xc/Xd block0
    k_buildX<<<8065, 256, 0, stream>>>(ws, h16);

    // 8) cell X-jobs: X1 / X4 / X6 in one launch
    {
        Job j; jclear(j);
        j.aoff[0] = H_ALC; j.lda[0] = 960; j.boff[0] = H_FIGT; j.ldb[0] = 960;
        j.len[0] = 960; j.coff[0] = H_XC + DE;
        j.aoff[1] = H_CH; j.lda[1] = 64; j.boff[1] = H_EXPT; j.ldb[1] = 64;
        j.len[1] = 64; j.coff[1] = H_XC + 2 * DE;
        j.aoff[2] = H_CHS; j.lda[2] = 64; j.boff[2] = H_EXPT; j.ldb[2] = 64;
        j.len[2] = 64; j.coff[2] = H_XC + 3 * DE; j.rsg[2] = -1.f; j.bflag[2] = 1;
        k_fgemm<64, 64, 0, 1><<<dim3(32, 1, 3), 256, 0, stream>>>(
            h16, h16, ws, h16, ws + O_EMBC, DE, NC, DE, 4 * DE, 3, 1, j);
    }
    // 9) drug X-jobs: X3 / X5 / X7 in one launch (BN=64 for 2x blocks)
    {
        Job j; jclear(j);
        j.aoff[0] = H_ALD; j.lda[0] = 64; j.boff[0] = H_EXPT; j.ldb[0] = 64;
        j.len[0] = 64; j.coff[0] = H_XD + DE;
        j.aoff[1] = H_DH; j.lda[1] = 960; j.boff[1] = H_FIGT; j.ldb[1] = 960;
        j.len[1] = 960; j.coff[1] = H_XD + 2 * DE;
        j.aoff[2] = H_DHS; j.lda[2] = 960; j.boff[2] = H_FIGT; j.ldb[2] = 960;
        j.len[2] = 960; j.coff[2] = H_XD + 3 * DE; j.rsg[2] = -1.f; j.bflag[2] = 1;
        k_fgemm<128, 64, 0, 1><<<dim3(32, 8, 3), 256, 0, stream>>>(
            h16, h16, ws, h16, ws + O_EMBD, DE, ND, DE, 4 * DE, 3, 1, j);
    }
    // 10) cell main: Xc16 @ [W0|W1|W4|W6]^T — 16 windows, BN=64, 2-region slabs
    {
        const int permc[4] = {0, 1, 4, 6};
        const int ko[4] = {0, 512, 1024, 1536};
        const int kl[4] = {512, 512, 512, 504};
        Job j; jclear(j);
        for (int z = 0; z < 16; ++z) {
            const int ib = z >> 2, sub = z & 3;
            j.aoff[z] = H_XC + ib * DE + ko[sub]; j.lda[z] = 4 * DE;
            j.boff[z] = permc[ib] * DE * DE + ko[sub]; j.ldb[z] = DE;
            j.len[z] = kl[sub];
            j.coff[z] = (z < 10) ? (O_PS + z * (NC * DE))
                                 : (O_PS2B + (z - 10) * (NC * DE));
        }
        k_fgemm<64, 64, 1, 0><<<dim3(32, 1, 16), 256, 0, stream>>>(
            h16, W_agg, ws, h16, nullptr, 0, NC, DE, DE, 16, 1, j);
        k_reduce2<<<479, 256, 0, stream>>>(ws + O_PS, 10, ws + O_PS2B, 6,
                                           ws + O_CSUM, NC * DE, NC * DE);
    }
    // 11) drug main: Xd16 @ [W2|W3|W5|W7]^T — z=0:(W2,W3)->DSUM,
    //     z=1:(W5,W7)->SLABD; k_epi sums. grid 960 blocks.
    {
        const int permd[4] = {2, 3, 5, 7};
        Job j; jclear(j);
        for (int z = 0; z < 4; ++z) {
            j.aoff[z] = H_XD + z * DE; j.lda[z] = 4 * DE;
            j.boff[z] = permd[z] * DE * DE; j.ldb[z] = DE;
            j.len[z] = DE;
        }
        j.coff[0] = O_DSUM;
        j.coff[2] = O_SLABD;
        k_fgemm<64, 64, 1, 0><<<dim3(32, 15, 2), 256, 0, stream>>>(
            h16, W_agg, ws, h16, nullptr, 0, ND, DE, DE, 4, 2, j);
    }

    // 12) epilogue, stats, corr
    k_epi<<<8065, 256, 0, stream>>>(ws, b_agg);
    k_rowstats<<<NC + ND, 256, 0, stream>>>(ws);
    k_corr<<<dim3(60, 4), 256, 0, stream>>>(ws, out);

    (void)in_sizes; (void)n_in; (void)out_size; (void)ws_size;
}

// Round 4
// 806.302 us; speedup vs baseline: 2.1750x; 1.0578x over previous
//
#include <hip/hip_runtime.h>
#include <math.h>

#define NC 60
#define ND 952
#define DE 2040
#define NG 17737
#define NF 881
#define GAMMA_C 8.7f
#define EPS_BN 1e-5f

// ---- fp32 workspace layout (float offsets) ----
#define O_DX      0
#define O_DC      64
#define O_DY      128
#define O_DDV     1088
#define O_B4H     2048
#define O_A4H     2112
#define O_CMU     3072
#define O_CIS     3136
#define O_DMU     3200
#define O_DIS     4160
#define O_ZSC     5120
#define O_ZSH     5184
#define O_EMBC    8000       // 60*2040   = 122400
#define O_EMBD    130400     // 952*2040  = 1942080
#define O_CSUM    2072480    // 122400
#define O_DSUM    2194880    // 1942080
#define O_PS      4136960    // 10*122400 = 1224000 (slabs, reused)
#define O_H16     5360960    // fp16 pool starts here (float offset, 16B aligned)
// total floats: 5360960 + 8023680 = 13384640 -> 53.5 MB

// ---- fp16 pool layout (half offsets, all mult of 8) ----
#define H_CX    0            // 60*17760   = 1065600 (znormed cell_exprs, K-pad)
#define H_DF    1065600      // 952*896    = 852992  (drug_finger, K-pad)
#define H_LDW   1918592      // 2040*896   = 1827840 (ldd_w, K-pad)
#define H_ALC   3746432      // 60*960     = 57600   (dx.*adj.*dy)
#define H_ALD   3804032      // 952*64     = 60928   (dy.*adjT.*dx)
#define H_CH    3864960      // 60*64      = 3840
#define H_CHS   3868800      // 60*64      = 3840    (b4h.*CH.*b4h)
#define H_DH    3872640      // 952*960    = 913920
#define H_DHS   4786560      // 952*960    = 913920  (a4h.*DH.*a4h)
#define H_FIGT  5700480      // 2040*960   = 1958400 (fig^T, pad)
#define H_EXPT  7658880      // 2040*64    = 130560  (exp^T, pad)
#define H_XC    7789440      // 60*8160    = 489600
#define H_XD    8279040      // 952*8160   = 7768320 -> end 16047360 halves

// ---- transient slab regions (aliasing dead ranges; float offsets) ----
// O_PS2: 40 slabs for step-4 splitK. Aliases h16 H_FIGT.. (written step 6+).
#define O_PS2   8211200      // 40*122400 = 4896000 -> end 13107200 (< 13384640)
// O_PS2B: 6 extra slabs for step-10. Aliases h16 H_CX.. (dead after step 5).
#define O_PS2B  5360960      // 6*122400 = 734400 -> end 6095360
// Step-11 K-split slabs. SLB1 reuses O_PS + dead h16 H_CX.. (O_PS and O_PS2B
//   are consumed by reduce2, which precedes step 11 in stream order).
//   SLB2 aliases dead h16 H_DF..H_DHS-part (read last at step 9).
//   SLB2 end 8021120 < 9500480 (= float start of live H_XD). k_epi sums
//   DSUM + SLB1 + SLB2 in fixed order.
#define O_SLB1  4136960      // 1942080 -> end 6079040
#define O_SLB2  6079040      // 1942080 -> end 8021120

#define EXP_KW   444
#define EXP_NWIN 40          // 40*444 = 17760 = padded K

typedef _Float16 f16;
typedef __attribute__((ext_vector_type(8))) _Float16 f16x8;
typedef __attribute__((ext_vector_type(4))) float f32x4;

struct Job {
    int aoff[16]; int boff[16]; int lda[16]; int ldb[16];
    int len[16]; int blim[16]; int coff[16]; int bflag[16];
    float rsg[16];
};

__device__ __forceinline__ float blockReduceSum(float v, float* red) {
    const int t = threadIdx.x;
    red[t] = v;
    __syncthreads();
    for (int off = 128; off > 0; off >>= 1) {
        if (t < off) red[t] += red[t + off];
        __syncthreads();
    }
    float r = red[0];
    __syncthreads();
    return r;
}

// ---- scalars: dx/dc/dy/ddv, b4h, a4h ----
__global__ __launch_bounds__(256) void k_pre(
    const float* __restrict__ adj, const float* __restrict__ ch,
    const float* __restrict__ dh, float* __restrict__ ws)
{
    __shared__ float red[256];
    const int b = blockIdx.x, t = threadIdx.x;
    if (b < NC) {
        const int c = b;
        float s = 0.f;
        for (int j = t; j < ND; j += 256) s += adj[c * ND + j];
        float rs = blockReduceSum(s, red) + 1.f;
        if (t == 0) { ws[O_DX + c] = rsqrtf(rs); ws[O_DC + c] = 1.f / rs + 1.f; }
        float s2 = (t < NC) ? ch[c * NC + t] : 0.f;
        float hs = blockReduceSum(s2, red) + 1.f;
        if (t == 0) ws[O_B4H + c] = 1.f / hs;
    } else {
        const int i = b - NC;
        float s = 0.f;
        for (int j = t; j < ND; j += 256) s += dh[i * ND + j];
        float hs = blockReduceSum(s, red) + 1.f;
        if (t == 0) ws[O_A4H + i] = 1.f / hs;
        float s2 = (t < NC) ? adj[t * ND + i] : 0.f;
        float cs = blockReduceSum(s2, red) + 1.f;
        if (t == 0) { ws[O_DY + i] = rsqrtf(cs); ws[O_DDV + i] = 1.f / cs + 1.f; }
    }
}

// ---- z-norm stats per cell row ----
__global__ __launch_bounds__(256) void k_zstats(
    const float* __restrict__ x, float* __restrict__ ws)
{
    __shared__ float r1[256];
    __shared__ float r2[256];
    const int c = blockIdx.x, t = threadIdx.x;
    const float* row = x + c * NG;
    float s = 0.f, q = 0.f;
    for (int j = t; j < NG; j += 256) { float v = row[j]; s += v; q += v * v; }
    r1[t] = s; r2[t] = q;
    __syncthreads();
    for (int off = 128; off > 0; off >>= 1) {
        if (t < off) { r1[t] += r1[t + off]; r2[t] += r2[t + off]; }
        __syncthreads();
    }
    if (t == 0) {
        const float mu = r1[0] / (float)NG;
        const float var = (r2[0] - (float)NG * mu * mu) / (float)(NG - 1);
        const float inv = rsqrtf(var);
        ws[O_ZSC + c] = inv;
        ws[O_ZSH + c] = -mu * inv;
    }
}

// ---- convert/pad/scale-fold all small fp16 operands in one pass ----
#define CVT_TOT 5700480
__global__ __launch_bounds__(256) void k_cvt(
    const float* __restrict__ ce, const float* __restrict__ dfing,
    const float* __restrict__ ldw, const float* __restrict__ adj,
    const float* __restrict__ chyp, const float* __restrict__ dhyp,
    const float* __restrict__ ws, f16* __restrict__ h16)
{
    const float* dx = ws + O_DX;
    const float* dy = ws + O_DY;
    const float* b4h = ws + O_B4H;
    const float* a4h = ws + O_A4H;
    const float* zsc = ws + O_ZSC;
    const float* zsh = ws + O_ZSH;
    for (int idx = blockIdx.x * 256 + threadIdx.x; idx < CVT_TOT;
         idx += gridDim.x * 256) {
        float v = 0.f;
        if (idx < H_DF) {                     // cx16: znormed cell_exprs
            const int c = idx / 17760, k = idx % 17760;
            if (k < NG) v = ce[c * NG + k] * zsc[c] + zsh[c];
        } else if (idx < H_LDW) {             // df16
            const int j = idx - H_DF;
            const int i = j / 896, k = j % 896;
            if (k < NF) v = dfing[i * NF + k];
        } else if (idx < H_ALC) {             // ldw16
            const int j = idx - H_LDW;
            const int d = j / 896, k = j % 896;
            if (k < NF) v = ldw[d * NF + k];
        } else if (idx < H_ALD) {             // aggLc
            const int j = idx - H_ALC;
            const int c = j / 960, i = j % 960;
            if (i < ND) v = dx[c] * adj[c * ND + i] * dy[i];
        } else if (idx < H_CH) {              // aggLd
            const int j = idx - H_ALD;
            const int i = j / 64, c = j % 64;
            if (c < NC) v = dy[i] * adj[c * ND + i] * dx[c];
        } else if (idx < H_CHS) {             // ch16
            const int j = idx - H_CH;
            const int c = j / 64, k = j % 64;
            if (k < NC) v = chyp[c * NC + k];
        } else if (idx < H_DH) {              // chs16
            const int j = idx - H_CHS;
            const int c = j / 64, k = j % 64;
            if (k < NC) v = b4h[c] * chyp[c * NC + k] * b4h[k];
        } else if (idx < H_DHS) {             // dh16
            const int j = idx - H_DH;
            const int i = j / 960, k = j % 960;
            if (k < ND) v = dhyp[i * ND + k];
        } else {                              // dhs16
            const int j = idx - H_DHS;
            const int i = j / 960, k = j % 960;
            if (k < ND) v = a4h[i] * dhyp[i * ND + k] * a4h[k];
        }
        h16[idx] = (f16)v;
    }
}

// ============================================================================
// Dedicated split-K GEMM for step 4:  exp = cx16 @ lcc_w^T.
// ============================================================================
__global__ __launch_bounds__(256) void k_gemm_exp(
    const f16* __restrict__ Ah,      // h16 (cx16 at H_CX=0), lda 17760
    const float* __restrict__ B,     // lcc_w [DE, NG]
    float* __restrict__ ws)
{
    constexpr int BM = 64, BN = 64;
    constexpr int PSA = BM * 8 + 8;
    constexpr int PSB = BN * 8 + 8;
    __shared__ __align__(16) unsigned short As[4 * PSA];
    __shared__ __align__(16) unsigned short Bs[4 * PSB];
    const int t = threadIdx.x;
    const int wv = t >> 6, ln = t & 63;
    const int wm = wv >> 1, wn = wv & 1;
    const int kg = ln >> 4, lm = ln & 15;
    const int n0 = blockIdx.x * BN;
    const int z = blockIdx.z;
    const int kbase = z * EXP_KW;
    const int blim = (NG - kbase < EXP_KW) ? (NG - kbase) : EXP_KW;

    f32x4 acc[2][2];
#pragma unroll
    for (int i = 0; i < 2; ++i)
#pragma unroll
        for (int j = 0; j < 2; ++j) acc[i][j] = (f32x4){0.f, 0.f, 0.f, 0.f};

    const int brow_l = t >> 5;        // 0..7
    const int bcol   = t & 31;        // 0..31
    const int bkc    = bcol >> 3, bke = bcol & 7;
    f16* BsH = (f16*)Bs;

    for (int kb = 0; kb < EXP_KW; kb += 32) {
        {
            const int m = t >> 2, kc = t & 3;
            const int k0 = kb + kc * 8;
            uint4 d = {0u, 0u, 0u, 0u};
            if (m < NC && k0 < EXP_KW)
                d = *(const uint4*)(Ah + kbase + m * 17760 + k0);
            *(uint4*)&As[kc * PSA + m * 8] = d;
        }
        {
            const int col = kb + bcol;
            const bool cok = col < blim;
#pragma unroll
            for (int e = 0; e < 8; ++e) {
                const int n = brow_l + e * 8;
                const int gn = n0 + n;
                float v = 0.f;
                if (cok && gn < DE) v = B[gn * NG + kbase + col];
                BsH[bkc * PSB + n * 8 + bke] = (f16)v;
            }
        }
        __syncthreads();
        f16x8 af[2], bfr[2];
#pragma unroll
        for (int i = 0; i < 2; ++i)
            af[i] = *(f16x8*)&As[kg * PSA + (wm * 32 + i * 16 + lm) * 8];
#pragma unroll
        for (int j = 0; j < 2; ++j)
            bfr[j] = *(f16x8*)&Bs[kg * PSB + (wn * 32 + j * 16 + lm) * 8];
#pragma unroll
        for (int i = 0; i < 2; ++i)
#pragma unroll
            for (int j = 0; j < 2; ++j)
                acc[i][j] = __builtin_amdgcn_mfma_f32_16x16x32_f16(
                    af[i], bfr[j], acc[i][j], 0, 0, 0);
        __syncthreads();
    }
    float* P = ws + O_PS2 + z * (NC * DE);
#pragma unroll
    for (int i = 0; i < 2; ++i) {
        const int mb = wm * 32 + i * 16 + kg * 4;
#pragma unroll
        for (int r = 0; r < 4; ++r) {
            const int m = mb + r;
            if (m >= NC) continue;
#pragma unroll
            for (int j = 0; j < 2; ++j) {
                const int n = n0 + wn * 32 + j * 16 + lm;
                if (n >= DE) continue;
                P[m * DE + n] = acc[i][j][r];
            }
        }
    }
}

// ============================================================================
// Unified fp16 MFMA NT GEMM with job table + register-prefetch pipeline.
//   Per K-step: write staged regs->LDS, barrier, issue NEXT step's global
//   loads (latency hides under compute), ds_read+MFMA, barrier.
//   BMODE: 0 = B fp16 (aligned uint4), 1 = B fp32 aligned (2x float4, cvt
//   during LDS-write phase).
//   jpz = jobs per blockIdx.z: 0 -> loop all nwin jobs (epilogue idx 0);
//   k>0 -> loop jobs [z*jpz, (z+1)*jpz), epilogue idx z*jpz.
// ============================================================================
template<int BM, int BN, int BMODE, int F16OUT>
__global__ __launch_bounds__(256) void k_fgemm(
    const f16* __restrict__ Ah, const void* __restrict__ Bp,
    float* __restrict__ ws, f16* __restrict__ h16,
    const float* __restrict__ basep, int baseld,
    int M, int N, int ldc, int nwin, int jpz, Job jb)
{
    constexpr int PSA = BM * 8 + 8;
    constexpr int PSB = BN * 8 + 8;
    constexpr int MI = BM / 32;
    constexpr int NI = BN / 32;
    constexpr int PA_IT = (BM * 4) / 256;
    constexpr int PB_IT = (BN * 4) / 256;
    __shared__ __align__(16) unsigned short As[4 * PSA];
    __shared__ __align__(16) unsigned short Bs[4 * PSB];
    const int t = threadIdx.x;
    const int wv = t >> 6, ln = t & 63;
    const int wm = wv >> 1, wn = wv & 1;
    const int kg = ln >> 4, lm = ln & 15;
    const int m0 = blockIdx.y * BM;
    const int n0 = blockIdx.x * BN;

    f32x4 acc[MI][NI];
#pragma unroll
    for (int i = 0; i < MI; ++i)
#pragma unroll
        for (int j = 0; j < NI; ++j) acc[i][j] = (f32x4){0.f, 0.f, 0.f, 0.f};

    const int z0 = jpz ? (int)blockIdx.z * jpz : 0;
    const int z1 = jpz ? z0 + jpz : nwin;

    // prefetch registers
    uint4 pA[PA_IT];
    uint4 pB0[PB_IT];
    float4 pBx[PB_IT], pBy[PB_IT];

    for (int zi = z0; zi < z1; ++zi) {
        const int Ab = jb.aoff[zi], Bb = jb.boff[zi];
        const int lda = jb.lda[zi], ldb = jb.ldb[zi];
        const int len = jb.len[zi];

        auto prefetch = [&](int kbp) {
#pragma unroll
            for (int p = 0; p < PA_IT; ++p) {
                const int ci = p * 256 + t;
                const int m = ci >> 2, kc = ci & 3;
                const int k0 = kbp + kc * 8;
                uint4 d = {0u, 0u, 0u, 0u};
                if (m0 + m < M && k0 < len)
                    d = *(const uint4*)(Ah + Ab + (m0 + m) * lda + k0);
                pA[p] = d;
            }
#pragma unroll
            for (int p = 0; p < PB_IT; ++p) {
                const int ci = p * 256 + t;
                const int n = ci >> 2, kc = ci & 3;
                const int k0 = kbp + kc * 8;
                const bool ok = (n0 + n < N) && (k0 < len);
                if (BMODE == 0) {
                    uint4 d = {0u, 0u, 0u, 0u};
                    if (ok) d = *(const uint4*)((const f16*)Bp + Bb + (n0 + n) * ldb + k0);
                    pB0[p] = d;
                } else {
                    float4 x = {0.f, 0.f, 0.f, 0.f}, y = {0.f, 0.f, 0.f, 0.f};
                    if (ok) {
                        const float* bq = (const float*)Bp + Bb + (n0 + n) * ldb + k0;
                        x = *(const float4*)bq;
                        y = *(const float4*)(bq + 4);
                    }
                    pBx[p] = x; pBy[p] = y;
                }
            }
        };
        auto writeLds = [&]() {
#pragma unroll
            for (int p = 0; p < PA_IT; ++p) {
                const int ci = p * 256 + t;
                const int m = ci >> 2, kc = ci & 3;
                *(uint4*)&As[kc * PSA + m * 8] = pA[p];
            }
#pragma unroll
            for (int p = 0; p < PB_IT; ++p) {
                const int ci = p * 256 + t;
                const int n = ci >> 2, kc = ci & 3;
                if (BMODE == 0) {
                    *(uint4*)&Bs[kc * PSB + n * 8] = pB0[p];
                } else {
                    f16x8 pk;
                    pk[0] = (f16)pBx[p].x; pk[1] = (f16)pBx[p].y;
                    pk[2] = (f16)pBx[p].z; pk[3] = (f16)pBx[p].w;
                    pk[4] = (f16)pBy[p].x; pk[5] = (f16)pBy[p].y;
                    pk[6] = (f16)pBy[p].z; pk[7] = (f16)pBy[p].w;
                    *(f16x8*)&Bs[kc * PSB + n * 8] = pk;
                }
            }
        };

        for (int kb = 0; kb < len; kb += 32) {
            if (kb == 0) prefetch(0);
            writeLds();
            __syncthreads();
            if (kb + 32 < len) prefetch(kb + 32);
            f16x8 af[MI], bfr[NI];
#pragma unroll
            for (int i = 0; i < MI; ++i)
                af[i] = *(f16x8*)&As[kg * PSA + (wm * (BM / 2) + i * 16 + lm) * 8];
#pragma unroll
            for (int j = 0; j < NI; ++j)
                bfr[j] = *(f16x8*)&Bs[kg * PSB + (wn * (BN / 2) + j * 16 + lm) * 8];
#pragma unroll
            for (int i = 0; i < MI; ++i)
#pragma unroll
                for (int j = 0; j < NI; ++j)
                    acc[i][j] = __builtin_amdgcn_mfma_f32_16x16x32_f16(
                        af[i], bfr[j], acc[i][j], 0, 0, 0);
            __syncthreads();
        }
    }
    // ---- epilogue ----
    const int zz = z0;
    const float rs = jb.rsg[zz];
    const int co = jb.coff[zz];
    const int bfl = jb.bflag[zz];
#pragma unroll
    for (int i = 0; i < MI; ++i) {
        const int mb = m0 + wm * (BM / 2) + i * 16 + kg * 4;
#pragma unroll
        for (int r = 0; r < 4; ++r) {
            const int m = mb + r;
            if (m >= M) continue;
#pragma unroll
            for (int j = 0; j < NI; ++j) {
                const int n = n0 + wn * (BN / 2) + j * 16 + lm;
                if (n >= N) continue;
                float v = rs * acc[i][j][r];
                if (bfl) v += basep[m * baseld + n];
                if (F16OUT) h16[co + m * ldc + n] = (f16)v;
                else        ws[co + m * ldc + n] = v;
            }
        }
    }
}

// ---- fixed-order reduction of Z partial slabs ----
__global__ __launch_bounds__(256) void k_reduce(
    const float* __restrict__ P, float* __restrict__ out, int Z, int slab, int n)
{
    const int i = blockIdx.x * 256 + threadIdx.x;
    if (i < n) {
        float s = 0.f;
        for (int z = 0; z < Z; ++z) s += P[z * slab + i];
        out[i] = s;
    }
}

// ---- fixed-order reduction over two slab regions ----
__global__ __launch_bounds__(256) void k_reduce2(
    const float* __restrict__ P1, int Z1, const float* __restrict__ P2, int Z2,
    float* __restrict__ out, int slab, int n)
{
    const int i = blockIdx.x * 256 + threadIdx.x;
    if (i < n) {
        float s = 0.f;
        for (int z = 0; z < Z1; ++z) s += P1[z * slab + i];
        for (int z = 0; z < Z2; ++z) s += P2[z * slab + i];
        out[i] = s;
    }
}

// ---- BatchNorm (train stats): one block per column, register-resident ----
__global__ __launch_bounds__(256) void k_bn2(
    float* __restrict__ ws, f16* __restrict__ h16,
    const float* __restrict__ cg, const float* __restrict__ cb,
    const float* __restrict__ dg, const float* __restrict__ db)
{
    __shared__ float r1[256];
    __shared__ float r2[256];
    const int id = blockIdx.x, t = threadIdx.x;
    float* X; f16* T; const float* g; const float* b; int R, Rp, ldT, d;
    if (id < DE) { d = id; X = ws + O_EMBC; T = h16 + H_EXPT; g = cg; b = cb; R = NC; Rp = 64; ldT = 64; }
    else { d = id - DE; X = ws + O_EMBD; T = h16 + H_FIGT; g = dg; b = db; R = ND; Rp = 960; ldT = 960; }
    float vals[4];
    float s = 0.f, q = 0.f;
#pragma unroll
    for (int v = 0; v < 4; ++v) {
        const int r = t + v * 256;
        float x = 0.f;
        if (r < R) x = X[r * DE + d];
        vals[v] = x;
        s += x; q += x * x;
    }
    r1[t] = s; r2[t] = q;
    __syncthreads();
    for (int off = 128; off > 0; off >>= 1) {
        if (t < off) { r1[t] += r1[t + off]; r2[t] += r2[t + off]; }
        __syncthreads();
    }
    const float mu = r1[0] / (float)R;
    float var = r2[0] / (float)R - mu * mu;
    var = fmaxf(var, 0.f);
    const float sc = rsqrtf(var + EPS_BN) * g[d];
    const float sh = b[d] - mu * sc;
#pragma unroll
    for (int v = 0; v < 4; ++v) {
        const int r = t + v * 256;
        if (r < R) {
            const float y = vals[v] * sc + sh;
            X[r * DE + d] = y;
            T[d * ldT + r] = (f16)y;
        } else if (r < Rp) {
            T[d * ldT + r] = (f16)0.f;
        }
    }
}

// ---- Xc/Xd block0 = diag-scaled emb (fp16) ----
__global__ __launch_bounds__(256) void k_buildX(
    const float* __restrict__ ws, f16* __restrict__ h16)
{
    const int idx = blockIdx.x * 256 + threadIdx.x;
    if (idx < NC * DE) {
        const int c = idx / DE, d = idx % DE;
        h16[H_XC + c * (4 * DE) + d] = (f16)(ws[O_DC + c] * ws[O_EMBC + idx]);
    } else if (idx < (NC + ND) * DE) {
        const int k = idx - NC * DE;
        const int i = k / DE, d = k % DE;
        h16[H_XD + i * (4 * DE) + d] = (f16)(ws[O_DDV + i] * ws[O_EMBD + k]);
    }
}

// ---- epilogue: agg = relu((sum + bias)*(emb+1)) in-place ----
// drug sum = DSUM + SLB1 + SLB2 (step-11 K-split partials), fixed order.
__global__ __launch_bounds__(256) void k_epi(
    float* __restrict__ ws, const float* __restrict__ b_agg)
{
    const int idx = blockIdx.x * 256 + threadIdx.x;
    if (idx < NC * DE) {
        const int d = idx % DE;
        const float bc = b_agg[0 * DE + d] + b_agg[1 * DE + d] + b_agg[4 * DE + d] + b_agg[6 * DE + d];
        const float v = (ws[O_CSUM + idx] + bc) * (ws[O_EMBC + idx] + 1.f);
        ws[O_CSUM + idx] = fmaxf(v, 0.f);
    } else if (idx < (NC + ND) * DE) {
        const int k = idx - NC * DE;
        const int d = k % DE;
        const float bd = b_agg[2 * DE + d] + b_agg[3 * DE + d] + b_agg[5 * DE + d] + b_agg[7 * DE + d];
        const float sum = ws[O_DSUM + k] + ws[O_SLB1 + k] + ws[O_SLB2 + k];
        const float v = (sum + bd) * (ws[O_EMBD + k] + 1.f);
        ws[O_DSUM + k] = fmaxf(v, 0.f);
    }
}

// ---- per-row mean + 1/||x-mu|| ----
__global__ __launch_bounds__(256) void k_rowstats(float* __restrict__ ws)
{
    __shared__ float red[256];
    const int b = blockIdx.x, t = threadIdx.x;
    const float* row;
    int omu, ois;
    if (b < NC) { row = ws + O_CSUM + b * DE; omu = O_CMU + b; ois = O_CIS + b; }
    else { const int i = b - NC; row = ws + O_DSUM + i * DE; omu = O_DMU + i; ois = O_DIS + i; }
    float s = 0.f;
    for (int j = t; j < DE; j += 256) s += row[j];
    const float mu = blockReduceSum(s, red) / (float)DE;
    float q = 0.f;
    for (int j = t; j < DE; j += 256) { const float v = row[j] - mu; q += v * v; }
    const float ss = blockReduceSum(q, red);
    if (t == 0) { ws[omu] = mu; ws[ois] = rsqrtf(ss); }
}

// ---- corr + sigmoid ----
__global__ __launch_bounds__(256) void k_corr(
    const float* __restrict__ ws, float* __restrict__ out)
{
    const int KT = 32;
    __shared__ float xs[16][KT + 1];
    __shared__ float ys[16][KT + 1];
    const int t = threadIdx.x;
    const int tcr = t >> 4, ti = t & 15;
    const int c0 = blockIdx.y * 16, i0 = blockIdx.x * 16;
    float acc = 0.f;
    for (int kb = 0; kb < DE; kb += KT) {
#pragma unroll
        for (int q = 0; q < 2; ++q) {
            const int s = q * 256 + t;
            const int row = s >> 5, kk = s & 31;
            const int k = kb + kk;
            const int c = c0 + row;
            xs[row][kk] = (c < NC && k < DE) ? ws[O_CSUM + c * DE + k] : 0.f;
            const int i = i0 + row;
            ys[row][kk] = (i < ND && k < DE) ? ws[O_DSUM + i * DE + k] : 0.f;
        }
        __syncthreads();
#pragma unroll
        for (int kt = 0; kt < KT; ++kt) acc += xs[tcr][kt] * ys[ti][kt];
        __syncthreads();
    }
    const int c = c0 + tcr, i = i0 + ti;
    if (c < NC && i < ND) {
        const float num = acc - (float)DE * ws[O_CMU + c] * ws[O_DMU + i];
        const float corr = num * ws[O_CIS + c] * ws[O_DIS + i];
        out[c * ND + i] = 1.f / (1.f + expf(-GAMMA_C * corr));
    }
}

static inline void jclear(Job& j) {
    for (int z = 0; z < 16; ++z) {
        j.aoff[z] = j.boff[z] = j.lda[z] = j.ldb[z] = 0;
        j.len[z] = j.blim[z] = j.coff[z] = j.bflag[z] = 0;
        j.rsg[z] = 1.f;
    }
}

extern "C" void kernel_launch(void* const* d_in, const int* in_sizes, int n_in,
                              void* d_out, int out_size, void* d_ws, size_t ws_size,
                              hipStream_t stream)
{
    const float* adj         = (const float*)d_in[0];
    const float* cell_exprs  = (const float*)d_in[1];
    const float* drug_finger = (const float*)d_in[2];
    const float* cell_hyper  = (const float*)d_in[3];
    const float* drug_hyper  = (const float*)d_in[4];
    const float* W_agg       = (const float*)d_in[5];
    const float* b_agg       = (const float*)d_in[6];
    const float* ldd_w       = (const float*)d_in[7];
    const float* lcc_w       = (const float*)d_in[9];
    const float* bnd_g       = (const float*)d_in[11];
    const float* bnd_b       = (const float*)d_in[12];
    const float* bnc_g       = (const float*)d_in[13];
    const float* bnc_b       = (const float*)d_in[14];
    float* ws  = (float*)d_ws;
    float* out = (float*)d_out;
    f16* h16 = (f16*)(ws + O_H16);

    // 1) scalars
    k_pre<<<NC + ND, 256, 0, stream>>>(adj, cell_hyper, drug_hyper, ws);
    // 2) z-norm stats
    k_zstats<<<NC, 256, 0, stream>>>(cell_exprs, ws);
    // 3) fp16 operand pool (scale-folded, padded)
    k_cvt<<<2048, 256, 0, stream>>>(cell_exprs, drug_finger, ldd_w, adj,
                                    cell_hyper, drug_hyper, ws, h16);

    // 4) exp = cx16 @ lcc_w^T — dedicated split-K (40 windows x 32 n-blocks)
    k_gemm_exp<<<dim3(32, 1, EXP_NWIN), 256, 0, stream>>>(h16, lcc_w, ws);
    k_reduce<<<479, 256, 0, stream>>>(ws + O_PS2, ws + O_EMBC, EXP_NWIN,
                                      NC * DE, NC * DE);

    // 5) fig = df16 @ ldw16^T (K=896) -> embD direct
    {
        Job j; jclear(j);
        j.aoff[0] = H_DF; j.lda[0] = 896;
        j.boff[0] = H_LDW; j.ldb[0] = 896;
        j.len[0] = 896; j.coff[0] = O_EMBD;
        k_fgemm<64, 64, 0, 0><<<dim3(32, 15, 1), 256, 0, stream>>>(
            h16, h16, ws, h16, nullptr, 0, ND, DE, DE, 1, 0, j);
    }
    // 6) BN (in-place fp32) + expT16/figT16 — one block per column
    k_bn2<<<2 * DE, 256, 0, stream>>>(ws, h16, bnc_g, bnc_b, bnd_g, bnd_b);
    // 7) Xc/Xd block0
    k_buildX<<<8065, 256, 0, stream>>>(ws, h16);

    // 8) cell X-jobs: X1 / X4 / X6 in one launch
    {
        Job j; jclear(j);
        j.aoff[0] = H_ALC; j.lda[0] = 960; j.boff[0] = H_FIGT; j.ldb[0] = 960;
        j.len[0] = 960; j.coff[0] = H_XC + DE;
        j.aoff[1] = H_CH; j.lda[1] = 64; j.boff[1] = H_EXPT; j.ldb[1] = 64;
        j.len[1] = 64; j.coff[1] = H_XC + 2 * DE;
        j.aoff[2] = H_CHS; j.lda[2] = 64; j.boff[2] = H_EXPT; j.ldb[2] = 64;
        j.len[2] = 64; j.coff[2] = H_XC + 3 * DE; j.rsg[2] = -1.f; j.bflag[2] = 1;
        k_fgemm<64, 64, 0, 1><<<dim3(32, 1, 3), 256, 0, stream>>>(
            h16, h16, ws, h16, ws + O_EMBC, DE, NC, DE, 4 * DE, 3, 1, j);
    }
    // 9) drug X-jobs: X3 / X5 / X7 in one launch
    {
        Job j; jclear(j);
        j.aoff[0] = H_ALD; j.lda[0] = 64; j.boff[0] = H_EXPT; j.ldb[0] = 64;
        j.len[0] = 64; j.coff[0] = H_XD + DE;
        j.aoff[1] = H_DH; j.lda[1] = 960; j.boff[1] = H_FIGT; j.ldb[1] = 960;
        j.len[1] = 960; j.coff[1] = H_XD + 2 * DE;
        j.aoff[2] = H_DHS; j.lda[2] = 960; j.boff[2] = H_FIGT; j.ldb[2] = 960;
        j.len[2] = 960; j.coff[2] = H_XD + 3 * DE; j.rsg[2] = -1.f; j.bflag[2] = 1;
        k_fgemm<128, 64, 0, 1><<<dim3(32, 8, 3), 256, 0, stream>>>(
            h16, h16, ws, h16, ws + O_EMBD, DE, ND, DE, 4 * DE, 3, 1, j);
    }
    // 10) cell main: Xc16 @ [W0|W1|W4|W6]^T — 16 windows, BN=64, 2-region slabs
    {
        const int permc[4] = {0, 1, 4, 6};
        const int ko[4] = {0, 512, 1024, 1536};
        const int kl[4] = {512, 512, 512, 504};
        Job j; jclear(j);
        for (int z = 0; z < 16; ++z) {
            const int ib = z >> 2, sub = z & 3;
            j.aoff[z] = H_XC + ib * DE + ko[sub]; j.lda[z] = 4 * DE;
            j.boff[z] = permc[ib] * DE * DE + ko[sub]; j.ldb[z] = DE;
            j.len[z] = kl[sub];
            j.coff[z] = (z < 10) ? (O_PS + z * (NC * DE))
                                 : (O_PS2B + (z - 10) * (NC * DE));
        }
        k_fgemm<64, 64, 1, 0><<<dim3(32, 1, 16), 256, 0, stream>>>(
            h16, W_agg, ws, h16, nullptr, 0, NC, DE, DE, 16, 1, j);
        k_reduce2<<<479, 256, 0, stream>>>(ws + O_PS, 10, ws + O_PS2B, 6,
                                           ws + O_CSUM, NC * DE, NC * DE);
    }
    // 11) drug main: Xd16 @ [W2|W3|W5|W7]^T — 3 balanced z-groups of K=2720:
    //     z0: W2 full + W3[0:680)      -> DSUM
    //     z1: W3[680:2040) + W5[0:1360)-> SLB1
    //     z2: W5[1360:2040) + W7 full  -> SLB2
    //     k_epi sums DSUM+SLB1+SLB2. grid (32,15,3) = 1440 blocks.
    {
        Job j; jclear(j);
        // job0: X-block0 (W2) full
        j.aoff[0] = H_XD + 0 * DE;        j.boff[0] = 2 * DE * DE;        j.len[0] = 2040;
        // job1: X-block1 (W3) [0,680)
        j.aoff[1] = H_XD + 1 * DE;        j.boff[1] = 3 * DE * DE;        j.len[1] = 680;
        // job2: X-block1 (W3) [680,2040)
        j.aoff[2] = H_XD + 1 * DE + 680;  j.boff[2] = 3 * DE * DE + 680;  j.len[2] = 1360;
        // job3: X-block2 (W5) [0,1360)
        j.aoff[3] = H_XD + 2 * DE;        j.boff[3] = 5 * DE * DE;        j.len[3] = 1360;
        // job4: X-block2 (W5) [1360,2040)
        j.aoff[4] = H_XD + 2 * DE + 1360; j.boff[4] = 5 * DE * DE + 1360; j.len[4] = 680;
        // job5: X-block3 (W7) full
        j.aoff[5] = H_XD + 3 * DE;        j.boff[5] = 7 * DE * DE;        j.len[5] = 2040;
        for (int z = 0; z < 6; ++z) { j.lda[z] = 4 * DE; j.ldb[z] = DE; }
        j.coff[0] = O_DSUM;
        j.coff[2] = O_SLB1;
        j.coff[4] = O_SLB2;
        k_fgemm<64, 64, 1, 0><<<dim3(32, 15, 3), 256, 0, stream>>>(
            h16, W_agg, ws, h16, nullptr, 0, ND, DE, DE, 6, 2, j);
    }

    // 12) epilogue, stats, corr
    k_epi<<<8065, 256, 0, stream>>>(ws, b_agg);
    k_rowstats<<<NC + ND, 256, 0, stream>>>(ws);
    k_corr<<<dim3(60, 4), 256, 0, stream>>>(ws, out);

    (void)in_sizes; (void)n_in; (void)out_size; (void)ws_size;
}

// Round 5
// 781.067 us; speedup vs baseline: 2.2453x; 1.0323x over previous
//
#include <hip/hip_runtime.h>
#include <math.h>

#define NC 60
#define ND 952
#define DE 2040
#define NG 17737
#define NF 881
#define GAMMA_C 8.7f
#define EPS_BN 1e-5f

// ---- fp32 workspace layout (float offsets) ----
#define O_DX      0
#define O_DC      64
#define O_DY      128
#define O_DDV     1088
#define O_B4H     2048
#define O_A4H     2112
#define O_CMU     3072
#define O_CIS     3136
#define O_DMU     3200
#define O_DIS     4160
#define O_ZSC     5120
#define O_ZSH     5184
#define O_EMBC    8000       // 60*2040   = 122400
#define O_EMBD    130400     // 952*2040  = 1942080
#define O_CSUM    2072480    // 122400
#define O_DSUM    2194880    // 1942080
#define O_PS      4136960    // 10*122400 = 1224000 (slabs, reused)
#define O_H16     5360960    // fp16 pool starts here (float offset, 16B aligned)
// total floats: 5360960 + 8023680 = 13384640 -> 53.5 MB

// ---- fp16 pool layout (half offsets, all mult of 8) ----
#define H_CX    0            // 60*17760   = 1065600 (znormed cell_exprs, K-pad)
#define H_DF    1065600      // 952*896    = 852992  (drug_finger, K-pad)
#define H_LDW   1918592      // 2040*896   = 1827840 (ldd_w, K-pad)
#define H_ALC   3746432      // 60*960     = 57600   (dx.*adj.*dy)
#define H_ALD   3804032      // 952*64     = 60928   (dy.*adjT.*dx)
#define H_CH    3864960      // 60*64      = 3840
#define H_CHS   3868800      // 60*64      = 3840    (b4h.*CH.*b4h)
#define H_DH    3872640      // 952*960    = 913920
#define H_DHS   4786560      // 952*960    = 913920  (a4h.*DH.*a4h)
#define H_FIGT  5700480      // 2040*960   = 1958400 (fig^T, pad)
#define H_EXPT  7658880      // 2040*64    = 130560  (exp^T, pad)
#define H_XC    7789440      // 60*8160    = 489600
#define H_XD    8279040      // 952*8160   = 7768320 -> end 16047360 halves

// ---- transient slab regions (aliasing dead ranges; float offsets) ----
// O_PS2: 40 slabs for step-4 splitK. Aliases h16 H_FIGT.. (written step 6+).
#define O_PS2   8211200      // 40*122400 = 4896000 -> end 13107200 (< 13384640)
// O_PS2B: 6 extra slabs for step-10. Aliases h16 H_CX.. (dead after step 5).
#define O_PS2B  5360960      // 6*122400 = 734400 -> end 6095360
// Step-11 K-split slabs. SLB1 reuses O_PS + dead h16 H_CX.. (O_PS and O_PS2B
//   are consumed by reduce2, which precedes step 11 in stream order).
//   SLB2 aliases dead h16 H_DF..H_DHS-part (read last at step 9).
//   SLB2 end 8021120 < 9500480 (= float start of live H_XD). k_epi sums
//   DSUM + SLB1 + SLB2 in fixed order.
#define O_SLB1  4136960      // 1942080 -> end 6079040
#define O_SLB2  6079040      // 1942080 -> end 8021120

#define EXP_KW   444
#define EXP_NWIN 40          // 40*444 = 17760 = padded K

typedef _Float16 f16;
typedef __attribute__((ext_vector_type(8))) _Float16 f16x8;
typedef __attribute__((ext_vector_type(4))) float f32x4;

struct Job {
    int aoff[16]; int boff[16]; int lda[16]; int ldb[16];
    int len[16]; int blim[16]; int coff[16]; int bflag[16];
    float rsg[16];
};

__device__ __forceinline__ float blockReduceSum(float v, float* red) {
    const int t = threadIdx.x;
    red[t] = v;
    __syncthreads();
    for (int off = 128; off > 0; off >>= 1) {
        if (t < off) red[t] += red[t + off];
        __syncthreads();
    }
    float r = red[0];
    __syncthreads();
    return r;
}

// ---- scalars: dx/dc/dy/ddv, b4h, a4h ----
__global__ __launch_bounds__(256) void k_pre(
    const float* __restrict__ adj, const float* __restrict__ ch,
    const float* __restrict__ dh, float* __restrict__ ws)
{
    __shared__ float red[256];
    const int b = blockIdx.x, t = threadIdx.x;
    if (b < NC) {
        const int c = b;
        float s = 0.f;
        for (int j = t; j < ND; j += 256) s += adj[c * ND + j];
        float rs = blockReduceSum(s, red) + 1.f;
        if (t == 0) { ws[O_DX + c] = rsqrtf(rs); ws[O_DC + c] = 1.f / rs + 1.f; }
        float s2 = (t < NC) ? ch[c * NC + t] : 0.f;
        float hs = blockReduceSum(s2, red) + 1.f;
        if (t == 0) ws[O_B4H + c] = 1.f / hs;
    } else {
        const int i = b - NC;
        float s = 0.f;
        for (int j = t; j < ND; j += 256) s += dh[i * ND + j];
        float hs = blockReduceSum(s, red) + 1.f;
        if (t == 0) ws[O_A4H + i] = 1.f / hs;
        float s2 = (t < NC) ? adj[t * ND + i] : 0.f;
        float cs = blockReduceSum(s2, red) + 1.f;
        if (t == 0) { ws[O_DY + i] = rsqrtf(cs); ws[O_DDV + i] = 1.f / cs + 1.f; }
    }
}

// ---- z-norm stats per cell row ----
__global__ __launch_bounds__(256) void k_zstats(
    const float* __restrict__ x, float* __restrict__ ws)
{
    __shared__ float r1[256];
    __shared__ float r2[256];
    const int c = blockIdx.x, t = threadIdx.x;
    const float* row = x + c * NG;
    float s = 0.f, q = 0.f;
    for (int j = t; j < NG; j += 256) { float v = row[j]; s += v; q += v * v; }
    r1[t] = s; r2[t] = q;
    __syncthreads();
    for (int off = 128; off > 0; off >>= 1) {
        if (t < off) { r1[t] += r1[t + off]; r2[t] += r2[t + off]; }
        __syncthreads();
    }
    if (t == 0) {
        const float mu = r1[0] / (float)NG;
        const float var = (r2[0] - (float)NG * mu * mu) / (float)(NG - 1);
        const float inv = rsqrtf(var);
        ws[O_ZSC + c] = inv;
        ws[O_ZSH + c] = -mu * inv;
    }
}

// ---- convert/pad/scale-fold all small fp16 operands in one pass ----
#define CVT_TOT 5700480
__global__ __launch_bounds__(256) void k_cvt(
    const float* __restrict__ ce, const float* __restrict__ dfing,
    const float* __restrict__ ldw, const float* __restrict__ adj,
    const float* __restrict__ chyp, const float* __restrict__ dhyp,
    const float* __restrict__ ws, f16* __restrict__ h16)
{
    const float* dx = ws + O_DX;
    const float* dy = ws + O_DY;
    const float* b4h = ws + O_B4H;
    const float* a4h = ws + O_A4H;
    const float* zsc = ws + O_ZSC;
    const float* zsh = ws + O_ZSH;
    for (int idx = blockIdx.x * 256 + threadIdx.x; idx < CVT_TOT;
         idx += gridDim.x * 256) {
        float v = 0.f;
        if (idx < H_DF) {                     // cx16: znormed cell_exprs
            const int c = idx / 17760, k = idx % 17760;
            if (k < NG) v = ce[c * NG + k] * zsc[c] + zsh[c];
        } else if (idx < H_LDW) {             // df16
            const int j = idx - H_DF;
            const int i = j / 896, k = j % 896;
            if (k < NF) v = dfing[i * NF + k];
        } else if (idx < H_ALC) {             // ldw16
            const int j = idx - H_LDW;
            const int d = j / 896, k = j % 896;
            if (k < NF) v = ldw[d * NF + k];
        } else if (idx < H_ALD) {             // aggLc
            const int j = idx - H_ALC;
            const int c = j / 960, i = j % 960;
            if (i < ND) v = dx[c] * adj[c * ND + i] * dy[i];
        } else if (idx < H_CH) {              // aggLd
            const int j = idx - H_ALD;
            const int i = j / 64, c = j % 64;
            if (c < NC) v = dy[i] * adj[c * ND + i] * dx[c];
        } else if (idx < H_CHS) {             // ch16
            const int j = idx - H_CH;
            const int c = j / 64, k = j % 64;
            if (k < NC) v = chyp[c * NC + k];
        } else if (idx < H_DH) {              // chs16
            const int j = idx - H_CHS;
            const int c = j / 64, k = j % 64;
            if (k < NC) v = b4h[c] * chyp[c * NC + k] * b4h[k];
        } else if (idx < H_DHS) {             // dh16
            const int j = idx - H_DH;
            const int i = j / 960, k = j % 960;
            if (k < ND) v = dhyp[i * ND + k];
        } else {                              // dhs16
            const int j = idx - H_DHS;
            const int i = j / 960, k = j % 960;
            if (k < ND) v = a4h[i] * dhyp[i * ND + k] * a4h[k];
        }
        h16[idx] = (f16)v;
    }
}

// ============================================================================
// Dedicated split-K GEMM for step 4:  exp = cx16 @ lcc_w^T.
//   2-deep ping-pong register prefetch: loads for phase k+2 are issued right
//   after phase k's barrier, so HBM latency (~900cy) hides under 2 phases.
// ============================================================================
__global__ __launch_bounds__(256) void k_gemm_exp(
    const f16* __restrict__ Ah,      // h16 (cx16 at H_CX=0), lda 17760
    const float* __restrict__ B,     // lcc_w [DE, NG]
    float* __restrict__ ws)
{
    constexpr int BM = 64, BN = 64;
    constexpr int PSA = BM * 8 + 8;
    constexpr int PSB = BN * 8 + 8;
    __shared__ __align__(16) unsigned short As[4 * PSA];
    __shared__ __align__(16) unsigned short Bs[4 * PSB];
    const int t = threadIdx.x;
    const int wv = t >> 6, ln = t & 63;
    const int wm = wv >> 1, wn = wv & 1;
    const int kg = ln >> 4, lm = ln & 15;
    const int n0 = blockIdx.x * BN;
    const int z = blockIdx.z;
    const int kbase = z * EXP_KW;
    const int blim = (NG - kbase < EXP_KW) ? (NG - kbase) : EXP_KW;

    f32x4 acc[2][2];
#pragma unroll
    for (int i = 0; i < 2; ++i)
#pragma unroll
        for (int j = 0; j < 2; ++j) acc[i][j] = (f32x4){0.f, 0.f, 0.f, 0.f};

    const int brow_l = t >> 5;        // 0..7
    const int bcol   = t & 31;        // 0..31
    const int bkc    = bcol >> 3, bke = bcol & 7;
    f16* BsH = (f16*)Bs;

    auto pf = [&](int kbp, uint4& da, float (&bv)[8]) {
        {
            const int m = t >> 2, kc = t & 3;
            const int k0 = kbp + kc * 8;
            da = (uint4){0u, 0u, 0u, 0u};
            if (m < NC && k0 < EXP_KW)
                da = *(const uint4*)(Ah + kbase + m * 17760 + k0);
        }
        {
            const int col = kbp + bcol;
            const bool cok = col < blim;
#pragma unroll
            for (int e = 0; e < 8; ++e) {
                const int n = brow_l + e * 8;
                const int gn = n0 + n;
                bv[e] = (cok && gn < DE) ? B[gn * NG + kbase + col] : 0.f;
            }
        }
    };
    auto wr = [&](const uint4& da, const float (&bv)[8]) {
        {
            const int m = t >> 2, kc = t & 3;
            *(uint4*)&As[kc * PSA + m * 8] = da;
        }
#pragma unroll
        for (int e = 0; e < 8; ++e) {
            const int n = brow_l + e * 8;
            BsH[bkc * PSB + n * 8 + bke] = (f16)bv[e];
        }
    };
    auto compute = [&]() {
        f16x8 af[2], bfr[2];
#pragma unroll
        for (int i = 0; i < 2; ++i)
            af[i] = *(f16x8*)&As[kg * PSA + (wm * 32 + i * 16 + lm) * 8];
#pragma unroll
        for (int j = 0; j < 2; ++j)
            bfr[j] = *(f16x8*)&Bs[kg * PSB + (wn * 32 + j * 16 + lm) * 8];
#pragma unroll
        for (int i = 0; i < 2; ++i)
#pragma unroll
            for (int j = 0; j < 2; ++j)
                acc[i][j] = __builtin_amdgcn_mfma_f32_16x16x32_f16(
                    af[i], bfr[j], acc[i][j], 0, 0, 0);
    };

    uint4 dA_a, dA_b;
    float bv_a[8], bv_b[8];
    pf(0, dA_a, bv_a);
    pf(32, dA_b, bv_b);
    for (int kb = 0; kb < EXP_KW; kb += 64) {
        wr(dA_a, bv_a);
        __syncthreads();
        pf(kb + 64, dA_a, bv_a);
        compute();
        __syncthreads();
        wr(dA_b, bv_b);
        __syncthreads();
        pf(kb + 96, dA_b, bv_b);
        compute();
        __syncthreads();
    }
    float* P = ws + O_PS2 + z * (NC * DE);
#pragma unroll
    for (int i = 0; i < 2; ++i) {
        const int mb = wm * 32 + i * 16 + kg * 4;
#pragma unroll
        for (int r = 0; r < 4; ++r) {
            const int m = mb + r;
            if (m >= NC) continue;
#pragma unroll
            for (int j = 0; j < 2; ++j) {
                const int n = n0 + wn * 32 + j * 16 + lm;
                if (n >= DE) continue;
                P[m * DE + n] = acc[i][j][r];
            }
        }
    }
}

// ============================================================================
// Unified fp16 MFMA NT GEMM with job table + 2-deep ping-pong prefetch.
//   Phase k: write staged regs(set)->LDS, barrier, issue loads for k+2 into
//   the same set (2 phases of slack before consumption), ds_read+MFMA,
//   barrier. Odd trailing phases compute harmlessly on zero-filled data.
//   BMODE: 0 = B fp16 (aligned uint4), 1 = B fp32 aligned (2x float4, cvt
//   during LDS-write phase).
//   jpz = jobs per blockIdx.z: 0 -> loop all nwin jobs (epilogue idx 0);
//   k>0 -> loop jobs [z*jpz, (z+1)*jpz), epilogue idx z*jpz.
// ============================================================================
template<int BM, int BN, int BMODE, int F16OUT>
__global__ __launch_bounds__(256) void k_fgemm(
    const f16* __restrict__ Ah, const void* __restrict__ Bp,
    float* __restrict__ ws, f16* __restrict__ h16,
    const float* __restrict__ basep, int baseld,
    int M, int N, int ldc, int nwin, int jpz, Job jb)
{
    constexpr int PSA = BM * 8 + 8;
    constexpr int PSB = BN * 8 + 8;
    constexpr int MI = BM / 32;
    constexpr int NI = BN / 32;
    constexpr int PA_IT = (BM * 4) / 256;
    constexpr int PB_IT = (BN * 4) / 256;
    __shared__ __align__(16) unsigned short As[4 * PSA];
    __shared__ __align__(16) unsigned short Bs[4 * PSB];
    const int t = threadIdx.x;
    const int wv = t >> 6, ln = t & 63;
    const int wm = wv >> 1, wn = wv & 1;
    const int kg = ln >> 4, lm = ln & 15;
    const int m0 = blockIdx.y * BM;
    const int n0 = blockIdx.x * BN;

    f32x4 acc[MI][NI];
#pragma unroll
    for (int i = 0; i < MI; ++i)
#pragma unroll
        for (int j = 0; j < NI; ++j) acc[i][j] = (f32x4){0.f, 0.f, 0.f, 0.f};

    const int z0 = jpz ? (int)blockIdx.z * jpz : 0;
    const int z1 = jpz ? z0 + jpz : nwin;

    // ping-pong prefetch register sets (named, statically indexed)
    uint4 pAa[PA_IT], pAb[PA_IT];
    uint4 pB0a[PB_IT], pB0b[PB_IT];
    float4 pBxa[PB_IT], pBya[PB_IT], pBxb[PB_IT], pByb[PB_IT];

    for (int zi = z0; zi < z1; ++zi) {
        const int Ab = jb.aoff[zi], Bb = jb.boff[zi];
        const int lda = jb.lda[zi], ldb = jb.ldb[zi];
        const int len = jb.len[zi];

        auto pf = [&](int kbp, uint4 (&pA)[PA_IT], uint4 (&pB0)[PB_IT],
                      float4 (&pBx)[PB_IT], float4 (&pBy)[PB_IT]) {
#pragma unroll
            for (int p = 0; p < PA_IT; ++p) {
                const int ci = p * 256 + t;
                const int m = ci >> 2, kc = ci & 3;
                const int k0 = kbp + kc * 8;
                uint4 d = {0u, 0u, 0u, 0u};
                if (m0 + m < M && k0 < len)
                    d = *(const uint4*)(Ah + Ab + (m0 + m) * lda + k0);
                pA[p] = d;
            }
#pragma unroll
            for (int p = 0; p < PB_IT; ++p) {
                const int ci = p * 256 + t;
                const int n = ci >> 2, kc = ci & 3;
                const int k0 = kbp + kc * 8;
                const bool ok = (n0 + n < N) && (k0 < len);
                if (BMODE == 0) {
                    uint4 d = {0u, 0u, 0u, 0u};
                    if (ok) d = *(const uint4*)((const f16*)Bp + Bb + (n0 + n) * ldb + k0);
                    pB0[p] = d;
                } else {
                    float4 x = {0.f, 0.f, 0.f, 0.f}, y = {0.f, 0.f, 0.f, 0.f};
                    if (ok) {
                        const float* bq = (const float*)Bp + Bb + (n0 + n) * ldb + k0;
                        x = *(const float4*)bq;
                        y = *(const float4*)(bq + 4);
                    }
                    pBx[p] = x; pBy[p] = y;
                }
            }
        };
        auto wr = [&](uint4 (&pA)[PA_IT], uint4 (&pB0)[PB_IT],
                      float4 (&pBx)[PB_IT], float4 (&pBy)[PB_IT]) {
#pragma unroll
            for (int p = 0; p < PA_IT; ++p) {
                const int ci = p * 256 + t;
                const int m = ci >> 2, kc = ci & 3;
                *(uint4*)&As[kc * PSA + m * 8] = pA[p];
            }
#pragma unroll
            for (int p = 0; p < PB_IT; ++p) {
                const int ci = p * 256 + t;
                const int n = ci >> 2, kc = ci & 3;
                if (BMODE == 0) {
                    *(uint4*)&Bs[kc * PSB + n * 8] = pB0[p];
                } else {
                    f16x8 pk;
                    pk[0] = (f16)pBx[p].x; pk[1] = (f16)pBx[p].y;
                    pk[2] = (f16)pBx[p].z; pk[3] = (f16)pBx[p].w;
                    pk[4] = (f16)pBy[p].x; pk[5] = (f16)pBy[p].y;
                    pk[6] = (f16)pBy[p].z; pk[7] = (f16)pBy[p].w;
                    *(f16x8*)&Bs[kc * PSB + n * 8] = pk;
                }
            }
        };
        auto compute = [&]() {
            f16x8 af[MI], bfr[NI];
#pragma unroll
            for (int i = 0; i < MI; ++i)
                af[i] = *(f16x8*)&As[kg * PSA + (wm * (BM / 2) + i * 16 + lm) * 8];
#pragma unroll
            for (int j = 0; j < NI; ++j)
                bfr[j] = *(f16x8*)&Bs[kg * PSB + (wn * (BN / 2) + j * 16 + lm) * 8];
#pragma unroll
            for (int i = 0; i < MI; ++i)
#pragma unroll
                for (int j = 0; j < NI; ++j)
                    acc[i][j] = __builtin_amdgcn_mfma_f32_16x16x32_f16(
                        af[i], bfr[j], acc[i][j], 0, 0, 0);
        };

        pf(0, pAa, pB0a, pBxa, pBya);
        pf(32, pAb, pB0b, pBxb, pByb);
        for (int kb = 0; kb < len; kb += 64) {
            wr(pAa, pB0a, pBxa, pBya);
            __syncthreads();
            pf(kb + 64, pAa, pB0a, pBxa, pBya);
            compute();
            __syncthreads();
            wr(pAb, pB0b, pBxb, pByb);
            __syncthreads();
            pf(kb + 96, pAb, pB0b, pBxb, pByb);
            compute();
            __syncthreads();
        }
    }
    // ---- epilogue ----
    const int zz = z0;
    const float rs = jb.rsg[zz];
    const int co = jb.coff[zz];
    const int bfl = jb.bflag[zz];
#pragma unroll
    for (int i = 0; i < MI; ++i) {
        const int mb = m0 + wm * (BM / 2) + i * 16 + kg * 4;
#pragma unroll
        for (int r = 0; r < 4; ++r) {
            const int m = mb + r;
            if (m >= M) continue;
#pragma unroll
            for (int j = 0; j < NI; ++j) {
                const int n = n0 + wn * (BN / 2) + j * 16 + lm;
                if (n >= N) continue;
                float v = rs * acc[i][j][r];
                if (bfl) v += basep[m * baseld + n];
                if (F16OUT) h16[co + m * ldc + n] = (f16)v;
                else        ws[co + m * ldc + n] = v;
            }
        }
    }
}

// ---- fixed-order reduction of Z partial slabs ----
__global__ __launch_bounds__(256) void k_reduce(
    const float* __restrict__ P, float* __restrict__ out, int Z, int slab, int n)
{
    const int i = blockIdx.x * 256 + threadIdx.x;
    if (i < n) {
        float s = 0.f;
        for (int z = 0; z < Z; ++z) s += P[z * slab + i];
        out[i] = s;
    }
}

// ---- fixed-order reduction over two slab regions ----
__global__ __launch_bounds__(256) void k_reduce2(
    const float* __restrict__ P1, int Z1, const float* __restrict__ P2, int Z2,
    float* __restrict__ out, int slab, int n)
{
    const int i = blockIdx.x * 256 + threadIdx.x;
    if (i < n) {
        float s = 0.f;
        for (int z = 0; z < Z1; ++z) s += P1[z * slab + i];
        for (int z = 0; z < Z2; ++z) s += P2[z * slab + i];
        out[i] = s;
    }
}

// ---- BatchNorm (train stats): one block per column, register-resident ----
__global__ __launch_bounds__(256) void k_bn2(
    float* __restrict__ ws, f16* __restrict__ h16,
    const float* __restrict__ cg, const float* __restrict__ cb,
    const float* __restrict__ dg, const float* __restrict__ db)
{
    __shared__ float r1[256];
    __shared__ float r2[256];
    const int id = blockIdx.x, t = threadIdx.x;
    float* X; f16* T; const float* g; const float* b; int R, Rp, ldT, d;
    if (id < DE) { d = id; X = ws + O_EMBC; T = h16 + H_EXPT; g = cg; b = cb; R = NC; Rp = 64; ldT = 64; }
    else { d = id - DE; X = ws + O_EMBD; T = h16 + H_FIGT; g = dg; b = db; R = ND; Rp = 960; ldT = 960; }
    float vals[4];
    float s = 0.f, q = 0.f;
#pragma unroll
    for (int v = 0; v < 4; ++v) {
        const int r = t + v * 256;
        float x = 0.f;
        if (r < R) x = X[r * DE + d];
        vals[v] = x;
        s += x; q += x * x;
    }
    r1[t] = s; r2[t] = q;
    __syncthreads();
    for (int off = 128; off > 0; off >>= 1) {
        if (t < off) { r1[t] += r1[t + off]; r2[t] += r2[t + off]; }
        __syncthreads();
    }
    const float mu = r1[0] / (float)R;
    float var = r2[0] / (float)R - mu * mu;
    var = fmaxf(var, 0.f);
    const float sc = rsqrtf(var + EPS_BN) * g[d];
    const float sh = b[d] - mu * sc;
#pragma unroll
    for (int v = 0; v < 4; ++v) {
        const int r = t + v * 256;
        if (r < R) {
            const float y = vals[v] * sc + sh;
            X[r * DE + d] = y;
            T[d * ldT + r] = (f16)y;
        } else if (r < Rp) {
            T[d * ldT + r] = (f16)0.f;
        }
    }
}

// ---- Xc/Xd block0 = diag-scaled emb (fp16) ----
__global__ __launch_bounds__(256) void k_buildX(
    const float* __restrict__ ws, f16* __restrict__ h16)
{
    const int idx = blockIdx.x * 256 + threadIdx.x;
    if (idx < NC * DE) {
        const int c = idx / DE, d = idx % DE;
        h16[H_XC + c * (4 * DE) + d] = (f16)(ws[O_DC + c] * ws[O_EMBC + idx]);
    } else if (idx < (NC + ND) * DE) {
        const int k = idx - NC * DE;
        const int i = k / DE, d = k % DE;
        h16[H_XD + i * (4 * DE) + d] = (f16)(ws[O_DDV + i] * ws[O_EMBD + k]);
    }
}

// ---- epilogue: agg = relu((sum + bias)*(emb+1)) in-place ----
// drug sum = DSUM + SLB1 + SLB2 (step-11 K-split partials), fixed order.
__global__ __launch_bounds__(256) void k_epi(
    float* __restrict__ ws, const float* __restrict__ b_agg)
{
    const int idx = blockIdx.x * 256 + threadIdx.x;
    if (idx < NC * DE) {
        const int d = idx % DE;
        const float bc = b_agg[0 * DE + d] + b_agg[1 * DE + d] + b_agg[4 * DE + d] + b_agg[6 * DE + d];
        const float v = (ws[O_CSUM + idx] + bc) * (ws[O_EMBC + idx] + 1.f);
        ws[O_CSUM + idx] = fmaxf(v, 0.f);
    } else if (idx < (NC + ND) * DE) {
        const int k = idx - NC * DE;
        const int d = k % DE;
        const float bd = b_agg[2 * DE + d] + b_agg[3 * DE + d] + b_agg[5 * DE + d] + b_agg[7 * DE + d];
        const float sum = ws[O_DSUM + k] + ws[O_SLB1 + k] + ws[O_SLB2 + k];
        const float v = (sum + bd) * (ws[O_EMBD + k] + 1.f);
        ws[O_DSUM + k] = fmaxf(v, 0.f);
    }
}

// ---- per-row mean + 1/||x-mu|| ----
__global__ __launch_bounds__(256) void k_rowstats(float* __restrict__ ws)
{
    __shared__ float red[256];
    const int b = blockIdx.x, t = threadIdx.x;
    const float* row;
    int omu, ois;
    if (b < NC) { row = ws + O_CSUM + b * DE; omu = O_CMU + b; ois = O_CIS + b; }
    else { const int i = b - NC; row = ws + O_DSUM + i * DE; omu = O_DMU + i; ois = O_DIS + i; }
    float s = 0.f;
    for (int j = t; j < DE; j += 256) s += row[j];
    const float mu = blockReduceSum(s, red) / (float)DE;
    float q = 0.f;
    for (int j = t; j < DE; j += 256) { const float v = row[j] - mu; q += v * v; }
    const float ss = blockReduceSum(q, red);
    if (t == 0) { ws[omu] = mu; ws[ois] = rsqrtf(ss); }
}

// ---- corr + sigmoid ----
__global__ __launch_bounds__(256) void k_corr(
    const float* __restrict__ ws, float* __restrict__ out)
{
    const int KT = 32;
    __shared__ float xs[16][KT + 1];
    __shared__ float ys[16][KT + 1];
    const int t = threadIdx.x;
    const int tcr = t >> 4, ti = t & 15;
    const int c0 = blockIdx.y * 16, i0 = blockIdx.x * 16;
    float acc = 0.f;
    for (int kb = 0; kb < DE; kb += KT) {
#pragma unroll
        for (int q = 0; q < 2; ++q) {
            const int s = q * 256 + t;
            const int row = s >> 5, kk = s & 31;
            const int k = kb + kk;
            const int c = c0 + row;
            xs[row][kk] = (c < NC && k < DE) ? ws[O_CSUM + c * DE + k] : 0.f;
            const int i = i0 + row;
            ys[row][kk] = (i < ND && k < DE) ? ws[O_DSUM + i * DE + k] : 0.f;
        }
        __syncthreads();
#pragma unroll
        for (int kt = 0; kt < KT; ++kt) acc += xs[tcr][kt] * ys[ti][kt];
        __syncthreads();
    }
    const int c = c0 + tcr, i = i0 + ti;
    if (c < NC && i < ND) {
        const float num = acc - (float)DE * ws[O_CMU + c] * ws[O_DMU + i];
        const float corr = num * ws[O_CIS + c] * ws[O_DIS + i];
        out[c * ND + i] = 1.f / (1.f + expf(-GAMMA_C * corr));
    }
}

static inline void jclear(Job& j) {
    for (int z = 0; z < 16; ++z) {
        j.aoff[z] = j.boff[z] = j.lda[z] = j.ldb[z] = 0;
        j.len[z] = j.blim[z] = j.coff[z] = j.bflag[z] = 0;
        j.rsg[z] = 1.f;
    }
}

extern "C" void kernel_launch(void* const* d_in, const int* in_sizes, int n_in,
                              void* d_out, int out_size, void* d_ws, size_t ws_size,
                              hipStream_t stream)
{
    const float* adj         = (const float*)d_in[0];
    const float* cell_exprs  = (const float*)d_in[1];
    const float* drug_finger = (const float*)d_in[2];
    const float* cell_hyper  = (const float*)d_in[3];
    const float* drug_hyper  = (const float*)d_in[4];
    const float* W_agg       = (const float*)d_in[5];
    const float* b_agg       = (const float*)d_in[6];
    const float* ldd_w       = (const float*)d_in[7];
    const float* lcc_w       = (const float*)d_in[9];
    const float* bnd_g       = (const float*)d_in[11];
    const float* bnd_b       = (const float*)d_in[12];
    const float* bnc_g       = (const float*)d_in[13];
    const float* bnc_b       = (const float*)d_in[14];
    float* ws  = (float*)d_ws;
    float* out = (float*)d_out;
    f16* h16 = (f16*)(ws + O_H16);

    // 1) scalars
    k_pre<<<NC + ND, 256, 0, stream>>>(adj, cell_hyper, drug_hyper, ws);
    // 2) z-norm stats
    k_zstats<<<NC, 256, 0, stream>>>(cell_exprs, ws);
    // 3) fp16 operand pool (scale-folded, padded)
    k_cvt<<<2048, 256, 0, stream>>>(cell_exprs, drug_finger, ldd_w, adj,
                                    cell_hyper, drug_hyper, ws, h16);

    // 4) exp = cx16 @ lcc_w^T — dedicated split-K (40 windows x 32 n-blocks)
    k_gemm_exp<<<dim3(32, 1, EXP_NWIN), 256, 0, stream>>>(h16, lcc_w, ws);
    k_reduce<<<479, 256, 0, stream>>>(ws + O_PS2, ws + O_EMBC, EXP_NWIN,
                                      NC * DE, NC * DE);

    // 5) fig = df16 @ ldw16^T (K=896) -> embD direct
    {
        Job j; jclear(j);
        j.aoff[0] = H_DF; j.lda[0] = 896;
        j.boff[0] = H_LDW; j.ldb[0] = 896;
        j.len[0] = 896; j.coff[0] = O_EMBD;
        k_fgemm<64, 64, 0, 0><<<dim3(32, 15, 1), 256, 0, stream>>>(
            h16, h16, ws, h16, nullptr, 0, ND, DE, DE, 1, 0, j);
    }
    // 6) BN (in-place fp32) + expT16/figT16 — one block per column
    k_bn2<<<2 * DE, 256, 0, stream>>>(ws, h16, bnc_g, bnc_b, bnd_g, bnd_b);
    // 7) Xc/Xd block0
    k_buildX<<<8065, 256, 0, stream>>>(ws, h16);

    // 8) cell X-jobs: X1 / X4 / X6 in one launch
    {
        Job j; jclear(j);
        j.aoff[0] = H_ALC; j.lda[0] = 960; j.boff[0] = H_FIGT; j.ldb[0] = 960;
        j.len[0] = 960; j.coff[0] = H_XC + DE;
        j.aoff[1] = H_CH; j.lda[1] = 64; j.boff[1] = H_EXPT; j.ldb[1] = 64;
        j.len[1] = 64; j.coff[1] = H_XC + 2 * DE;
        j.aoff[2] = H_CHS; j.lda[2] = 64; j.boff[2] = H_EXPT; j.ldb[2] = 64;
        j.len[2] = 64; j.coff[2] = H_XC + 3 * DE; j.rsg[2] = -1.f; j.bflag[2] = 1;
        k_fgemm<64, 64, 0, 1><<<dim3(32, 1, 3), 256, 0, stream>>>(
            h16, h16, ws, h16, ws + O_EMBC, DE, NC, DE, 4 * DE, 3, 1, j);
    }
    // 9) drug X-jobs: X3 / X5 / X7 in one launch
    {
        Job j; jclear(j);
        j.aoff[0] = H_ALD; j.lda[0] = 64; j.boff[0] = H_EXPT; j.ldb[0] = 64;
        j.len[0] = 64; j.coff[0] = H_XD + DE;
        j.aoff[1] = H_DH; j.lda[1] = 960; j.boff[1] = H_FIGT; j.ldb[1] = 960;
        j.len[1] = 960; j.coff[1] = H_XD + 2 * DE;
        j.aoff[2] = H_DHS; j.lda[2] = 960; j.boff[2] = H_FIGT; j.ldb[2] = 960;
        j.len[2] = 960; j.coff[2] = H_XD + 3 * DE; j.rsg[2] = -1.f; j.bflag[2] = 1;
        k_fgemm<128, 64, 0, 1><<<dim3(32, 8, 3), 256, 0, stream>>>(
            h16, h16, ws, h16, ws + O_EMBD, DE, ND, DE, 4 * DE, 3, 1, j);
    }
    // 10) cell main: Xc16 @ [W0|W1|W4|W6]^T — 16 windows, BN=64, 2-region slabs
    {
        const int permc[4] = {0, 1, 4, 6};
        const int ko[4] = {0, 512, 1024, 1536};
        const int kl[4] = {512, 512, 512, 504};
        Job j; jclear(j);
        for (int z = 0; z < 16; ++z) {
            const int ib = z >> 2, sub = z & 3;
            j.aoff[z] = H_XC + ib * DE + ko[sub]; j.lda[z] = 4 * DE;
            j.boff[z] = permc[ib] * DE * DE + ko[sub]; j.ldb[z] = DE;
            j.len[z] = kl[sub];
            j.coff[z] = (z < 10) ? (O_PS + z * (NC * DE))
                                 : (O_PS2B + (z - 10) * (NC * DE));
        }
        k_fgemm<64, 64, 1, 0><<<dim3(32, 1, 16), 256, 0, stream>>>(
            h16, W_agg, ws, h16, nullptr, 0, NC, DE, DE, 16, 1, j);
        k_reduce2<<<479, 256, 0, stream>>>(ws + O_PS, 10, ws + O_PS2B, 6,
                                           ws + O_CSUM, NC * DE, NC * DE);
    }
    // 11) drug main: Xd16 @ [W2|W3|W5|W7]^T — 3 balanced z-groups of K=2720:
    //     z0: W2 full + W3[0:680)      -> DSUM
    //     z1: W3[680:2040) + W5[0:1360)-> SLB1
    //     z2: W5[1360:2040) + W7 full  -> SLB2
    //     k_epi sums DSUM+SLB1+SLB2. grid (32,15,3) = 1440 blocks.
    {
        Job j; jclear(j);
        // job0: X-block0 (W2) full
        j.aoff[0] = H_XD + 0 * DE;        j.boff[0] = 2 * DE * DE;        j.len[0] = 2040;
        // job1: X-block1 (W3) [0,680)
        j.aoff[1] = H_XD + 1 * DE;        j.boff[1] = 3 * DE * DE;        j.len[1] = 680;
        // job2: X-block1 (W3) [680,2040)
        j.aoff[2] = H_XD + 1 * DE + 680;  j.boff[2] = 3 * DE * DE + 680;  j.len[2] = 1360;
        // job3: X-block2 (W5) [0,1360)
        j.aoff[3] = H_XD + 2 * DE;        j.boff[3] = 5 * DE * DE;        j.len[3] = 1360;
        // job4: X-block2 (W5) [1360,2040)
        j.aoff[4] = H_XD + 2 * DE + 1360; j.boff[4] = 5 * DE * DE + 1360; j.len[4] = 680;
        // job5: X-block3 (W7) full
        j.aoff[5] = H_XD + 3 * DE;        j.boff[5] = 7 * DE * DE;        j.len[5] = 2040;
        for (int z = 0; z < 6; ++z) { j.lda[z] = 4 * DE; j.ldb[z] = DE; }
        j.coff[0] = O_DSUM;
        j.coff[2] = O_SLB1;
        j.coff[4] = O_SLB2;
        k_fgemm<64, 64, 1, 0><<<dim3(32, 15, 3), 256, 0, stream>>>(
            h16, W_agg, ws, h16, nullptr, 0, ND, DE, DE, 6, 2, j);
    }

    // 12) epilogue, stats, corr
    k_epi<<<8065, 256, 0, stream>>>(ws, b_agg);
    k_rowstats<<<NC + ND, 256, 0, stream>>>(ws);
    k_corr<<<dim3(60, 4), 256, 0, stream>>>(ws, out);

    (void)in_sizes; (void)n_in; (void)out_size; (void)ws_size;
}

// Round 6
// 767.652 us; speedup vs baseline: 2.2845x; 1.0175x over previous
//
#include <hip/hip_runtime.h>
#include <math.h>

#define NC 60
#define ND 952
#define DE 2040
#define NG 17737
#define NF 881
#define GAMMA_C 8.7f
#define EPS_BN 1e-5f

// ---- fp32 workspace layout (float offsets) ----
#define O_DX      0
#define O_DC      64
#define O_DY      128
#define O_DDV     1088
#define O_B4H     2048
#define O_A4H     2112
#define O_CMU     3072
#define O_CIS     3136
#define O_DMU     3200
#define O_DIS     4160
#define O_ZSC     5120
#define O_ZSH     5184
#define O_EMBC    8000       // 60*2040   = 122400
#define O_EMBD    130400     // 952*2040  = 1942080
#define O_CSUM    2072480    // 122400
#define O_DSUM    2194880    // 1942080
#define O_PS      4136960    // 10*122400 = 1224000 (slabs)
#define O_H16     5360960    // fp16 pool starts here (float offset)
// total floats: 5360960 + 8023680 = 13384640 -> 53.5 MB

// ---- fp16 pool layout (half offsets, all mult of 8) ----
#define H_CX    0            // 60*17760   = 1065600 (znormed cell_exprs, K-pad)
#define H_DF    1065600      // 952*896    = 852992  (drug_finger, K-pad)
#define H_LDW   1918592      // 2040*896   = 1827840 (ldd_w, K-pad)
#define H_ALC   3746432      // 60*960     = 57600   (dx.*adj.*dy)
#define H_ALD   3804032      // 952*64     = 60928   (dy.*adjT.*dx)
#define H_CH    3864960      // 60*64      = 3840
#define H_CHS   3868800      // 60*64      = 3840    (b4h.*CH.*b4h)
#define H_DH    3872640      // 952*960    = 913920
#define H_DHS   4786560      // 952*960    = 913920  (a4h.*DH.*a4h)
#define H_FIGT  5700480      // 2040*960   = 1958400 (fig^T, pad)
#define H_EXPT  7658880      // 2040*64    = 130560  (exp^T, pad)
#define H_XC    7789440      // 60*8160    = 489600
#define H_XD    8279040      // 952*8160   = 7768320 -> end 16047360 halves

// ---- transient slab regions (aliasing dead ranges; float offsets) ----
// O_PS2: 40 slabs for step-4 splitK. Aliases h16 H_FIGT.. (written step 6+).
#define O_PS2   8211200      // 40*122400 = 4896000 -> end 13107200
// Step-11 K-split slabs, live DURING merged 10/11 launch. They alias h16
//   H_CX..H_EXPT-part (floats 5360960..9245120), all dead after step 9
//   (merged-8/9 is the last reader of H_*T/H_DH*). H_XC (live, read by
//   step-10 jobs) starts at float 9255680 > 9245120. k_epi sums
//   DSUM + SLB1 + SLB2 in fixed order.
#define O_SLB1  5360960      // 1942080 -> end 7303040
#define O_SLB2  7303040      // 1942080 -> end 9245120

#define EXP_KW   444
#define EXP_NWIN 40          // 40*444 = 17760 = padded K

typedef _Float16 f16;
typedef __attribute__((ext_vector_type(8))) _Float16 f16x8;
typedef __attribute__((ext_vector_type(4))) float f32x4;

// Generalized job table: 24 job slots; per-grid-z {job range, M}.
struct Job {
    int aoff[24]; int boff[24]; int lda[24]; int ldb[24];
    int len[24]; int coff[24]; int bflag[24];
    float rsg[24];
    int zs[24]; int zcnt[24]; int Mz[24];
};

__device__ __forceinline__ float blockReduceSum(float v, float* red) {
    const int t = threadIdx.x;
    red[t] = v;
    __syncthreads();
    for (int off = 128; off > 0; off >>= 1) {
        if (t < off) red[t] += red[t + off];
        __syncthreads();
    }
    float r = red[0];
    __syncthreads();
    return r;
}

// ---- scalars: dx/dc/dy/ddv, b4h, a4h ----
__global__ __launch_bounds__(256) void k_pre(
    const float* __restrict__ adj, const float* __restrict__ ch,
    const float* __restrict__ dh, float* __restrict__ ws)
{
    __shared__ float red[256];
    const int b = blockIdx.x, t = threadIdx.x;
    if (b < NC) {
        const int c = b;
        float s = 0.f;
        for (int j = t; j < ND; j += 256) s += adj[c * ND + j];
        float rs = blockReduceSum(s, red) + 1.f;
        if (t == 0) { ws[O_DX + c] = rsqrtf(rs); ws[O_DC + c] = 1.f / rs + 1.f; }
        float s2 = (t < NC) ? ch[c * NC + t] : 0.f;
        float hs = blockReduceSum(s2, red) + 1.f;
        if (t == 0) ws[O_B4H + c] = 1.f / hs;
    } else {
        const int i = b - NC;
        float s = 0.f;
        for (int j = t; j < ND; j += 256) s += dh[i * ND + j];
        float hs = blockReduceSum(s, red) + 1.f;
        if (t == 0) ws[O_A4H + i] = 1.f / hs;
        float s2 = (t < NC) ? adj[t * ND + i] : 0.f;
        float cs = blockReduceSum(s2, red) + 1.f;
        if (t == 0) { ws[O_DY + i] = rsqrtf(cs); ws[O_DDV + i] = 1.f / cs + 1.f; }
    }
}

// ---- z-norm stats per cell row ----
__global__ __launch_bounds__(256) void k_zstats(
    const float* __restrict__ x, float* __restrict__ ws)
{
    __shared__ float r1[256];
    __shared__ float r2[256];
    const int c = blockIdx.x, t = threadIdx.x;
    const float* row = x + c * NG;
    float s = 0.f, q = 0.f;
    for (int j = t; j < NG; j += 256) { float v = row[j]; s += v; q += v * v; }
    r1[t] = s; r2[t] = q;
    __syncthreads();
    for (int off = 128; off > 0; off >>= 1) {
        if (t < off) { r1[t] += r1[t + off]; r2[t] += r2[t + off]; }
        __syncthreads();
    }
    if (t == 0) {
        const float mu = r1[0] / (float)NG;
        const float var = (r2[0] - (float)NG * mu * mu) / (float)(NG - 1);
        const float inv = rsqrtf(var);
        ws[O_ZSC + c] = inv;
        ws[O_ZSH + c] = -mu * inv;
    }
}

// ---- convert/pad/scale-fold all small fp16 operands in one pass ----
#define CVT_TOT 5700480
__global__ __launch_bounds__(256) void k_cvt(
    const float* __restrict__ ce, const float* __restrict__ dfing,
    const float* __restrict__ ldw, const float* __restrict__ adj,
    const float* __restrict__ chyp, const float* __restrict__ dhyp,
    const float* __restrict__ ws, f16* __restrict__ h16)
{
    const float* dx = ws + O_DX;
    const float* dy = ws + O_DY;
    const float* b4h = ws + O_B4H;
    const float* a4h = ws + O_A4H;
    const float* zsc = ws + O_ZSC;
    const float* zsh = ws + O_ZSH;
    for (int idx = blockIdx.x * 256 + threadIdx.x; idx < CVT_TOT;
         idx += gridDim.x * 256) {
        float v = 0.f;
        if (idx < H_DF) {                     // cx16: znormed cell_exprs
            const int c = idx / 17760, k = idx % 17760;
            if (k < NG) v = ce[c * NG + k] * zsc[c] + zsh[c];
        } else if (idx < H_LDW) {             // df16
            const int j = idx - H_DF;
            const int i = j / 896, k = j % 896;
            if (k < NF) v = dfing[i * NF + k];
        } else if (idx < H_ALC) {             // ldw16
            const int j = idx - H_LDW;
            const int d = j / 896, k = j % 896;
            if (k < NF) v = ldw[d * NF + k];
        } else if (idx < H_ALD) {             // aggLc
            const int j = idx - H_ALC;
            const int c = j / 960, i = j % 960;
            if (i < ND) v = dx[c] * adj[c * ND + i] * dy[i];
        } else if (idx < H_CH) {              // aggLd
            const int j = idx - H_ALD;
            const int i = j / 64, c = j % 64;
            if (c < NC) v = dy[i] * adj[c * ND + i] * dx[c];
        } else if (idx < H_CHS) {             // ch16
            const int j = idx - H_CH;
            const int c = j / 64, k = j % 64;
            if (k < NC) v = chyp[c * NC + k];
        } else if (idx < H_DH) {              // chs16
            const int j = idx - H_CHS;
            const int c = j / 64, k = j % 64;
            if (k < NC) v = b4h[c] * chyp[c * NC + k] * b4h[k];
        } else if (idx < H_DHS) {             // dh16
            const int j = idx - H_DH;
            const int i = j / 960, k = j % 960;
            if (k < ND) v = dhyp[i * ND + k];
        } else {                              // dhs16
            const int j = idx - H_DHS;
            const int i = j / 960, k = j % 960;
            if (k < ND) v = a4h[i] * dhyp[i * ND + k] * a4h[k];
        }
        h16[idx] = (f16)v;
    }
}

// ============================================================================
// Dedicated split-K GEMM for step 4:  exp = cx16 @ lcc_w^T.
//   Double-buffered LDS (1 barrier/step) + 2-step-ahead register prefetch.
// ============================================================================
__global__ __launch_bounds__(256) void k_gemm_exp(
    const f16* __restrict__ Ah,      // h16 (cx16 at H_CX=0), lda 17760
    const float* __restrict__ B,     // lcc_w [DE, NG]
    float* __restrict__ ws)
{
    constexpr int BN = 64;
    constexpr int PSA = 64 * 8 + 8;
    constexpr int PSB = 64 * 8 + 8;
    __shared__ __align__(16) unsigned short As[2 * 4 * PSA];
    __shared__ __align__(16) unsigned short Bs[2 * 4 * PSB];
    const int t = threadIdx.x;
    const int wv = t >> 6, ln = t & 63;
    const int wm = wv >> 1, wn = wv & 1;
    const int kg = ln >> 4, lm = ln & 15;
    const int n0 = blockIdx.x * BN;
    const int z = blockIdx.z;
    const int kbase = z * EXP_KW;
    const int blim = (NG - kbase < EXP_KW) ? (NG - kbase) : EXP_KW;

    f32x4 acc[2][2];
#pragma unroll
    for (int i = 0; i < 2; ++i)
#pragma unroll
        for (int j = 0; j < 2; ++j) acc[i][j] = (f32x4){0.f, 0.f, 0.f, 0.f};

    const int brow_l = t >> 5;        // 0..7
    const int bcol   = t & 31;        // 0..31
    const int bkc    = bcol >> 3, bke = bcol & 7;

    auto pf = [&](int s, uint4& da, float (&bv)[8]) {
        const int kbp = s << 5;
        {
            const int m = t >> 2, kc = t & 3;
            const int k0 = kbp + kc * 8;
            da = (uint4){0u, 0u, 0u, 0u};
            if (m < NC && k0 < EXP_KW)
                da = *(const uint4*)(Ah + kbase + m * 17760 + k0);
        }
        {
            const int col = kbp + bcol;
            const bool cok = col < blim;
#pragma unroll
            for (int e = 0; e < 8; ++e) {
                const int n = brow_l + e * 8;
                const int gn = n0 + n;
                bv[e] = (cok && gn < DE) ? B[gn * NG + kbase + col] : 0.f;
            }
        }
    };
    auto wr = [&](int buf, const uint4& da, const float (&bv)[8]) {
        unsigned short* Asb = As + buf * 4 * PSA;
        f16* BsH = (f16*)(Bs + buf * 4 * PSB);
        {
            const int m = t >> 2, kc = t & 3;
            *(uint4*)&Asb[kc * PSA + m * 8] = da;
        }
#pragma unroll
        for (int e = 0; e < 8; ++e) {
            const int n = brow_l + e * 8;
            BsH[bkc * PSB + n * 8 + bke] = (f16)bv[e];
        }
    };
    auto compute = [&](int buf) {
        const unsigned short* Asb = As + buf * 4 * PSA;
        const unsigned short* Bsb = Bs + buf * 4 * PSB;
        f16x8 af[2], bfr[2];
#pragma unroll
        for (int i = 0; i < 2; ++i)
            af[i] = *(f16x8*)&Asb[kg * PSA + (wm * 32 + i * 16 + lm) * 8];
#pragma unroll
        for (int j = 0; j < 2; ++j)
            bfr[j] = *(f16x8*)&Bsb[kg * PSB + (wn * 32 + j * 16 + lm) * 8];
#pragma unroll
        for (int i = 0; i < 2; ++i)
#pragma unroll
            for (int j = 0; j < 2; ++j)
                acc[i][j] = __builtin_amdgcn_mfma_f32_16x16x32_f16(
                    af[i], bfr[j], acc[i][j], 0, 0, 0);
    };

    constexpr int S = (EXP_KW + 31) / 32;   // 14
    uint4 dA_a, dA_b;
    float bv_a[8], bv_b[8];
    pf(0, dA_a, bv_a);
    pf(1, dA_b, bv_b);
    wr(0, dA_a, bv_a);
    pf(2, dA_a, bv_a);
    __syncthreads();
    int buf = 0, useB = 1;
    for (int s = 0; s < S; ++s) {
        compute(buf);
        if (s + 1 < S) {
            if (useB) { wr(buf ^ 1, dA_b, bv_b); pf(s + 3, dA_b, bv_b); }
            else      { wr(buf ^ 1, dA_a, bv_a); pf(s + 3, dA_a, bv_a); }
            useB ^= 1;
        }
        __syncthreads();
        buf ^= 1;
    }
    float* P = ws + O_PS2 + z * (NC * DE);
#pragma unroll
    for (int i = 0; i < 2; ++i) {
        const int mb = wm * 32 + i * 16 + kg * 4;
#pragma unroll
        for (int r = 0; r < 4; ++r) {
            const int m = mb + r;
            if (m >= NC) continue;
#pragma unroll
            for (int j = 0; j < 2; ++j) {
                const int n = n0 + wn * 32 + j * 16 + lm;
                if (n >= DE) continue;
                P[m * DE + n] = acc[i][j][r];
            }
        }
    }
}

// ============================================================================
// Unified fp16 MFMA NT GEMM, generalized job table.
//   Per grid-z: jobs [zs[z], zs[z]+zcnt[z]), M = Mz[z] (blocks with
//   m0 >= M exit immediately — whole block uniform, barrier-safe).
//   Double-buffered LDS: 1 barrier per 32-K step; ds_write(next buf) and
//   MFMA(cur buf) co-scheduled; register prefetch 2 steps ahead.
//   BMODE: 0 = B fp16 (uint4), 1 = B fp32 (2x float4, cvt at LDS-write).
//   Epilogue: v = rsg*acc (+ base[m,n]: bflag 1 -> basec, 2 -> based);
//   F16OUT picks h16 vs ws destination. Deterministic, no atomics.
// ============================================================================
template<int BM, int BN, int BMODE, int F16OUT>
__global__ __launch_bounds__(256) void k_fgemm(
    const f16* __restrict__ Ah, const void* __restrict__ Bp,
    float* __restrict__ ws, f16* __restrict__ h16,
    const float* __restrict__ basec, const float* __restrict__ based,
    int N, int ldc, int baseld, Job jb)
{
    constexpr int PSA = BM * 8 + 8;
    constexpr int PSB = BN * 8 + 8;
    constexpr int MI = BM / 32;
    constexpr int NI = BN / 32;
    constexpr int PA_IT = (BM * 4) / 256;
    constexpr int PB_IT = (BN * 4) / 256;
    __shared__ __align__(16) unsigned short As[2 * 4 * PSA];
    __shared__ __align__(16) unsigned short Bs[2 * 4 * PSB];
    const int bz = blockIdx.z;
    const int M = jb.Mz[bz];
    const int m0 = blockIdx.y * BM;
    if (m0 >= M) return;
    const int t = threadIdx.x;
    const int wv = t >> 6, ln = t & 63;
    const int wm = wv >> 1, wn = wv & 1;
    const int kg = ln >> 4, lm = ln & 15;
    const int n0 = blockIdx.x * BN;

    f32x4 acc[MI][NI];
#pragma unroll
    for (int i = 0; i < MI; ++i)
#pragma unroll
        for (int j = 0; j < NI; ++j) acc[i][j] = (f32x4){0.f, 0.f, 0.f, 0.f};

    const int z0 = jb.zs[bz];
    const int z1 = z0 + jb.zcnt[bz];

    uint4 pAa[PA_IT], pAb[PA_IT];
    uint4 pB0a[PB_IT], pB0b[PB_IT];
    float4 pBxa[PB_IT], pBya[PB_IT], pBxb[PB_IT], pByb[PB_IT];

    for (int zi = z0; zi < z1; ++zi) {
        const int Ab = jb.aoff[zi], Bb = jb.boff[zi];
        const int lda = jb.lda[zi], ldb = jb.ldb[zi];
        const int len = jb.len[zi];

        auto pf = [&](int s, uint4 (&pA)[PA_IT], uint4 (&pB0)[PB_IT],
                      float4 (&pBx)[PB_IT], float4 (&pBy)[PB_IT]) {
            const int kbp = s << 5;
#pragma unroll
            for (int p = 0; p < PA_IT; ++p) {
                const int ci = p * 256 + t;
                const int m = ci >> 2, kc = ci & 3;
                const int k0 = kbp + kc * 8;
                uint4 d = {0u, 0u, 0u, 0u};
                if (m0 + m < M && k0 < len)
                    d = *(const uint4*)(Ah + Ab + (m0 + m) * lda + k0);
                pA[p] = d;
            }
#pragma unroll
            for (int p = 0; p < PB_IT; ++p) {
                const int ci = p * 256 + t;
                const int n = ci >> 2, kc = ci & 3;
                const int k0 = kbp + kc * 8;
                const bool ok = (n0 + n < N) && (k0 < len);
                if (BMODE == 0) {
                    uint4 d = {0u, 0u, 0u, 0u};
                    if (ok) d = *(const uint4*)((const f16*)Bp + Bb + (n0 + n) * ldb + k0);
                    pB0[p] = d;
                } else {
                    float4 x = {0.f, 0.f, 0.f, 0.f}, y = {0.f, 0.f, 0.f, 0.f};
                    if (ok) {
                        const float* bq = (const float*)Bp + Bb + (n0 + n) * ldb + k0;
                        x = *(const float4*)bq;
                        y = *(const float4*)(bq + 4);
                    }
                    pBx[p] = x; pBy[p] = y;
                }
            }
        };
        auto wr = [&](int buf, uint4 (&pA)[PA_IT], uint4 (&pB0)[PB_IT],
                      float4 (&pBx)[PB_IT], float4 (&pBy)[PB_IT]) {
            unsigned short* Asb = As + buf * 4 * PSA;
            unsigned short* Bsb = Bs + buf * 4 * PSB;
#pragma unroll
            for (int p = 0; p < PA_IT; ++p) {
                const int ci = p * 256 + t;
                const int m = ci >> 2, kc = ci & 3;
                *(uint4*)&Asb[kc * PSA + m * 8] = pA[p];
            }
#pragma unroll
            for (int p = 0; p < PB_IT; ++p) {
                const int ci = p * 256 + t;
                const int n = ci >> 2, kc = ci & 3;
                if (BMODE == 0) {
                    *(uint4*)&Bsb[kc * PSB + n * 8] = pB0[p];
                } else {
                    f16x8 pk;
                    pk[0] = (f16)pBx[p].x; pk[1] = (f16)pBx[p].y;
                    pk[2] = (f16)pBx[p].z; pk[3] = (f16)pBx[p].w;
                    pk[4] = (f16)pBy[p].x; pk[5] = (f16)pBy[p].y;
                    pk[6] = (f16)pBy[p].z; pk[7] = (f16)pBy[p].w;
                    *(f16x8*)&Bsb[kc * PSB + n * 8] = pk;
                }
            }
        };
        auto compute = [&](int buf) {
            const unsigned short* Asb = As + buf * 4 * PSA;
            const unsigned short* Bsb = Bs + buf * 4 * PSB;
            f16x8 af[MI], bfr[NI];
#pragma unroll
            for (int i = 0; i < MI; ++i)
                af[i] = *(f16x8*)&Asb[kg * PSA + (wm * (BM / 2) + i * 16 + lm) * 8];
#pragma unroll
            for (int j = 0; j < NI; ++j)
                bfr[j] = *(f16x8*)&Bsb[kg * PSB + (wn * (BN / 2) + j * 16 + lm) * 8];
#pragma unroll
            for (int i = 0; i < MI; ++i)
#pragma unroll
                for (int j = 0; j < NI; ++j)
                    acc[i][j] = __builtin_amdgcn_mfma_f32_16x16x32_f16(
                        af[i], bfr[j], acc[i][j], 0, 0, 0);
        };

        const int S = (len + 31) >> 5;
        pf(0, pAa, pB0a, pBxa, pBya);
        pf(1, pAb, pB0b, pBxb, pByb);
        wr(0, pAa, pB0a, pBxa, pBya);
        pf(2, pAa, pB0a, pBxa, pBya);
        __syncthreads();
        int buf = 0, useB = 1;
        for (int s = 0; s < S; ++s) {
            compute(buf);
            if (s + 1 < S) {
                if (useB) { wr(buf ^ 1, pAb, pB0b, pBxb, pByb); pf(s + 3, pAb, pB0b, pBxb, pByb); }
                else      { wr(buf ^ 1, pAa, pB0a, pBxa, pBya); pf(s + 3, pAa, pB0a, pBxa, pBya); }
                useB ^= 1;
            }
            __syncthreads();
            buf ^= 1;
        }
    }
    // ---- epilogue ----
    const int zz = z0;
    const float rs = jb.rsg[zz];
    const int co = jb.coff[zz];
    const int bfl = jb.bflag[zz];
    const float* basep = (bfl == 1) ? basec : based;
#pragma unroll
    for (int i = 0; i < MI; ++i) {
        const int mb = m0 + wm * (BM / 2) + i * 16 + kg * 4;
#pragma unroll
        for (int r = 0; r < 4; ++r) {
            const int m = mb + r;
            if (m >= M) continue;
#pragma unroll
            for (int j = 0; j < NI; ++j) {
                const int n = n0 + wn * (BN / 2) + j * 16 + lm;
                if (n >= N) continue;
                float v = rs * acc[i][j][r];
                if (bfl) v += basep[m * baseld + n];
                if (F16OUT) h16[co + m * ldc + n] = (f16)v;
                else        ws[co + m * ldc + n] = v;
            }
        }
    }
}

// ---- fixed-order reduction of Z partial slabs ----
__global__ __launch_bounds__(256) void k_reduce(
    const float* __restrict__ P, float* __restrict__ out, int Z, int slab, int n)
{
    const int i = blockIdx.x * 256 + threadIdx.x;
    if (i < n) {
        float s = 0.f;
        for (int z = 0; z < Z; ++z) s += P[z * slab + i];
        out[i] = s;
    }
}

// ---- BatchNorm (train stats): one block per column, register-resident ----
__global__ __launch_bounds__(256) void k_bn2(
    float* __restrict__ ws, f16* __restrict__ h16,
    const float* __restrict__ cg, const float* __restrict__ cb,
    const float* __restrict__ dg, const float* __restrict__ db)
{
    __shared__ float r1[256];
    __shared__ float r2[256];
    const int id = blockIdx.x, t = threadIdx.x;
    float* X; f16* T; const float* g; const float* b; int R, Rp, ldT, d;
    if (id < DE) { d = id; X = ws + O_EMBC; T = h16 + H_EXPT; g = cg; b = cb; R = NC; Rp = 64; ldT = 64; }
    else { d = id - DE; X = ws + O_EMBD; T = h16 + H_FIGT; g = dg; b = db; R = ND; Rp = 960; ldT = 960; }
    float vals[4];
    float s = 0.f, q = 0.f;
#pragma unroll
    for (int v = 0; v < 4; ++v) {
        const int r = t + v * 256;
        float x = 0.f;
        if (r < R) x = X[r * DE + d];
        vals[v] = x;
        s += x; q += x * x;
    }
    r1[t] = s; r2[t] = q;
    __syncthreads();
    for (int off = 128; off > 0; off >>= 1) {
        if (t < off) { r1[t] += r1[t + off]; r2[t] += r2[t + off]; }
        __syncthreads();
    }
    const float mu = r1[0] / (float)R;
    float var = r2[0] / (float)R - mu * mu;
    var = fmaxf(var, 0.f);
    const float sc = rsqrtf(var + EPS_BN) * g[d];
    const float sh = b[d] - mu * sc;
#pragma unroll
    for (int v = 0; v < 4; ++v) {
        const int r = t + v * 256;
        if (r < R) {
            const float y = vals[v] * sc + sh;
            X[r * DE + d] = y;
            T[d * ldT + r] = (f16)y;
        } else if (r < Rp) {
            T[d * ldT + r] = (f16)0.f;
        }
    }
}

// ---- Xc/Xd block0 = diag-scaled emb (fp16) ----
__global__ __launch_bounds__(256) void k_buildX(
    const float* __restrict__ ws, f16* __restrict__ h16)
{
    const int idx = blockIdx.x * 256 + threadIdx.x;
    if (idx < NC * DE) {
        const int c = idx / DE, d = idx % DE;
        h16[H_XC + c * (4 * DE) + d] = (f16)(ws[O_DC + c] * ws[O_EMBC + idx]);
    } else if (idx < (NC + ND) * DE) {
        const int k = idx - NC * DE;
        const int i = k / DE, d = k % DE;
        h16[H_XD + i * (4 * DE) + d] = (f16)(ws[O_DDV + i] * ws[O_EMBD + k]);
    }
}

// ---- epilogue: agg = relu((sum + bias)*(emb+1)) in-place ----
// drug sum = DSUM + SLB1 + SLB2 (step-11 K-split partials), fixed order.
__global__ __launch_bounds__(256) void k_epi(
    float* __restrict__ ws, const float* __restrict__ b_agg)
{
    const int idx = blockIdx.x * 256 + threadIdx.x;
    if (idx < NC * DE) {
        const int d = idx % DE;
        const float bc = b_agg[0 * DE + d] + b_agg[1 * DE + d] + b_agg[4 * DE + d] + b_agg[6 * DE + d];
        const float v = (ws[O_CSUM + idx] + bc) * (ws[O_EMBC + idx] + 1.f);
        ws[O_CSUM + idx] = fmaxf(v, 0.f);
    } else if (idx < (NC + ND) * DE) {
        const int k = idx - NC * DE;
        const int d = k % DE;
        const float bd = b_agg[2 * DE + d] + b_agg[3 * DE + d] + b_agg[5 * DE + d] + b_agg[7 * DE + d];
        const float sum = ws[O_DSUM + k] + ws[O_SLB1 + k] + ws[O_SLB2 + k];
        const float v = (sum + bd) * (ws[O_EMBD + k] + 1.f);
        ws[O_DSUM + k] = fmaxf(v, 0.f);
    }
}

// ---- per-row mean + 1/||x-mu|| ----
__global__ __launch_bounds__(256) void k_rowstats(float* __restrict__ ws)
{
    __shared__ float red[256];
    const int b = blockIdx.x, t = threadIdx.x;
    const float* row;
    int omu, ois;
    if (b < NC) { row = ws + O_CSUM + b * DE; omu = O_CMU + b; ois = O_CIS + b; }
    else { const int i = b - NC; row = ws + O_DSUM + i * DE; omu = O_DMU + i; ois = O_DIS + i; }
    float s = 0.f;
    for (int j = t; j < DE; j += 256) s += row[j];
    const float mu = blockReduceSum(s, red) / (float)DE;
    float q = 0.f;
    for (int j = t; j < DE; j += 256) { const float v = row[j] - mu; q += v * v; }
    const float ss = blockReduceSum(q, red);
    if (t == 0) { ws[omu] = mu; ws[ois] = rsqrtf(ss); }
}

// ---- corr + sigmoid ----
__global__ __launch_bounds__(256) void k_corr(
    const float* __restrict__ ws, float* __restrict__ out)
{
    const int KT = 32;
    __shared__ float xs[16][KT + 1];
    __shared__ float ys[16][KT + 1];
    const int t = threadIdx.x;
    const int tcr = t >> 4, ti = t & 15;
    const int c0 = blockIdx.y * 16, i0 = blockIdx.x * 16;
    float acc = 0.f;
    for (int kb = 0; kb < DE; kb += KT) {
#pragma unroll
        for (int q = 0; q < 2; ++q) {
            const int s = q * 256 + t;
            const int row = s >> 5, kk = s & 31;
            const int k = kb + kk;
            const int c = c0 + row;
            xs[row][kk] = (c < NC && k < DE) ? ws[O_CSUM + c * DE + k] : 0.f;
            const int i = i0 + row;
            ys[row][kk] = (i < ND && k < DE) ? ws[O_DSUM + i * DE + k] : 0.f;
        }
        __syncthreads();
#pragma unroll
        for (int kt = 0; kt < KT; ++kt) acc += xs[tcr][kt] * ys[ti][kt];
        __syncthreads();
    }
    const int c = c0 + tcr, i = i0 + ti;
    if (c < NC && i < ND) {
        const float num = acc - (float)DE * ws[O_CMU + c] * ws[O_DMU + i];
        const float corr = num * ws[O_CIS + c] * ws[O_DIS + i];
        out[c * ND + i] = 1.f / (1.f + expf(-GAMMA_C * corr));
    }
}

static inline void jclear(Job& j) {
    for (int z = 0; z < 24; ++z) {
        j.aoff[z] = j.boff[z] = j.lda[z] = j.ldb[z] = 0;
        j.len[z] = j.coff[z] = j.bflag[z] = 0;
        j.rsg[z] = 1.f;
        j.zs[z] = 0; j.zcnt[z] = 0; j.Mz[z] = 0;
    }
}

extern "C" void kernel_launch(void* const* d_in, const int* in_sizes, int n_in,
                              void* d_out, int out_size, void* d_ws, size_t ws_size,
                              hipStream_t stream)
{
    const float* adj         = (const float*)d_in[0];
    const float* cell_exprs  = (const float*)d_in[1];
    const float* drug_finger = (const float*)d_in[2];
    const float* cell_hyper  = (const float*)d_in[3];
    const float* drug_hyper  = (const float*)d_in[4];
    const float* W_agg       = (const float*)d_in[5];
    const float* b_agg       = (const float*)d_in[6];
    const float* ldd_w       = (const float*)d_in[7];
    const float* lcc_w       = (const float*)d_in[9];
    const float* bnd_g       = (const float*)d_in[11];
    const float* bnd_b       = (const float*)d_in[12];
    const float* bnc_g       = (const float*)d_in[13];
    const float* bnc_b       = (const float*)d_in[14];
    float* ws  = (float*)d_ws;
    float* out = (float*)d_out;
    f16* h16 = (f16*)(ws + O_H16);

    // 1) scalars
    k_pre<<<NC + ND, 256, 0, stream>>>(adj, cell_hyper, drug_hyper, ws);
    // 2) z-norm stats
    k_zstats<<<NC, 256, 0, stream>>>(cell_exprs, ws);
    // 3) fp16 operand pool (scale-folded, padded)
    k_cvt<<<2048, 256, 0, stream>>>(cell_exprs, drug_finger, ldd_w, adj,
                                    cell_hyper, drug_hyper, ws, h16);

    // 4) exp = cx16 @ lcc_w^T — dedicated split-K (40 windows x 32 n-blocks)
    k_gemm_exp<<<dim3(32, 1, EXP_NWIN), 256, 0, stream>>>(h16, lcc_w, ws);
    k_reduce<<<479, 256, 0, stream>>>(ws + O_PS2, ws + O_EMBC, EXP_NWIN,
                                      NC * DE, NC * DE);

    // 5) fig = df16 @ ldw16^T (K=896) -> embD direct
    {
        Job j; jclear(j);
        j.aoff[0] = H_DF; j.lda[0] = 896;
        j.boff[0] = H_LDW; j.ldb[0] = 896;
        j.len[0] = 896; j.coff[0] = O_EMBD;
        j.zs[0] = 0; j.zcnt[0] = 1; j.Mz[0] = ND;
        k_fgemm<64, 64, 0, 0><<<dim3(32, 15, 1), 256, 0, stream>>>(
            h16, h16, ws, h16, nullptr, nullptr, DE, DE, DE, j);
    }
    // 6) BN (in-place fp32) + expT16/figT16 — one block per column
    k_bn2<<<2 * DE, 256, 0, stream>>>(ws, h16, bnc_g, bnc_b, bnd_g, bnd_b);
    // 7) Xc/Xd block0
    k_buildX<<<8065, 256, 0, stream>>>(ws, h16);

    // 8+9) cell X-jobs (z0..2, M=NC) + drug X-jobs (z3..5, M=ND), one launch
    {
        Job j; jclear(j);
        j.aoff[0] = H_ALC; j.lda[0] = 960; j.boff[0] = H_FIGT; j.ldb[0] = 960;
        j.len[0] = 960; j.coff[0] = H_XC + DE;
        j.aoff[1] = H_CH;  j.lda[1] = 64;  j.boff[1] = H_EXPT; j.ldb[1] = 64;
        j.len[1] = 64;  j.coff[1] = H_XC + 2 * DE;
        j.aoff[2] = H_CHS; j.lda[2] = 64;  j.boff[2] = H_EXPT; j.ldb[2] = 64;
        j.len[2] = 64;  j.coff[2] = H_XC + 3 * DE; j.rsg[2] = -1.f; j.bflag[2] = 1;
        j.aoff[3] = H_ALD; j.lda[3] = 64;  j.boff[3] = H_EXPT; j.ldb[3] = 64;
        j.len[3] = 64;  j.coff[3] = H_XD + DE;
        j.aoff[4] = H_DH;  j.lda[4] = 960; j.boff[4] = H_FIGT; j.ldb[4] = 960;
        j.len[4] = 960; j.coff[4] = H_XD + 2 * DE;
        j.aoff[5] = H_DHS; j.lda[5] = 960; j.boff[5] = H_FIGT; j.ldb[5] = 960;
        j.len[5] = 960; j.coff[5] = H_XD + 3 * DE; j.rsg[5] = -1.f; j.bflag[5] = 2;
        for (int z = 0; z < 6; ++z) {
            j.zs[z] = z; j.zcnt[z] = 1;
            j.Mz[z] = (z < 3) ? NC : ND;
        }
        k_fgemm<64, 64, 0, 1><<<dim3(32, 15, 6), 256, 0, stream>>>(
            h16, h16, ws, h16, ws + O_EMBC, ws + O_EMBD, DE, 4 * DE, DE, j);
    }
    // 10+11) cell main (8 windows, z0..7 -> O_PS slabs) + drug main
    //     (6 jobs in 3 z-groups of K=2720: z8 W2+W3a->DSUM, z9 W3b+W5a->SLB1,
    //      z10 W5b+W7->SLB2) in ONE launch. k_epi sums drug partials.
    {
        const int permc[4] = {0, 1, 4, 6};
        Job j; jclear(j);
        for (int z = 0; z < 8; ++z) {
            const int ib = z >> 1, sub = z & 1;
            const int ko = sub * 1024;
            j.aoff[z] = H_XC + ib * DE + ko; j.lda[z] = 4 * DE;
            j.boff[z] = permc[ib] * DE * DE + ko; j.ldb[z] = DE;
            j.len[z] = sub ? 1016 : 1024;
            j.coff[z] = O_PS + z * (NC * DE);
            j.zs[z] = z; j.zcnt[z] = 1; j.Mz[z] = NC;
        }
        j.aoff[8]  = H_XD;               j.boff[8]  = 2 * DE * DE;       j.len[8]  = 2040;
        j.aoff[9]  = H_XD + DE;          j.boff[9]  = 3 * DE * DE;       j.len[9]  = 680;
        j.aoff[10] = H_XD + DE + 680;    j.boff[10] = 3 * DE * DE + 680; j.len[10] = 1360;
        j.aoff[11] = H_XD + 2 * DE;      j.boff[11] = 5 * DE * DE;       j.len[11] = 1360;
        j.aoff[12] = H_XD + 2 * DE + 1360; j.boff[12] = 5 * DE * DE + 1360; j.len[12] = 680;
        j.aoff[13] = H_XD + 3 * DE;      j.boff[13] = 7 * DE * DE;       j.len[13] = 2040;
        for (int q = 8; q < 14; ++q) { j.lda[q] = 4 * DE; j.ldb[q] = DE; }
        j.coff[8] = O_DSUM; j.coff[10] = O_SLB1; j.coff[12] = O_SLB2;
        j.zs[8]  = 8;  j.zcnt[8]  = 2; j.Mz[8]  = ND;
        j.zs[9]  = 10; j.zcnt[9]  = 2; j.Mz[9]  = ND;
        j.zs[10] = 12; j.zcnt[10] = 2; j.Mz[10] = ND;
        k_fgemm<64, 64, 1, 0><<<dim3(32, 15, 11), 256, 0, stream>>>(
            h16, W_agg, ws, h16, nullptr, nullptr, DE, DE, DE, j);
        k_reduce<<<479, 256, 0, stream>>>(ws + O_PS, ws + O_CSUM, 8,
                                          NC * DE, NC * DE);
    }

    // 12) epilogue, stats, corr
    k_epi<<<8065, 256, 0, stream>>>(ws, b_agg);
    k_rowstats<<<NC + ND, 256, 0, stream>>>(ws);
    k_corr<<<dim3(60, 4), 256, 0, stream>>>(ws, out);

    (void)in_sizes; (void)n_in; (void)out_size; (void)ws_size;
}